// Round 4
// baseline (4730.300 us; speedup 1.0000x reference)
//
#include <hip/hip_runtime.h>
#include <hip/hip_bf16.h>

#define BB 2
#define HH 256
#define WW 256
#define HW (HH*WW)

__device__ __forceinline__ float geluf(float x) {
    return 0.5f * x * (1.0f + erff(x * 0.7071067811865475f));
}

__device__ __forceinline__ float ldf(const float* p) { return *p; }
__device__ __forceinline__ float ldf(const __hip_bfloat16* p) { return __bfloat162float(*p); }

// compact index [0,96) -> actual coordinate (rows/cols = 0,2,6 mod 8)
__device__ __forceinline__ int dec96(int i) {
    int q = i / 3, r = i - q * 3;
    return q * 8 + (r == 0 ? 0 : (r == 1 ? 2 : 6));
}

// Generic 3x3 conv, pad=1, COB output channels per thread.
// ACT: 0=none, 1=gelu, 2=relu
template<int CIN, int COB, int ACT, typename TIN>
__global__ __launch_bounds__(256) void conv3x3_kernel(
    const TIN* __restrict__ in, const float* __restrict__ wgt,
    const float* __restrict__ bias, float* __restrict__ out, int coBlocks)
{
    const int wx = blockIdx.x * 32 + threadIdx.x;
    const int hy = blockIdx.y * 8 + threadIdx.y;
    const int co = (blockIdx.z % coBlocks) * COB;
    const int b  = blockIdx.z / coBlocks;

    float acc[COB];
    #pragma unroll
    for (int k = 0; k < COB; ++k) acc[k] = bias[co + k];

    bool ok[9];
    int off[9];
    #pragma unroll
    for (int ky = 0; ky < 3; ++ky) {
        const int iy = hy + ky - 1;
        const bool oky = (unsigned)iy < (unsigned)HH;
        #pragma unroll
        for (int kx = 0; kx < 3; ++kx) {
            const int ix = wx + kx - 1;
            ok[ky*3+kx]  = oky && ((unsigned)ix < (unsigned)WW);
            off[ky*3+kx] = iy * WW + ix;
        }
    }

    const TIN* inb = in + (size_t)b * CIN * HW;
    const float* wb = wgt + (size_t)co * CIN * 9;

    #pragma unroll 1
    for (int ci = 0; ci < CIN; ++ci) {
        const TIN* inc = inb + (size_t)ci * HW;
        float v[9];
        #pragma unroll
        for (int t = 0; t < 9; ++t)
            v[t] = ok[t] ? ldf(inc + off[t]) : 0.0f;
        #pragma unroll
        for (int k = 0; k < COB; ++k) {
            const float* wk = wb + ((size_t)k * CIN + ci) * 9;
            #pragma unroll
            for (int t = 0; t < 9; ++t)
                acc[k] = fmaf(v[t], wk[t], acc[k]);
        }
    }

    #pragma unroll
    for (int k = 0; k < COB; ++k) {
        float r = acc[k];
        if (ACT == 1) r = geluf(r);
        if (ACT == 2) r = fmaxf(r, 0.0f);
        size_t oidx = ((size_t)(blockIdx.z * COB + k) * HH + hy) * WW + wx;
        out[oidx] = r;
    }
}

// Branch conv (64->64, 3x3, pad 1) evaluated ONLY at the compact 96x96 grid
// of pixels the stride-8/dil-2 depthwise conv will read. All 7 distinct
// layers in one launch. out = gelu(conv)+feat at the same pixel.
__global__ __launch_bounds__(256) void branch_conv_kernel(
    const float* __restrict__ feat,   // [B,64,256,256]
    const float* __restrict__ ddct_w, // [7,64,64,3,3]
    const float* __restrict__ ddct_b, // [7,64]
    float* __restrict__ ycomp)        // [7,B,64,96,96]
{
    const int c_comp = blockIdx.x * 32 + threadIdx.x; // [0,96)
    const int r_comp = blockIdx.y * 8 + threadIdx.y;  // [0,96)
    int z = blockIdx.z;                               // li*(B*8) + b*8 + coB
    const int li = z / (BB * 8);
    z -= li * (BB * 8);
    const int b  = z / 8;
    const int co = (z - b * 8) * 8;

    const int C = dec96(c_comp);
    const int R = dec96(r_comp);

    float acc[8];
    #pragma unroll
    for (int k = 0; k < 8; ++k) acc[k] = ddct_b[li * 64 + co + k];

    bool ok[9];
    int off[9];
    #pragma unroll
    for (int ky = 0; ky < 3; ++ky) {
        const int iy = R + ky - 1;
        const bool oky = (unsigned)iy < (unsigned)HH;
        #pragma unroll
        for (int kx = 0; kx < 3; ++kx) {
            const int ix = C + kx - 1;
            ok[ky*3+kx]  = oky && ((unsigned)ix < (unsigned)WW);
            off[ky*3+kx] = iy * WW + ix;
        }
    }

    const float* inb = feat + (size_t)b * 64 * HW;
    const float* wb  = ddct_w + (size_t)li * 64 * 64 * 9 + (size_t)co * 64 * 9;

    #pragma unroll 1
    for (int ci = 0; ci < 64; ++ci) {
        const float* inc = inb + (size_t)ci * HW;
        float v[9];
        #pragma unroll
        for (int t = 0; t < 9; ++t)
            v[t] = ok[t] ? inc[off[t]] : 0.0f;
        #pragma unroll
        for (int k = 0; k < 8; ++k) {
            const float* wk = wb + ((size_t)k * 64 + ci) * 9;
            #pragma unroll
            for (int t = 0; t < 9; ++t)
                acc[k] = fmaf(v[t], wk[t], acc[k]);
        }
    }

    #pragma unroll
    for (int k = 0; k < 8; ++k) {
        float r = geluf(acc[k]) + feat[(((size_t)b * 64 + co + k) * HH + R) * WW + C];
        ycomp[((((size_t)li * BB + b) * 64 + co + k) * 96 + r_comp) * 96 + c_comp] = r;
    }
}

// Depthwise 3x3, stride 8, dil 2, pad 2 -> 32x32, reading the compact grid.
// (block DCT->IDCT is the identity with an orthonormal basis: skipped.)
__global__ __launch_bounds__(256) void dctc_kernel(
    const float* __restrict__ ycomp,  // [7,B,64,96,96]
    const float* __restrict__ dctc_w, // [7,64,1,3,3]
    const float* __restrict__ dctc_b, // [7,64]
    float* __restrict__ s_all)        // [7,B,64,32,32]
{
    const int idx = blockIdx.x * 256 + threadIdx.x;
    if (idx >= 7 * BB * 64 * 32 * 32) return;
    const int ow = idx & 31;
    const int oh = (idx >> 5) & 31;
    const int c  = (idx >> 10) & 63;
    const int b  = (idx >> 16) & (BB - 1);
    const int li = idx >> 17;

    const float* yc = ycomp + (((size_t)li * BB + b) * 64 + c) * (96 * 96);
    const float* w  = dctc_w + (li * 64 + c) * 9;
    float acc = dctc_b[li * 64 + c];
    #pragma unroll
    for (int ky = 0; ky < 3; ++ky) {
        const int cr = 3 * oh + ky - 1;     // maps to rows 8oh-2, 8oh, 8oh+2
        if (cr < 0) continue;
        #pragma unroll
        for (int kx = 0; kx < 3; ++kx) {
            const int cc = 3 * ow + kx - 1;
            if (cc < 0) continue;
            acc = fmaf(yc[cr * 96 + cc], w[ky * 3 + kx], acc);
        }
    }
    s_all[idx] = acc;
}

// Fused: 1x1 conv (32->512) + sigmoid gate, bilinear 32->256 upsample of the
// matching branch output, multiply, store bf16.
__global__ __launch_bounds__(256) void gated_kernel(
    const float* __restrict__ relu1,  // [B,32,256,256]
    const float* __restrict__ dw3_w,  // [512,32]
    const float* __restrict__ dw3_b,  // [512]
    const float* __restrict__ s_all,  // [7,B,64,32,32]
    __hip_bfloat16* __restrict__ gated) // [B,512,256,256]
{
    const int wx = threadIdx.x;
    const int hy = blockIdx.y;
    const int z  = blockIdx.x;            // b*512 + ch
    const int b  = z >> 9;
    const int ch = z & 511;
    const int branch = ch >> 6;
    const int c  = ch & 63;
    const int lmap[8] = {0, 1, 2, 3, 4, 3, 5, 6};
    const int li = lmap[branch];

    float acc = dw3_b[ch];
    const float* rp = relu1 + ((size_t)b * 32 * HH + hy) * WW + wx;
    const float* wp = dw3_w + ch * 32;
    #pragma unroll
    for (int k = 0; k < 32; ++k)
        acc = fmaf(rp[(size_t)k * HW], wp[k], acc);
    const float g = 1.0f / (1.0f + expf(-acc));

    // bilinear, half-pixel centers, edge clamp (== jax.image.resize linear upsample)
    const float sy = (hy + 0.5f) * 0.125f - 0.5f;
    const float sx = (wx + 0.5f) * 0.125f - 0.5f;
    const float fy0 = floorf(sy), fx0 = floorf(sx);
    const float fy = sy - fy0, fx = sx - fx0;
    int y0 = (int)fy0, x0 = (int)fx0;
    const int y1 = min(y0 + 1, 31), x1 = min(x0 + 1, 31);
    y0 = max(y0, 0); x0 = max(x0, 0);
    const float* sp = s_all + (((size_t)li * BB + b) * 64 + c) * 1024;
    const float v00 = sp[y0*32+x0], v01 = sp[y0*32+x1];
    const float v10 = sp[y1*32+x0], v11 = sp[y1*32+x1];
    const float v = (1.f - fy) * ((1.f - fx) * v00 + fx * v01)
                  + fy * ((1.f - fx) * v10 + fx * v11);

    gated[((size_t)z * HH + hy) * WW + wx] = __float2bfloat16(v * g);
}

extern "C" void kernel_launch(void* const* d_in, const int* in_sizes, int n_in,
                              void* d_out, int out_size, void* d_ws, size_t ws_size,
                              hipStream_t stream) {
    const float* x      = (const float*)d_in[0];
    const float* conv_w = (const float*)d_in[1];
    const float* conv_b = (const float*)d_in[2];
    const float* ddct_w = (const float*)d_in[3];
    const float* ddct_b = (const float*)d_in[4];
    const float* dctc_w = (const float*)d_in[5];
    const float* dctc_b = (const float*)d_in[6];
    const float* dw1_w  = (const float*)d_in[7];
    const float* dw1_b  = (const float*)d_in[8];
    const float* dw3_w  = (const float*)d_in[9];
    const float* dw3_b  = (const float*)d_in[10];
    const float* ar_w   = (const float*)d_in[11];
    const float* ar_b   = (const float*)d_in[12];
    float* out = (float*)d_out;

    float* ws = (float*)d_ws;
    float* feat  = ws;                        // 2*64*256*256      = 8388608 f
    float* ycomp = feat  + 8388608;           // 7*2*64*96*96      = 8257536 f
    float* s_all = ycomp + 8257536;           // 7*2*64*32*32      = 917504 f
    float* relu1 = s_all + 917504;            // 2*32*256*256      = 4194304 f
    __hip_bfloat16* gated = (__hip_bfloat16*)(relu1 + 4194304); // 2*512*256*256 bf16

    const dim3 blk(32, 8);

    // 1) feat = gelu(conv3x3(x, conv_w))          72 -> 64
    conv3x3_kernel<72, 8, 1, float>
        <<<dim3(8, 32, BB * 8), blk, 0, stream>>>(x, conv_w, conv_b, feat, 8);

    // 2) compact branch convs, all 7 layers       64 -> 64 (gelu + residual)
    branch_conv_kernel
        <<<dim3(3, 12, 7 * BB * 8), blk, 0, stream>>>(feat, ddct_w, ddct_b, ycomp);

    // 3) depthwise stride-8 convs (DCT/IDCT identity skipped)
    dctc_kernel<<<dim3((7 * BB * 64 * 32 * 32) / 256), dim3(256), 0, stream>>>(
        ycomp, dctc_w, dctc_b, s_all);

    // 4) relu1 = relu(conv3x3(x, dw1_w))          72 -> 32
    conv3x3_kernel<72, 8, 2, float>
        <<<dim3(8, 32, BB * 4), blk, 0, stream>>>(x, dw1_w, dw1_b, relu1, 4);

    // 5) gated = upsample(s) * sigmoid(1x1conv(relu1))  -> bf16 [B,512,H,W]
    gated_kernel<<<dim3(BB * 512, HH), dim3(256), 0, stream>>>(
        relu1, dw3_w, dw3_b, s_all, gated);

    // 6) out = conv3x3(gated, ar_w)               512 -> 72
    conv3x3_kernel<512, 8, 0, __hip_bfloat16>
        <<<dim3(8, 32, BB * 9), blk, 0, stream>>>(gated, ar_w, ar_b, out, 9);
}

// Round 5
// 1738.653 us; speedup vs baseline: 2.7207x; 2.7207x over previous
//
#include <hip/hip_runtime.h>
#include <hip/hip_bf16.h>

#define BB 2
#define HH 256
#define WW 256
#define HW (HH*WW)

typedef __attribute__((ext_vector_type(8))) short bf16x8;
typedef __attribute__((ext_vector_type(4))) float f32x4;

__device__ __forceinline__ float geluf(float x) {
    return 0.5f * x * (1.0f + erff(x * 0.7071067811865475f));
}

__device__ __forceinline__ float ldf(const float* p) { return *p; }
__device__ __forceinline__ float ldf(const __hip_bfloat16* p) { return __bfloat162float(*p); }

__device__ __forceinline__ ushort f2bf(float f) {
    __hip_bfloat16 h = __float2bfloat16(f);
    return *reinterpret_cast<ushort*>(&h);
}

// compact index [0,96) -> actual coordinate (rows/cols = 0,2,6 mod 8)
__device__ __forceinline__ int dec96(int i) {
    int q = i / 3, r = i - q * 3;
    return q * 8 + (r == 0 ? 0 : (r == 1 ? 2 : 6));
}

// Generic 3x3 conv, pad=1, COB output channels per thread. ACT: 0=none,1=gelu,2=relu
template<int CIN, int COB, int ACT, typename TIN>
__global__ __launch_bounds__(256) void conv3x3_kernel(
    const TIN* __restrict__ in, const float* __restrict__ wgt,
    const float* __restrict__ bias, float* __restrict__ out, int coBlocks)
{
    const int wx = blockIdx.x * 32 + threadIdx.x;
    const int hy = blockIdx.y * 8 + threadIdx.y;
    const int co = (blockIdx.z % coBlocks) * COB;
    const int b  = blockIdx.z / coBlocks;

    float acc[COB];
    #pragma unroll
    for (int k = 0; k < COB; ++k) acc[k] = bias[co + k];

    bool ok[9];
    int off[9];
    #pragma unroll
    for (int ky = 0; ky < 3; ++ky) {
        const int iy = hy + ky - 1;
        const bool oky = (unsigned)iy < (unsigned)HH;
        #pragma unroll
        for (int kx = 0; kx < 3; ++kx) {
            const int ix = wx + kx - 1;
            ok[ky*3+kx]  = oky && ((unsigned)ix < (unsigned)WW);
            off[ky*3+kx] = iy * WW + ix;
        }
    }

    const TIN* inb = in + (size_t)b * CIN * HW;
    const float* wb = wgt + (size_t)co * CIN * 9;

    #pragma unroll 1
    for (int ci = 0; ci < CIN; ++ci) {
        const TIN* inc = inb + (size_t)ci * HW;
        float v[9];
        #pragma unroll
        for (int t = 0; t < 9; ++t)
            v[t] = ok[t] ? ldf(inc + off[t]) : 0.0f;
        #pragma unroll
        for (int k = 0; k < COB; ++k) {
            const float* wk = wb + ((size_t)k * CIN + ci) * 9;
            #pragma unroll
            for (int t = 0; t < 9; ++t)
                acc[k] = fmaf(v[t], wk[t], acc[k]);
        }
    }

    #pragma unroll
    for (int k = 0; k < COB; ++k) {
        float r = acc[k];
        if (ACT == 1) r = geluf(r);
        if (ACT == 2) r = fmaxf(r, 0.0f);
        size_t oidx = ((size_t)(blockIdx.z * COB + k) * HH + hy) * WW + wx;
        out[oidx] = r;
    }
}

// Branch conv (64->64, 3x3, pad 1) on the compact 96x96 grid only.
__global__ __launch_bounds__(256) void branch_conv_kernel(
    const float* __restrict__ feat, const float* __restrict__ ddct_w,
    const float* __restrict__ ddct_b, float* __restrict__ ycomp)
{
    const int c_comp = blockIdx.x * 32 + threadIdx.x;
    const int r_comp = blockIdx.y * 8 + threadIdx.y;
    int z = blockIdx.z;
    const int li = z / (BB * 8);
    z -= li * (BB * 8);
    const int b  = z / 8;
    const int co = (z - b * 8) * 8;

    const int C = dec96(c_comp);
    const int R = dec96(r_comp);

    float acc[8];
    #pragma unroll
    for (int k = 0; k < 8; ++k) acc[k] = ddct_b[li * 64 + co + k];

    bool ok[9];
    int off[9];
    #pragma unroll
    for (int ky = 0; ky < 3; ++ky) {
        const int iy = R + ky - 1;
        const bool oky = (unsigned)iy < (unsigned)HH;
        #pragma unroll
        for (int kx = 0; kx < 3; ++kx) {
            const int ix = C + kx - 1;
            ok[ky*3+kx]  = oky && ((unsigned)ix < (unsigned)WW);
            off[ky*3+kx] = iy * WW + ix;
        }
    }

    const float* inb = feat + (size_t)b * 64 * HW;
    const float* wb  = ddct_w + (size_t)li * 64 * 64 * 9 + (size_t)co * 64 * 9;

    #pragma unroll 1
    for (int ci = 0; ci < 64; ++ci) {
        const float* inc = inb + (size_t)ci * HW;
        float v[9];
        #pragma unroll
        for (int t = 0; t < 9; ++t)
            v[t] = ok[t] ? inc[off[t]] : 0.0f;
        #pragma unroll
        for (int k = 0; k < 8; ++k) {
            const float* wk = wb + ((size_t)k * 64 + ci) * 9;
            #pragma unroll
            for (int t = 0; t < 9; ++t)
                acc[k] = fmaf(v[t], wk[t], acc[k]);
        }
    }

    #pragma unroll
    for (int k = 0; k < 8; ++k) {
        float r = geluf(acc[k]) + feat[(((size_t)b * 64 + co + k) * HH + R) * WW + C];
        ycomp[((((size_t)li * BB + b) * 64 + co + k) * 96 + r_comp) * 96 + c_comp] = r;
    }
}

// Depthwise 3x3 stride 8 dil 2 pad 2 -> 32x32 (DCT->IDCT identity skipped).
__global__ __launch_bounds__(256) void dctc_kernel(
    const float* __restrict__ ycomp, const float* __restrict__ dctc_w,
    const float* __restrict__ dctc_b, float* __restrict__ s_all)
{
    const int idx = blockIdx.x * 256 + threadIdx.x;
    if (idx >= 7 * BB * 64 * 32 * 32) return;
    const int ow = idx & 31;
    const int oh = (idx >> 5) & 31;
    const int c  = (idx >> 10) & 63;
    const int b  = (idx >> 16) & (BB - 1);
    const int li = idx >> 17;

    const float* yc = ycomp + (((size_t)li * BB + b) * 64 + c) * (96 * 96);
    const float* w  = dctc_w + (li * 64 + c) * 9;
    float acc = dctc_b[li * 64 + c];
    #pragma unroll
    for (int ky = 0; ky < 3; ++ky) {
        const int cr = 3 * oh + ky - 1;
        if (cr < 0) continue;
        #pragma unroll
        for (int kx = 0; kx < 3; ++kx) {
            const int cc = 3 * ow + kx - 1;
            if (cc < 0) continue;
            acc = fmaf(yc[cr * 96 + cc], w[ky * 3 + kx], acc);
        }
    }
    s_all[idx] = acc;
}

// Gate + bilinear upsample + multiply, writing gated in NHWC bf16.
// Block = 32-px x-strip; thread = channel pair (ch0=2*tid). Coalesced NHWC writes.
__global__ __launch_bounds__(256) void gated_nhwc_kernel(
    const float* __restrict__ relu1, const float* __restrict__ dw3_w,
    const float* __restrict__ dw3_b, const float* __restrict__ s_all,
    ushort* __restrict__ gt)
{
    const int pix0 = blockIdx.x * 32;
    const int b  = pix0 >> 16;
    const int y  = (pix0 >> 8) & 255;
    const int x0 = pix0 & 255;
    const int ch0 = threadIdx.x * 2;
    const int branch = ch0 >> 6;
    const int c0 = ch0 & 63;
    const int lmap[8] = {0, 1, 2, 3, 4, 3, 5, 6};
    const int li = lmap[branch];

    float w0[32], w1[32];
    const float* wp0 = dw3_w + ch0 * 32;
    #pragma unroll
    for (int k = 0; k < 32; ++k) { w0[k] = wp0[k]; w1[k] = wp0[32 + k]; }
    const float bb0 = dw3_b[ch0], bb1 = dw3_b[ch0 + 1];

    const float* rp  = relu1 + (size_t)b * 32 * HW + y * WW + x0;
    const float* sp0 = s_all + (((size_t)li * BB + b) * 64 + c0) * 1024;
    const float* sp1 = sp0 + 1024;

    const float sy = (y + 0.5f) * 0.125f - 0.5f;
    const float fy0f = floorf(sy);
    const float fy = sy - fy0f;
    int y0 = (int)fy0f;
    const int y1 = min(y0 + 1, 31);
    y0 = max(y0, 0);

    #pragma unroll 1
    for (int px = 0; px < 32; ++px) {
        const int x = x0 + px;
        float a0 = bb0, a1 = bb1;
        #pragma unroll
        for (int k = 0; k < 32; ++k) {
            const float r = rp[(size_t)k * HW + px];
            a0 = fmaf(r, w0[k], a0);
            a1 = fmaf(r, w1[k], a1);
        }
        const float g0 = 1.0f / (1.0f + expf(-a0));
        const float g1 = 1.0f / (1.0f + expf(-a1));

        const float sx = (x + 0.5f) * 0.125f - 0.5f;
        const float fx0f = floorf(sx);
        const float fx = sx - fx0f;
        int x0i = (int)fx0f;
        const int x1i = min(x0i + 1, 31);
        x0i = max(x0i, 0);

        float v00 = sp0[y0*32+x0i], v01 = sp0[y0*32+x1i];
        float v10 = sp0[y1*32+x0i], v11 = sp0[y1*32+x1i];
        const float va = (1.f-fy)*((1.f-fx)*v00 + fx*v01) + fy*((1.f-fx)*v10 + fx*v11);
        v00 = sp1[y0*32+x0i]; v01 = sp1[y0*32+x1i];
        v10 = sp1[y1*32+x0i]; v11 = sp1[y1*32+x1i];
        const float vb = (1.f-fy)*((1.f-fx)*v00 + fx*v01) + fy*((1.f-fx)*v10 + fx*v11);

        const uint pack = (uint)f2bf(va * g0) | ((uint)f2bf(vb * g1) << 16);
        *reinterpret_cast<uint*>(gt + ((size_t)(pix0 + px)) * 512 + ch0) = pack;
    }
}

// Prepack ar_w into MFMA A-fragment order (bf16):
// wpack[((t*16+cb)*5+mf)*512 + lane*8 + j] = W[co = mf*16+(lane&15)][ci = cb*32+(lane>>4)*8+j][tap t]
__global__ __launch_bounds__(256) void prepack_w_kernel(
    const float* __restrict__ ar_w, ushort* __restrict__ wpack)
{
    const int idx = blockIdx.x * 256 + threadIdx.x;   // 9*16*5*64 = 46080
    if (idx >= 9 * 16 * 5 * 64) return;
    const int lane = idx & 63;
    int rest = idx >> 6;
    const int mf = rest % 5; rest /= 5;
    const int cb = rest & 15;
    const int t  = rest >> 4;
    const int co  = mf * 16 + (lane & 15);
    const int ci0 = cb * 32 + (lane >> 4) * 8;
    ushort* dst = wpack + (size_t)idx * 8;
    #pragma unroll
    for (int j = 0; j < 8; ++j) {
        const float w = (co < 72) ? ar_w[((size_t)co * 512 + ci0 + j) * 9 + t] : 0.0f;
        dst[j] = f2bf(w);
    }
}

// Final conv 512->72 as implicit GEMM on MFMA.
// A = weights [m=co 80pad][K], B = gated NHWC [K][n=pixels]. K = tap-major, 32 ci per step.
// Workgroup: 4 waves, 128 px; wave: 80co x 32px = acc[5 mf][2 nf] f32x4.
__global__ __launch_bounds__(256) void conv_ar_mfma_kernel(
    const ushort* __restrict__ gt, const ushort* __restrict__ wpack,
    const float* __restrict__ ar_b, float* __restrict__ out)
{
    const int lane = threadIdx.x & 63;
    const int wave = threadIdx.x >> 6;
    const int l15  = lane & 15;
    const int lg   = lane >> 4;

    const int bid  = blockIdx.x;          // 1024 = b(2) * y(256) * xt(2)
    const int b    = bid >> 9;
    const int rest = bid & 511;
    const int y    = rest >> 1;
    const int x0   = (rest & 1) * 128 + wave * 32;

    f32x4 acc[5][2];
    #pragma unroll
    for (int mf = 0; mf < 5; ++mf)
        #pragma unroll
        for (int nf = 0; nf < 2; ++nf)
            acc[mf][nf] = (f32x4){0.f, 0.f, 0.f, 0.f};

    const bf16x8 zero8 = {};

    #pragma unroll 1
    for (int t = 0; t < 9; ++t) {
        const int dy = t / 3 - 1, dx = t % 3 - 1;
        const int yy = y + dy;
        if ((unsigned)yy >= (unsigned)HH) continue;

        const int xA = x0 + l15 + dx;
        const int xB = xA + 16;
        const bool va = (unsigned)xA < (unsigned)WW;
        const bool vb = (unsigned)xB < (unsigned)WW;
        const int xAc = min(max(xA, 0), WW - 1);
        const int xBc = min(xB, WW - 1);

        const ushort* rowbase = gt + ((size_t)(b * HH + yy) * WW) * 512;
        const ushort* pA = rowbase + (size_t)xAc * 512 + lg * 8;
        const ushort* pB = rowbase + (size_t)xBc * 512 + lg * 8;
        const ushort* wp = wpack + (size_t)t * (16 * 5 * 512) + lane * 8;

        #pragma unroll 2
        for (int cb = 0; cb < 16; ++cb) {
            bf16x8 B0 = *reinterpret_cast<const bf16x8*>(pA + cb * 32);
            bf16x8 B1 = *reinterpret_cast<const bf16x8*>(pB + cb * 32);
            B0 = va ? B0 : zero8;
            B1 = vb ? B1 : zero8;
            const ushort* wpc = wp + (size_t)cb * (5 * 512);
            #pragma unroll
            for (int mf = 0; mf < 5; ++mf) {
                const bf16x8 A = *reinterpret_cast<const bf16x8*>(wpc + mf * 512);
                acc[mf][0] = __builtin_amdgcn_mfma_f32_16x16x32_bf16(A, B0, acc[mf][0], 0, 0, 0);
                acc[mf][1] = __builtin_amdgcn_mfma_f32_16x16x32_bf16(A, B1, acc[mf][1], 0, 0, 0);
            }
        }
    }

    // Epilogue: C[row=co][col=px]: co = mf*16 + lg*4 + r, px = x0 + nf*16 + l15
    #pragma unroll
    for (int mf = 0; mf < 5; ++mf) {
        const int co = mf * 16 + lg * 4;
        if (co >= 72) continue;
        #pragma unroll
        for (int nf = 0; nf < 2; ++nf) {
            const int x = x0 + nf * 16 + l15;
            float* op = out + (((size_t)(b * 72 + co) * HH + y) * WW) + x;
            #pragma unroll
            for (int r = 0; r < 4; ++r)
                op[(size_t)r * HW] = acc[mf][nf][r] + ar_b[co + r];
        }
    }
}

extern "C" void kernel_launch(void* const* d_in, const int* in_sizes, int n_in,
                              void* d_out, int out_size, void* d_ws, size_t ws_size,
                              hipStream_t stream) {
    const float* x      = (const float*)d_in[0];
    const float* conv_w = (const float*)d_in[1];
    const float* conv_b = (const float*)d_in[2];
    const float* ddct_w = (const float*)d_in[3];
    const float* ddct_b = (const float*)d_in[4];
    const float* dctc_w = (const float*)d_in[5];
    const float* dctc_b = (const float*)d_in[6];
    const float* dw1_w  = (const float*)d_in[7];
    const float* dw1_b  = (const float*)d_in[8];
    const float* dw3_w  = (const float*)d_in[9];
    const float* dw3_b  = (const float*)d_in[10];
    const float* ar_w   = (const float*)d_in[11];
    const float* ar_b   = (const float*)d_in[12];
    float* out = (float*)d_out;

    float* ws = (float*)d_ws;
    // gated_t (NHWC bf16): 2*256*256*512 ushort = 33,554,432 float-slots at ws+0.
    // feat/ycomp alias its range (both dead before gated_t is written).
    ushort* gated_t = (ushort*)ws;
    float* feat  = ws;                          // 8,388,608 f
    float* ycomp = ws + 8388608;                // 8,257,536 f (ends 16,646,144 < 33,554,432)
    float* s_all = ws + 33554432;               // 917,504 f
    float* relu1 = ws + 34471936;               // 4,194,304 f
    ushort* wpack = (ushort*)(ws + 38666240);   // 368,640 ushort

    const dim3 blk(32, 8);

    // 0) prepack final-conv weights into MFMA fragment order
    prepack_w_kernel<<<dim3(180), dim3(256), 0, stream>>>(ar_w, wpack);

    // 1) feat = gelu(conv3x3(x))                72 -> 64
    conv3x3_kernel<72, 8, 1, float>
        <<<dim3(8, 32, BB * 8), blk, 0, stream>>>(x, conv_w, conv_b, feat, 8);

    // 2) compact branch convs (7 layers)        64 -> 64
    branch_conv_kernel
        <<<dim3(3, 12, 7 * BB * 8), blk, 0, stream>>>(feat, ddct_w, ddct_b, ycomp);

    // 3) depthwise stride-8 convs
    dctc_kernel<<<dim3((7 * BB * 64 * 32 * 32) / 256), dim3(256), 0, stream>>>(
        ycomp, dctc_w, dctc_b, s_all);

    // 4) relu1 = relu(conv3x3(x))               72 -> 32
    conv3x3_kernel<72, 8, 2, float>
        <<<dim3(8, 32, BB * 4), blk, 0, stream>>>(x, dw1_w, dw1_b, relu1, 4);

    // 5) gated (NHWC bf16) = upsample(s) * sigmoid(1x1conv(relu1))
    gated_nhwc_kernel<<<dim3(BB * HW / 32), dim3(256), 0, stream>>>(
        relu1, dw3_w, dw3_b, s_all, gated_t);

    // 6) out = conv3x3(gated, ar_w)             512 -> 72, MFMA implicit GEMM
    conv_ar_mfma_kernel<<<dim3(BB * HH * 2), dim3(256), 0, stream>>>(
        gated_t, wpack, ar_b, out);
}

// Round 6
// 1727.605 us; speedup vs baseline: 2.7381x; 1.0064x over previous
//
#include <hip/hip_runtime.h>
#include <hip/hip_bf16.h>

#define BB 2
#define HH 256
#define WW 256
#define HW (HH*WW)

typedef __attribute__((ext_vector_type(8))) short bf16x8;
typedef __attribute__((ext_vector_type(4))) float f32x4;

__device__ __forceinline__ float geluf(float x) {
    return 0.5f * x * (1.0f + erff(x * 0.7071067811865475f));
}

__device__ __forceinline__ float ldf(const float* p) { return *p; }
__device__ __forceinline__ float ldf(const __hip_bfloat16* p) { return __bfloat162float(*p); }

__device__ __forceinline__ ushort f2bf(float f) {
    __hip_bfloat16 h = __float2bfloat16(f);
    return *reinterpret_cast<ushort*>(&h);
}

// compact index [0,96) -> actual coordinate (rows/cols = 0,2,6 mod 8)
__device__ __forceinline__ int dec96(int i) {
    int q = i / 3, r = i - q * 3;
    return q * 8 + (r == 0 ? 0 : (r == 1 ? 2 : 6));
}

// Generic 3x3 conv, pad=1, COB output channels per thread. ACT: 0=none,1=gelu,2=relu
template<int CIN, int COB, int ACT, typename TIN>
__global__ __launch_bounds__(256) void conv3x3_kernel(
    const TIN* __restrict__ in, const float* __restrict__ wgt,
    const float* __restrict__ bias, float* __restrict__ out, int coBlocks)
{
    const int wx = blockIdx.x * 32 + threadIdx.x;
    const int hy = blockIdx.y * 8 + threadIdx.y;
    const int co = (blockIdx.z % coBlocks) * COB;
    const int b  = blockIdx.z / coBlocks;

    float acc[COB];
    #pragma unroll
    for (int k = 0; k < COB; ++k) acc[k] = bias[co + k];

    bool ok[9];
    int off[9];
    #pragma unroll
    for (int ky = 0; ky < 3; ++ky) {
        const int iy = hy + ky - 1;
        const bool oky = (unsigned)iy < (unsigned)HH;
        #pragma unroll
        for (int kx = 0; kx < 3; ++kx) {
            const int ix = wx + kx - 1;
            ok[ky*3+kx]  = oky && ((unsigned)ix < (unsigned)WW);
            off[ky*3+kx] = iy * WW + ix;
        }
    }

    const TIN* inb = in + (size_t)b * CIN * HW;
    const float* wb = wgt + (size_t)co * CIN * 9;

    #pragma unroll 1
    for (int ci = 0; ci < CIN; ++ci) {
        const TIN* inc = inb + (size_t)ci * HW;
        float v[9];
        #pragma unroll
        for (int t = 0; t < 9; ++t)
            v[t] = ok[t] ? ldf(inc + off[t]) : 0.0f;
        #pragma unroll
        for (int k = 0; k < COB; ++k) {
            const float* wk = wb + ((size_t)k * CIN + ci) * 9;
            #pragma unroll
            for (int t = 0; t < 9; ++t)
                acc[k] = fmaf(v[t], wk[t], acc[k]);
        }
    }

    #pragma unroll
    for (int k = 0; k < COB; ++k) {
        float r = acc[k];
        if (ACT == 1) r = geluf(r);
        if (ACT == 2) r = fmaxf(r, 0.0f);
        size_t oidx = ((size_t)(blockIdx.z * COB + k) * HH + hy) * WW + wx;
        out[oidx] = r;
    }
}

// Branch conv (64->64, 3x3, pad 1) on the compact 96x96 grid only.
__global__ __launch_bounds__(256) void branch_conv_kernel(
    const float* __restrict__ feat, const float* __restrict__ ddct_w,
    const float* __restrict__ ddct_b, float* __restrict__ ycomp)
{
    const int c_comp = blockIdx.x * 32 + threadIdx.x;
    const int r_comp = blockIdx.y * 8 + threadIdx.y;
    int z = blockIdx.z;
    const int li = z / (BB * 8);
    z -= li * (BB * 8);
    const int b  = z / 8;
    const int co = (z - b * 8) * 8;

    const int C = dec96(c_comp);
    const int R = dec96(r_comp);

    float acc[8];
    #pragma unroll
    for (int k = 0; k < 8; ++k) acc[k] = ddct_b[li * 64 + co + k];

    bool ok[9];
    int off[9];
    #pragma unroll
    for (int ky = 0; ky < 3; ++ky) {
        const int iy = R + ky - 1;
        const bool oky = (unsigned)iy < (unsigned)HH;
        #pragma unroll
        for (int kx = 0; kx < 3; ++kx) {
            const int ix = C + kx - 1;
            ok[ky*3+kx]  = oky && ((unsigned)ix < (unsigned)WW);
            off[ky*3+kx] = iy * WW + ix;
        }
    }

    const float* inb = feat + (size_t)b * 64 * HW;
    const float* wb  = ddct_w + (size_t)li * 64 * 64 * 9 + (size_t)co * 64 * 9;

    #pragma unroll 1
    for (int ci = 0; ci < 64; ++ci) {
        const float* inc = inb + (size_t)ci * HW;
        float v[9];
        #pragma unroll
        for (int t = 0; t < 9; ++t)
            v[t] = ok[t] ? inc[off[t]] : 0.0f;
        #pragma unroll
        for (int k = 0; k < 8; ++k) {
            const float* wk = wb + ((size_t)k * 64 + ci) * 9;
            #pragma unroll
            for (int t = 0; t < 9; ++t)
                acc[k] = fmaf(v[t], wk[t], acc[k]);
        }
    }

    #pragma unroll
    for (int k = 0; k < 8; ++k) {
        float r = geluf(acc[k]) + feat[(((size_t)b * 64 + co + k) * HH + R) * WW + C];
        ycomp[((((size_t)li * BB + b) * 64 + co + k) * 96 + r_comp) * 96 + c_comp] = r;
    }
}

// Depthwise 3x3 stride 8 dil 2 pad 2 -> 32x32 (DCT->IDCT identity skipped).
__global__ __launch_bounds__(256) void dctc_kernel(
    const float* __restrict__ ycomp, const float* __restrict__ dctc_w,
    const float* __restrict__ dctc_b, float* __restrict__ s_all)
{
    const int idx = blockIdx.x * 256 + threadIdx.x;
    if (idx >= 7 * BB * 64 * 32 * 32) return;
    const int ow = idx & 31;
    const int oh = (idx >> 5) & 31;
    const int c  = (idx >> 10) & 63;
    const int b  = (idx >> 16) & (BB - 1);
    const int li = idx >> 17;

    const float* yc = ycomp + (((size_t)li * BB + b) * 64 + c) * (96 * 96);
    const float* w  = dctc_w + (li * 64 + c) * 9;
    float acc = dctc_b[li * 64 + c];
    #pragma unroll
    for (int ky = 0; ky < 3; ++ky) {
        const int cr = 3 * oh + ky - 1;
        if (cr < 0) continue;
        #pragma unroll
        for (int kx = 0; kx < 3; ++kx) {
            const int cc = 3 * ow + kx - 1;
            if (cc < 0) continue;
            acc = fmaf(yc[cr * 96 + cc], w[ky * 3 + kx], acc);
        }
    }
    s_all[idx] = acc;
}

// Gate + bilinear upsample + multiply, writing gated in NHWC bf16.
// Block = 32-px x-strip; thread = channel pair. relu1 tile staged in LDS once
// (was: 1024 stride-HW scalar global loads per thread, 256x redundant per block).
__global__ __launch_bounds__(256) void gated_nhwc_kernel(
    const float* __restrict__ relu1, const float* __restrict__ dw3_w,
    const float* __restrict__ dw3_b, const float* __restrict__ s_all,
    ushort* __restrict__ gt)
{
    __shared__ float sm[32][32];   // [k][px]
    const int pix0 = blockIdx.x * 32;
    const int b  = pix0 >> 16;
    const int y  = (pix0 >> 8) & 255;
    const int x0 = pix0 & 255;

    // cooperative stage: 4 coalesced 128B rows per 8-thread k-group
    {
        const int spx = threadIdx.x & 31;
        const int k0  = threadIdx.x >> 5;        // 0..7
        const float* rbase = relu1 + (size_t)b * 32 * HW + (size_t)y * WW + x0 + spx;
        #pragma unroll
        for (int i = 0; i < 4; ++i)
            sm[k0 + 8 * i][spx] = rbase[(size_t)(k0 + 8 * i) * HW];
    }
    __syncthreads();

    const int ch0 = threadIdx.x * 2;
    const int branch = ch0 >> 6;
    const int c0 = ch0 & 63;
    const int lmap[8] = {0, 1, 2, 3, 4, 3, 5, 6};
    const int li = lmap[branch];

    float w0[32], w1[32];
    const float* wp0 = dw3_w + ch0 * 32;
    #pragma unroll
    for (int k = 0; k < 32; ++k) { w0[k] = wp0[k]; w1[k] = wp0[32 + k]; }
    const float bb0 = dw3_b[ch0], bb1 = dw3_b[ch0 + 1];

    const float* sp0 = s_all + (((size_t)li * BB + b) * 64 + c0) * 1024;
    const float* sp1 = sp0 + 1024;

    const float sy = (y + 0.5f) * 0.125f - 0.5f;
    const float fy0f = floorf(sy);
    const float fy = sy - fy0f;
    int y0 = (int)fy0f;
    const int y1 = min(y0 + 1, 31);
    y0 = max(y0, 0);

    #pragma unroll 1
    for (int px = 0; px < 32; ++px) {
        const int x = x0 + px;
        float a0 = bb0, a1 = bb1;
        #pragma unroll
        for (int k = 0; k < 32; ++k) {
            const float r = sm[k][px];           // wave-uniform LDS broadcast
            a0 = fmaf(r, w0[k], a0);
            a1 = fmaf(r, w1[k], a1);
        }
        const float g0 = 1.0f / (1.0f + expf(-a0));
        const float g1 = 1.0f / (1.0f + expf(-a1));

        const float sx = (x + 0.5f) * 0.125f - 0.5f;
        const float fx0f = floorf(sx);
        const float fx = sx - fx0f;
        int x0i = (int)fx0f;
        const int x1i = min(x0i + 1, 31);
        x0i = max(x0i, 0);

        float v00 = sp0[y0*32+x0i], v01 = sp0[y0*32+x1i];
        float v10 = sp0[y1*32+x0i], v11 = sp0[y1*32+x1i];
        const float va = (1.f-fy)*((1.f-fx)*v00 + fx*v01) + fy*((1.f-fx)*v10 + fx*v11);
        v00 = sp1[y0*32+x0i]; v01 = sp1[y0*32+x1i];
        v10 = sp1[y1*32+x0i]; v11 = sp1[y1*32+x1i];
        const float vb = (1.f-fy)*((1.f-fx)*v00 + fx*v01) + fy*((1.f-fx)*v10 + fx*v11);

        const uint pack = (uint)f2bf(va * g0) | ((uint)f2bf(vb * g1) << 16);
        *reinterpret_cast<uint*>(gt + ((size_t)(pix0 + px)) * 512 + ch0) = pack;
    }
}

// Prepack ar_w into MFMA A-fragment order (bf16):
// wpack[((t*16+cb)*5+mf)*512 + lane*8 + j] = W[co = mf*16+(lane&15)][ci = cb*32+(lane>>4)*8+j][tap t]
__global__ __launch_bounds__(256) void prepack_w_kernel(
    const float* __restrict__ ar_w, ushort* __restrict__ wpack)
{
    const int idx = blockIdx.x * 256 + threadIdx.x;   // 9*16*5*64 = 46080
    if (idx >= 9 * 16 * 5 * 64) return;
    const int lane = idx & 63;
    int rest = idx >> 6;
    const int mf = rest % 5; rest /= 5;
    const int cb = rest & 15;
    const int t  = rest >> 4;
    const int co  = mf * 16 + (lane & 15);
    const int ci0 = cb * 32 + (lane >> 4) * 8;
    ushort* dst = wpack + (size_t)idx * 8;
    #pragma unroll
    for (int j = 0; j < 8; ++j) {
        const float w = (co < 72) ? ar_w[((size_t)co * 512 + ci0 + j) * 9 + t] : 0.0f;
        dst[j] = f2bf(w);
    }
}

// Final conv 512->72 as implicit GEMM on MFMA.
// A = weights [m=co 80pad][K], B = gated NHWC [K][n=pixels]. K = tap-major, 32 ci per step.
// Workgroup: 4 waves, 128 px; wave: 80co x 32px = acc[5 mf][2 nf] f32x4.
__global__ __launch_bounds__(256) void conv_ar_mfma_kernel(
    const ushort* __restrict__ gt, const ushort* __restrict__ wpack,
    const float* __restrict__ ar_b, float* __restrict__ out)
{
    const int lane = threadIdx.x & 63;
    const int wave = threadIdx.x >> 6;
    const int l15  = lane & 15;
    const int lg   = lane >> 4;

    const int bid  = blockIdx.x;          // 1024 = b(2) * y(256) * xt(2)
    const int b    = bid >> 9;
    const int rest = bid & 511;
    const int y    = rest >> 1;
    const int x0   = (rest & 1) * 128 + wave * 32;

    f32x4 acc[5][2];
    #pragma unroll
    for (int mf = 0; mf < 5; ++mf)
        #pragma unroll
        for (int nf = 0; nf < 2; ++nf)
            acc[mf][nf] = (f32x4){0.f, 0.f, 0.f, 0.f};

    const bf16x8 zero8 = {};

    #pragma unroll 1
    for (int t = 0; t < 9; ++t) {
        const int dy = t / 3 - 1, dx = t % 3 - 1;
        const int yy = y + dy;
        if ((unsigned)yy >= (unsigned)HH) continue;

        const int xA = x0 + l15 + dx;
        const int xB = xA + 16;
        const bool va = (unsigned)xA < (unsigned)WW;
        const bool vb = (unsigned)xB < (unsigned)WW;
        const int xAc = min(max(xA, 0), WW - 1);
        const int xBc = min(xB, WW - 1);

        const ushort* rowbase = gt + ((size_t)(b * HH + yy) * WW) * 512;
        const ushort* pA = rowbase + (size_t)xAc * 512 + lg * 8;
        const ushort* pB = rowbase + (size_t)xBc * 512 + lg * 8;
        const ushort* wp = wpack + (size_t)t * (16 * 5 * 512) + lane * 8;

        #pragma unroll 2
        for (int cb = 0; cb < 16; ++cb) {
            bf16x8 B0 = *reinterpret_cast<const bf16x8*>(pA + cb * 32);
            bf16x8 B1 = *reinterpret_cast<const bf16x8*>(pB + cb * 32);
            B0 = va ? B0 : zero8;
            B1 = vb ? B1 : zero8;
            const ushort* wpc = wp + (size_t)cb * (5 * 512);
            #pragma unroll
            for (int mf = 0; mf < 5; ++mf) {
                const bf16x8 A = *reinterpret_cast<const bf16x8*>(wpc + mf * 512);
                acc[mf][0] = __builtin_amdgcn_mfma_f32_16x16x32_bf16(A, B0, acc[mf][0], 0, 0, 0);
                acc[mf][1] = __builtin_amdgcn_mfma_f32_16x16x32_bf16(A, B1, acc[mf][1], 0, 0, 0);
            }
        }
    }

    // Epilogue: C[row=co][col=px]: co = mf*16 + lg*4 + r, px = x0 + nf*16 + l15
    #pragma unroll
    for (int mf = 0; mf < 5; ++mf) {
        const int co = mf * 16 + lg * 4;
        if (co >= 72) continue;
        #pragma unroll
        for (int nf = 0; nf < 2; ++nf) {
            const int x = x0 + nf * 16 + l15;
            float* op = out + (((size_t)(b * 72 + co) * HH + y) * WW) + x;
            #pragma unroll
            for (int r = 0; r < 4; ++r)
                op[(size_t)r * HW] = acc[mf][nf][r] + ar_b[co + r];
        }
    }
}

extern "C" void kernel_launch(void* const* d_in, const int* in_sizes, int n_in,
                              void* d_out, int out_size, void* d_ws, size_t ws_size,
                              hipStream_t stream) {
    const float* x      = (const float*)d_in[0];
    const float* conv_w = (const float*)d_in[1];
    const float* conv_b = (const float*)d_in[2];
    const float* ddct_w = (const float*)d_in[3];
    const float* ddct_b = (const float*)d_in[4];
    const float* dctc_w = (const float*)d_in[5];
    const float* dctc_b = (const float*)d_in[6];
    const float* dw1_w  = (const float*)d_in[7];
    const float* dw1_b  = (const float*)d_in[8];
    const float* dw3_w  = (const float*)d_in[9];
    const float* dw3_b  = (const float*)d_in[10];
    const float* ar_w   = (const float*)d_in[11];
    const float* ar_b   = (const float*)d_in[12];
    float* out = (float*)d_out;

    float* ws = (float*)d_ws;
    // gated_t (NHWC bf16): 2*256*256*512 ushort = 33,554,432 float-slots at ws+0.
    // feat/ycomp alias its range (both dead before gated_t is written).
    ushort* gated_t = (ushort*)ws;
    float* feat  = ws;                          // 8,388,608 f
    float* ycomp = ws + 8388608;                // 8,257,536 f (ends 16,646,144 < 33,554,432)
    float* s_all = ws + 33554432;               // 917,504 f
    float* relu1 = ws + 34471936;               // 4,194,304 f
    ushort* wpack = (ushort*)(ws + 38666240);   // 368,640 ushort

    const dim3 blk(32, 8);

    // 0) prepack final-conv weights into MFMA fragment order
    prepack_w_kernel<<<dim3(180), dim3(256), 0, stream>>>(ar_w, wpack);

    // 1) feat = gelu(conv3x3(x))                72 -> 64
    conv3x3_kernel<72, 8, 1, float>
        <<<dim3(8, 32, BB * 8), blk, 0, stream>>>(x, conv_w, conv_b, feat, 8);

    // 2) compact branch convs (7 layers)        64 -> 64
    branch_conv_kernel
        <<<dim3(3, 12, 7 * BB * 8), blk, 0, stream>>>(feat, ddct_w, ddct_b, ycomp);

    // 3) depthwise stride-8 convs
    dctc_kernel<<<dim3((7 * BB * 64 * 32 * 32) / 256), dim3(256), 0, stream>>>(
        ycomp, dctc_w, dctc_b, s_all);

    // 4) relu1 = relu(conv3x3(x))               72 -> 32
    conv3x3_kernel<72, 8, 2, float>
        <<<dim3(8, 32, BB * 4), blk, 0, stream>>>(x, dw1_w, dw1_b, relu1, 4);

    // 5) gated (NHWC bf16) = upsample(s) * sigmoid(1x1conv(relu1))
    gated_nhwc_kernel<<<dim3(BB * HW / 32), dim3(256), 0, stream>>>(
        relu1, dw3_w, dw3_b, s_all, gated_t);

    // 6) out = conv3x3(gated, ar_w)             512 -> 72, MFMA implicit GEMM
    conv_ar_mfma_kernel<<<dim3(BB * HH * 2), dim3(256), 0, stream>>>(
        gated_t, wpack, ar_b, out);
}

// Round 7
// 1231.614 us; speedup vs baseline: 3.8407x; 1.4027x over previous
//
#include <hip/hip_runtime.h>
#include <hip/hip_bf16.h>

#define BB 2
#define HH 256
#define WW 256
#define HW (HH*WW)

typedef __attribute__((ext_vector_type(8))) short bf16x8;
typedef __attribute__((ext_vector_type(4))) float f32x4;

__device__ __forceinline__ float geluf(float x) {
    return 0.5f * x * (1.0f + erff(x * 0.7071067811865475f));
}

__device__ __forceinline__ float ldf(const float* p) { return *p; }
__device__ __forceinline__ float ldf(const __hip_bfloat16* p) { return __bfloat162float(*p); }

__device__ __forceinline__ ushort f2bf(float f) {
    __hip_bfloat16 h = __float2bfloat16(f);
    return *reinterpret_cast<ushort*>(&h);
}

// compact index [0,96) -> actual coordinate (rows/cols = 0,2,6 mod 8)
__device__ __forceinline__ int dec96(int i) {
    int q = i / 3, r = i - q * 3;
    return q * 8 + (r == 0 ? 0 : (r == 1 ? 2 : 6));
}

// Generic 3x3 conv, pad=1, COB output channels per thread. ACT: 0=none,1=gelu,2=relu
template<int CIN, int COB, int ACT, typename TIN>
__global__ __launch_bounds__(256) void conv3x3_kernel(
    const TIN* __restrict__ in, const float* __restrict__ wgt,
    const float* __restrict__ bias, float* __restrict__ out, int coBlocks)
{
    const int wx = blockIdx.x * 32 + threadIdx.x;
    const int hy = blockIdx.y * 8 + threadIdx.y;
    const int co = (blockIdx.z % coBlocks) * COB;
    const int b  = blockIdx.z / coBlocks;

    float acc[COB];
    #pragma unroll
    for (int k = 0; k < COB; ++k) acc[k] = bias[co + k];

    bool ok[9];
    int off[9];
    #pragma unroll
    for (int ky = 0; ky < 3; ++ky) {
        const int iy = hy + ky - 1;
        const bool oky = (unsigned)iy < (unsigned)HH;
        #pragma unroll
        for (int kx = 0; kx < 3; ++kx) {
            const int ix = wx + kx - 1;
            ok[ky*3+kx]  = oky && ((unsigned)ix < (unsigned)WW);
            off[ky*3+kx] = iy * WW + ix;
        }
    }

    const TIN* inb = in + (size_t)b * CIN * HW;
    const float* wb = wgt + (size_t)co * CIN * 9;

    #pragma unroll 1
    for (int ci = 0; ci < CIN; ++ci) {
        const TIN* inc = inb + (size_t)ci * HW;
        float v[9];
        #pragma unroll
        for (int t = 0; t < 9; ++t)
            v[t] = ok[t] ? ldf(inc + off[t]) : 0.0f;
        #pragma unroll
        for (int k = 0; k < COB; ++k) {
            const float* wk = wb + ((size_t)k * CIN + ci) * 9;
            #pragma unroll
            for (int t = 0; t < 9; ++t)
                acc[k] = fmaf(v[t], wk[t], acc[k]);
        }
    }

    #pragma unroll
    for (int k = 0; k < COB; ++k) {
        float r = acc[k];
        if (ACT == 1) r = geluf(r);
        if (ACT == 2) r = fmaxf(r, 0.0f);
        size_t oidx = ((size_t)(blockIdx.z * COB + k) * HH + hy) * WW + wx;
        out[oidx] = r;
    }
}

// Branch conv (64->64, 3x3, pad 1) on the compact 96x96 grid only.
__global__ __launch_bounds__(256) void branch_conv_kernel(
    const float* __restrict__ feat, const float* __restrict__ ddct_w,
    const float* __restrict__ ddct_b, float* __restrict__ ycomp)
{
    const int c_comp = blockIdx.x * 32 + threadIdx.x;
    const int r_comp = blockIdx.y * 8 + threadIdx.y;
    int z = blockIdx.z;
    const int li = z / (BB * 8);
    z -= li * (BB * 8);
    const int b  = z / 8;
    const int co = (z - b * 8) * 8;

    const int C = dec96(c_comp);
    const int R = dec96(r_comp);

    float acc[8];
    #pragma unroll
    for (int k = 0; k < 8; ++k) acc[k] = ddct_b[li * 64 + co + k];

    bool ok[9];
    int off[9];
    #pragma unroll
    for (int ky = 0; ky < 3; ++ky) {
        const int iy = R + ky - 1;
        const bool oky = (unsigned)iy < (unsigned)HH;
        #pragma unroll
        for (int kx = 0; kx < 3; ++kx) {
            const int ix = C + kx - 1;
            ok[ky*3+kx]  = oky && ((unsigned)ix < (unsigned)WW);
            off[ky*3+kx] = iy * WW + ix;
        }
    }

    const float* inb = feat + (size_t)b * 64 * HW;
    const float* wb  = ddct_w + (size_t)li * 64 * 64 * 9 + (size_t)co * 64 * 9;

    #pragma unroll 1
    for (int ci = 0; ci < 64; ++ci) {
        const float* inc = inb + (size_t)ci * HW;
        float v[9];
        #pragma unroll
        for (int t = 0; t < 9; ++t)
            v[t] = ok[t] ? inc[off[t]] : 0.0f;
        #pragma unroll
        for (int k = 0; k < 8; ++k) {
            const float* wk = wb + ((size_t)k * 64 + ci) * 9;
            #pragma unroll
            for (int t = 0; t < 9; ++t)
                acc[k] = fmaf(v[t], wk[t], acc[k]);
        }
    }

    #pragma unroll
    for (int k = 0; k < 8; ++k) {
        float r = geluf(acc[k]) + feat[(((size_t)b * 64 + co + k) * HH + R) * WW + C];
        ycomp[((((size_t)li * BB + b) * 64 + co + k) * 96 + r_comp) * 96 + c_comp] = r;
    }
}

// Depthwise 3x3 stride 8 dil 2 pad 2 -> 32x32 (DCT->IDCT identity skipped).
__global__ __launch_bounds__(256) void dctc_kernel(
    const float* __restrict__ ycomp, const float* __restrict__ dctc_w,
    const float* __restrict__ dctc_b, float* __restrict__ s_all)
{
    const int idx = blockIdx.x * 256 + threadIdx.x;
    if (idx >= 7 * BB * 64 * 32 * 32) return;
    const int ow = idx & 31;
    const int oh = (idx >> 5) & 31;
    const int c  = (idx >> 10) & 63;
    const int b  = (idx >> 16) & (BB - 1);
    const int li = idx >> 17;

    const float* yc = ycomp + (((size_t)li * BB + b) * 64 + c) * (96 * 96);
    const float* w  = dctc_w + (li * 64 + c) * 9;
    float acc = dctc_b[li * 64 + c];
    #pragma unroll
    for (int ky = 0; ky < 3; ++ky) {
        const int cr = 3 * oh + ky - 1;
        if (cr < 0) continue;
        #pragma unroll
        for (int kx = 0; kx < 3; ++kx) {
            const int cc = 3 * ow + kx - 1;
            if (cc < 0) continue;
            acc = fmaf(yc[cr * 96 + cc], w[ky * 3 + kx], acc);
        }
    }
    s_all[idx] = acc;
}

// Gate + bilinear upsample + multiply, writing gated in NHWC bf16.
// Block = 32-px x-strip; thread = channel pair.
// v2 fixes (round-6 post-mortem): (a) bilinear s_all gathers hoisted out of
// the px loop — a 32-px strip touches only 6 x-nodes; pre-blend in y ->
// 24 gathers total instead of 256 lane-divergent ones inside the loop.
// (b) conv loop restructured k-outer/px-inner with per-px register
// accumulators and float4 LDS row reads: 1024 ds_read_b32 -> 256 ds_read_b128.
// (c) px loop fully unrolled; 8x upsample makes cell index/fraction
// compile-time: j=(px+4)>>3, fx=((px+4)&7)/8+1/16 (exact sixteenths).
__global__ __launch_bounds__(256) void gated_nhwc_kernel(
    const float* __restrict__ relu1, const float* __restrict__ dw3_w,
    const float* __restrict__ dw3_b, const float* __restrict__ s_all,
    ushort* __restrict__ gt)
{
    __shared__ float sm[32][32];   // [k][px]
    const int pix0 = blockIdx.x * 32;
    const int b  = pix0 >> 16;
    const int y  = (pix0 >> 8) & 255;
    const int x0 = pix0 & 255;

    // cooperative stage: coalesced 128B rows
    {
        const int spx = threadIdx.x & 31;
        const int k0  = threadIdx.x >> 5;        // 0..7
        const float* rbase = relu1 + (size_t)b * 32 * HW + (size_t)y * WW + x0 + spx;
        #pragma unroll
        for (int i = 0; i < 4; ++i)
            sm[k0 + 8 * i][spx] = rbase[(size_t)(k0 + 8 * i) * HW];
    }
    __syncthreads();

    const int ch0 = threadIdx.x * 2;
    const int branch = ch0 >> 6;
    const int c0 = ch0 & 63;
    const int lmap[8] = {0, 1, 2, 3, 4, 3, 5, 6};
    const int li = lmap[branch];

    const float bb0 = dw3_b[ch0], bb1 = dw3_b[ch0 + 1];

    // 1x1 conv: k-outer, per-px register accumulators, float4 LDS rows.
    float acc0[32], acc1[32];
    #pragma unroll
    for (int px = 0; px < 32; ++px) { acc0[px] = bb0; acc1[px] = bb1; }

    const float* wp0 = dw3_w + ch0 * 32;
    #pragma unroll
    for (int k = 0; k < 32; ++k) {
        const float w0k = wp0[k];
        const float w1k = wp0[32 + k];
        const float4* row = reinterpret_cast<const float4*>(&sm[k][0]);
        #pragma unroll
        for (int q = 0; q < 8; ++q) {
            const float4 r4 = row[q];
            acc0[q*4+0] = fmaf(r4.x, w0k, acc0[q*4+0]);
            acc0[q*4+1] = fmaf(r4.y, w0k, acc0[q*4+1]);
            acc0[q*4+2] = fmaf(r4.z, w0k, acc0[q*4+2]);
            acc0[q*4+3] = fmaf(r4.w, w0k, acc0[q*4+3]);
            acc1[q*4+0] = fmaf(r4.x, w1k, acc1[q*4+0]);
            acc1[q*4+1] = fmaf(r4.y, w1k, acc1[q*4+1]);
            acc1[q*4+2] = fmaf(r4.z, w1k, acc1[q*4+2]);
            acc1[q*4+3] = fmaf(r4.w, w1k, acc1[q*4+3]);
        }
    }

    // hoisted bilinear nodes: 6 x-positions, pre-blended in y.
    const float* sp0 = s_all + (((size_t)li * BB + b) * 64 + c0) * 1024;
    const float* sp1 = sp0 + 1024;

    const float sy = (y + 0.5f) * 0.125f - 0.5f;
    const float fy0f = floorf(sy);
    const float fy = sy - fy0f;
    int y0 = (int)fy0f;
    const int y1 = min(y0 + 1, 31);
    y0 = max(y0, 0);

    float n0[6], n1[6];
    const int xb = (x0 >> 3) - 1;
    #pragma unroll
    for (int jj = 0; jj < 6; ++jj) {
        const int xn = min(max(xb + jj, 0), 31);
        const float a00 = sp0[y0 * 32 + xn], a01 = sp0[y1 * 32 + xn];
        const float a10 = sp1[y0 * 32 + xn], a11 = sp1[y1 * 32 + xn];
        n0[jj] = a00 + fy * (a01 - a00);
        n1[jj] = a10 + fy * (a11 - a10);
    }

    ushort* gbase = gt + (size_t)pix0 * 512 + ch0;
    #pragma unroll
    for (int px = 0; px < 32; ++px) {
        const int   j  = (px + 4) >> 3;                     // compile-time
        const float fx = (float)((px + 4) & 7) * 0.125f + 0.0625f;
        const float va = n0[j] + fx * (n0[j + 1] - n0[j]);
        const float vb = n1[j] + fx * (n1[j + 1] - n1[j]);
        const float g0 = 1.0f / (1.0f + exp2f(-1.4426950408889634f * acc0[px]));
        const float g1 = 1.0f / (1.0f + exp2f(-1.4426950408889634f * acc1[px]));
        const uint pack = (uint)f2bf(va * g0) | ((uint)f2bf(vb * g1) << 16);
        *reinterpret_cast<uint*>(gbase + (size_t)px * 512) = pack;
    }
}

// Prepack ar_w into MFMA A-fragment order (bf16):
// wpack[((t*16+cb)*5+mf)*512 + lane*8 + j] = W[co = mf*16+(lane&15)][ci = cb*32+(lane>>4)*8+j][tap t]
__global__ __launch_bounds__(256) void prepack_w_kernel(
    const float* __restrict__ ar_w, ushort* __restrict__ wpack)
{
    const int idx = blockIdx.x * 256 + threadIdx.x;   // 9*16*5*64 = 46080
    if (idx >= 9 * 16 * 5 * 64) return;
    const int lane = idx & 63;
    int rest = idx >> 6;
    const int mf = rest % 5; rest /= 5;
    const int cb = rest & 15;
    const int t  = rest >> 4;
    const int co  = mf * 16 + (lane & 15);
    const int ci0 = cb * 32 + (lane >> 4) * 8;
    ushort* dst = wpack + (size_t)idx * 8;
    #pragma unroll
    for (int j = 0; j < 8; ++j) {
        const float w = (co < 72) ? ar_w[((size_t)co * 512 + ci0 + j) * 9 + t] : 0.0f;
        dst[j] = f2bf(w);
    }
}

// Final conv 512->72 as implicit GEMM on MFMA.
// A = weights [m=co 80pad][K], B = gated NHWC [K][n=pixels]. K = tap-major, 32 ci per step.
// Workgroup: 4 waves, 128 px; wave: 80co x 32px = acc[5 mf][2 nf] f32x4.
__global__ __launch_bounds__(256) void conv_ar_mfma_kernel(
    const ushort* __restrict__ gt, const ushort* __restrict__ wpack,
    const float* __restrict__ ar_b, float* __restrict__ out)
{
    const int lane = threadIdx.x & 63;
    const int wave = threadIdx.x >> 6;
    const int l15  = lane & 15;
    const int lg   = lane >> 4;

    const int bid  = blockIdx.x;          // 1024 = b(2) * y(256) * xt(2)
    const int b    = bid >> 9;
    const int rest = bid & 511;
    const int y    = rest >> 1;
    const int x0   = (rest & 1) * 128 + wave * 32;

    f32x4 acc[5][2];
    #pragma unroll
    for (int mf = 0; mf < 5; ++mf)
        #pragma unroll
        for (int nf = 0; nf < 2; ++nf)
            acc[mf][nf] = (f32x4){0.f, 0.f, 0.f, 0.f};

    const bf16x8 zero8 = {};

    #pragma unroll 1
    for (int t = 0; t < 9; ++t) {
        const int dy = t / 3 - 1, dx = t % 3 - 1;
        const int yy = y + dy;
        if ((unsigned)yy >= (unsigned)HH) continue;

        const int xA = x0 + l15 + dx;
        const int xB = xA + 16;
        const bool va = (unsigned)xA < (unsigned)WW;
        const bool vb = (unsigned)xB < (unsigned)WW;
        const int xAc = min(max(xA, 0), WW - 1);
        const int xBc = min(xB, WW - 1);

        const ushort* rowbase = gt + ((size_t)(b * HH + yy) * WW) * 512;
        const ushort* pA = rowbase + (size_t)xAc * 512 + lg * 8;
        const ushort* pB = rowbase + (size_t)xBc * 512 + lg * 8;
        const ushort* wp = wpack + (size_t)t * (16 * 5 * 512) + lane * 8;

        #pragma unroll 2
        for (int cb = 0; cb < 16; ++cb) {
            bf16x8 B0 = *reinterpret_cast<const bf16x8*>(pA + cb * 32);
            bf16x8 B1 = *reinterpret_cast<const bf16x8*>(pB + cb * 32);
            B0 = va ? B0 : zero8;
            B1 = vb ? B1 : zero8;
            const ushort* wpc = wp + (size_t)cb * (5 * 512);
            #pragma unroll
            for (int mf = 0; mf < 5; ++mf) {
                const bf16x8 A = *reinterpret_cast<const bf16x8*>(wpc + mf * 512);
                acc[mf][0] = __builtin_amdgcn_mfma_f32_16x16x32_bf16(A, B0, acc[mf][0], 0, 0, 0);
                acc[mf][1] = __builtin_amdgcn_mfma_f32_16x16x32_bf16(A, B1, acc[mf][1], 0, 0, 0);
            }
        }
    }

    // Epilogue: C[row=co][col=px]: co = mf*16 + lg*4 + r, px = x0 + nf*16 + l15
    #pragma unroll
    for (int mf = 0; mf < 5; ++mf) {
        const int co = mf * 16 + lg * 4;
        if (co >= 72) continue;
        #pragma unroll
        for (int nf = 0; nf < 2; ++nf) {
            const int x = x0 + nf * 16 + l15;
            float* op = out + (((size_t)(b * 72 + co) * HH + y) * WW) + x;
            #pragma unroll
            for (int r = 0; r < 4; ++r)
                op[(size_t)r * HW] = acc[mf][nf][r] + ar_b[co + r];
        }
    }
}

extern "C" void kernel_launch(void* const* d_in, const int* in_sizes, int n_in,
                              void* d_out, int out_size, void* d_ws, size_t ws_size,
                              hipStream_t stream) {
    const float* x      = (const float*)d_in[0];
    const float* conv_w = (const float*)d_in[1];
    const float* conv_b = (const float*)d_in[2];
    const float* ddct_w = (const float*)d_in[3];
    const float* ddct_b = (const float*)d_in[4];
    const float* dctc_w = (const float*)d_in[5];
    const float* dctc_b = (const float*)d_in[6];
    const float* dw1_w  = (const float*)d_in[7];
    const float* dw1_b  = (const float*)d_in[8];
    const float* dw3_w  = (const float*)d_in[9];
    const float* dw3_b  = (const float*)d_in[10];
    const float* ar_w   = (const float*)d_in[11];
    const float* ar_b   = (const float*)d_in[12];
    float* out = (float*)d_out;

    float* ws = (float*)d_ws;
    // gated_t (NHWC bf16): 2*256*256*512 ushort = 33,554,432 float-slots at ws+0.
    // feat/ycomp alias its range (both dead before gated_t is written).
    ushort* gated_t = (ushort*)ws;
    float* feat  = ws;                          // 8,388,608 f
    float* ycomp = ws + 8388608;                // 8,257,536 f (ends 16,646,144 < 33,554,432)
    float* s_all = ws + 33554432;               // 917,504 f
    float* relu1 = ws + 34471936;               // 4,194,304 f
    ushort* wpack = (ushort*)(ws + 38666240);   // 368,640 ushort

    const dim3 blk(32, 8);

    // 0) prepack final-conv weights into MFMA fragment order
    prepack_w_kernel<<<dim3(180), dim3(256), 0, stream>>>(ar_w, wpack);

    // 1) feat = gelu(conv3x3(x))                72 -> 64
    conv3x3_kernel<72, 8, 1, float>
        <<<dim3(8, 32, BB * 8), blk, 0, stream>>>(x, conv_w, conv_b, feat, 8);

    // 2) compact branch convs (7 layers)        64 -> 64
    branch_conv_kernel
        <<<dim3(3, 12, 7 * BB * 8), blk, 0, stream>>>(feat, ddct_w, ddct_b, ycomp);

    // 3) depthwise stride-8 convs
    dctc_kernel<<<dim3((7 * BB * 64 * 32 * 32) / 256), dim3(256), 0, stream>>>(
        ycomp, dctc_w, dctc_b, s_all);

    // 4) relu1 = relu(conv3x3(x))               72 -> 32
    conv3x3_kernel<72, 8, 2, float>
        <<<dim3(8, 32, BB * 4), blk, 0, stream>>>(x, dw1_w, dw1_b, relu1, 4);

    // 5) gated (NHWC bf16) = upsample(s) * sigmoid(1x1conv(relu1))
    gated_nhwc_kernel<<<dim3(BB * HW / 32), dim3(256), 0, stream>>>(
        relu1, dw3_w, dw3_b, s_all, gated_t);

    // 6) out = conv3x3(gated, ar_w)             512 -> 72, MFMA implicit GEMM
    conv_ar_mfma_kernel<<<dim3(BB * HH * 2), dim3(256), 0, stream>>>(
        gated_t, wpack, ar_b, out);
}

// Round 8
// 759.965 us; speedup vs baseline: 6.2244x; 1.6206x over previous
//
#include <hip/hip_runtime.h>
#include <hip/hip_bf16.h>

#define BB 2
#define HH 256
#define WW 256
#define HW (HH*WW)

typedef __attribute__((ext_vector_type(8))) short bf16x8;
typedef __attribute__((ext_vector_type(4))) float f32x4;

__device__ __forceinline__ float geluf(float x) {
    return 0.5f * x * (1.0f + erff(x * 0.7071067811865475f));
}

__device__ __forceinline__ float ldf(const float* p) { return *p; }
__device__ __forceinline__ float ldf(const __hip_bfloat16* p) { return __bfloat162float(*p); }

__device__ __forceinline__ ushort f2bf(float f) {
    __hip_bfloat16 h = __float2bfloat16(f);
    return *reinterpret_cast<ushort*>(&h);
}
__device__ __forceinline__ float bf2f(ushort u) {
    uint v = ((uint)u) << 16;
    return *reinterpret_cast<float*>(&v);
}

// compact index [0,96) -> actual coordinate (rows/cols = 0,2,6 mod 8)
__device__ __forceinline__ int dec96(int i) {
    int q = i / 3, r = i - q * 3;
    return q * 8 + (r == 0 ? 0 : (r == 1 ? 2 : 6));
}

// Generic 3x3 conv, pad=1, COB outputs/thread, NCHW fp32 out. ACT: 0=none,1=gelu,2=relu
template<int CIN, int COB, int ACT, typename TIN>
__global__ __launch_bounds__(256) void conv3x3_kernel(
    const TIN* __restrict__ in, const float* __restrict__ wgt,
    const float* __restrict__ bias, float* __restrict__ out, int coBlocks)
{
    const int wx = blockIdx.x * 32 + threadIdx.x;
    const int hy = blockIdx.y * 8 + threadIdx.y;
    const int co = (blockIdx.z % coBlocks) * COB;
    const int b  = blockIdx.z / coBlocks;

    float acc[COB];
    #pragma unroll
    for (int k = 0; k < COB; ++k) acc[k] = bias[co + k];

    bool ok[9];
    int off[9];
    #pragma unroll
    for (int ky = 0; ky < 3; ++ky) {
        const int iy = hy + ky - 1;
        const bool oky = (unsigned)iy < (unsigned)HH;
        #pragma unroll
        for (int kx = 0; kx < 3; ++kx) {
            const int ix = wx + kx - 1;
            ok[ky*3+kx]  = oky && ((unsigned)ix < (unsigned)WW);
            off[ky*3+kx] = iy * WW + ix;
        }
    }

    const TIN* inb = in + (size_t)b * CIN * HW;
    const float* wb = wgt + (size_t)co * CIN * 9;

    #pragma unroll 1
    for (int ci = 0; ci < CIN; ++ci) {
        const TIN* inc = inb + (size_t)ci * HW;
        float v[9];
        #pragma unroll
        for (int t = 0; t < 9; ++t)
            v[t] = ok[t] ? ldf(inc + off[t]) : 0.0f;
        #pragma unroll
        for (int k = 0; k < COB; ++k) {
            const float* wk = wb + ((size_t)k * CIN + ci) * 9;
            #pragma unroll
            for (int t = 0; t < 9; ++t)
                acc[k] = fmaf(v[t], wk[t], acc[k]);
        }
    }

    #pragma unroll
    for (int k = 0; k < COB; ++k) {
        float r = acc[k];
        if (ACT == 1) r = geluf(r);
        if (ACT == 2) r = fmaxf(r, 0.0f);
        size_t oidx = ((size_t)(blockIdx.z * COB + k) * HH + hy) * WW + wx;
        out[oidx] = r;
    }
}

// conv1 variant: 72 -> 64, gelu, writes feat as NHWC bf16 [B][256][256][64].
__global__ __launch_bounds__(256) void conv1_nhwc_kernel(
    const float* __restrict__ in, const float* __restrict__ wgt,
    const float* __restrict__ bias, ushort* __restrict__ fg)
{
    const int wx = blockIdx.x * 32 + threadIdx.x;
    const int hy = blockIdx.y * 8 + threadIdx.y;
    const int co = (blockIdx.z & 7) * 8;
    const int b  = blockIdx.z >> 3;

    float acc[8];
    #pragma unroll
    for (int k = 0; k < 8; ++k) acc[k] = bias[co + k];

    bool ok[9];
    int off[9];
    #pragma unroll
    for (int ky = 0; ky < 3; ++ky) {
        const int iy = hy + ky - 1;
        const bool oky = (unsigned)iy < (unsigned)HH;
        #pragma unroll
        for (int kx = 0; kx < 3; ++kx) {
            const int ix = wx + kx - 1;
            ok[ky*3+kx]  = oky && ((unsigned)ix < (unsigned)WW);
            off[ky*3+kx] = iy * WW + ix;
        }
    }

    const float* inb = in + (size_t)b * 72 * HW;
    const float* wb  = wgt + (size_t)co * 72 * 9;

    #pragma unroll 1
    for (int ci = 0; ci < 72; ++ci) {
        const float* inc = inb + (size_t)ci * HW;
        float v[9];
        #pragma unroll
        for (int t = 0; t < 9; ++t)
            v[t] = ok[t] ? inc[off[t]] : 0.0f;
        #pragma unroll
        for (int k = 0; k < 8; ++k) {
            const float* wk = wb + ((size_t)k * 72 + ci) * 9;
            #pragma unroll
            for (int t = 0; t < 9; ++t)
                acc[k] = fmaf(v[t], wk[t], acc[k]);
        }
    }

    ushort pk[8];
    #pragma unroll
    for (int k = 0; k < 8; ++k) pk[k] = f2bf(geluf(acc[k]));
    *reinterpret_cast<uint4*>(fg + ((size_t)(b * HH + hy) * WW + wx) * 64 + co) =
        *reinterpret_cast<uint4*>(pk);
}

// Prepack ddct weights (7 layers) into MFMA A-fragment order:
// wpb[((li*9+t)*2+cb)*4+mf][lane*8+j] = Wl[co=mf*16+(lane&15)][ci=cb*32+(lane>>4)*8+j][t]
__global__ __launch_bounds__(256) void prepack_wb_kernel(
    const float* __restrict__ ddct_w, ushort* __restrict__ wpb)
{
    const int idx = blockIdx.x * 256 + threadIdx.x;   // 7*9*2*4*64 = 32256
    if (idx >= 7 * 9 * 2 * 4 * 64) return;
    const int lane = idx & 63;
    int rest = idx >> 6;
    const int mf = rest & 3; rest >>= 2;
    const int cb = rest & 1; rest >>= 1;
    const int t  = rest % 9;
    const int li = rest / 9;
    const int co  = mf * 16 + (lane & 15);
    const int ci0 = cb * 32 + (lane >> 4) * 8;
    ushort* dst = wpb + (size_t)idx * 8;
    #pragma unroll
    for (int j = 0; j < 8; ++j)
        dst[j] = f2bf(ddct_w[(((size_t)li * 64 + co) * 64 + ci0 + j) * 9 + t]);
}

// All 7 branch convs (64->64, 3x3, pad 1) on the compact 96x96 grid as MFMA
// implicit GEMM over NHWC bf16 feat. Epilogue fuses gelu + residual.
// Wave: 64co x 32px (acc[4 mf][2 nf]); block: 4 waves; grid: (li,b) x 72.
__global__ __launch_bounds__(256) void branch_mfma_kernel(
    const ushort* __restrict__ fg,     // [B][256][256][64] bf16
    const ushort* __restrict__ wpb,    // prepacked A-frags
    const float* __restrict__ ddct_b,  // [7][64]
    float* __restrict__ ycomp)         // [7][B][64][96][96]
{
    const int lane = threadIdx.x & 63;
    const int wave = threadIdx.x >> 6;
    const int l15  = lane & 15;
    const int lg   = lane >> 4;

    int bid = blockIdx.x;              // (li*BB+b)*72 + t72
    const int t72 = bid % 72; bid /= 72;
    const int b  = bid & 1;
    const int li = bid >> 1;
    const int widx = t72 * 4 + wave;   // 0..287
    const int r  = widx / 3;
    const int c0 = (widx - r * 3) * 32;
    const int R  = dec96(r);

    const int cA = c0 + l15, cB = cA + 16;
    const int CA = dec96(cA), CB2 = dec96(cB);

    f32x4 acc[4][2];
    #pragma unroll
    for (int mf = 0; mf < 4; ++mf)
        #pragma unroll
        for (int nf = 0; nf < 2; ++nf)
            acc[mf][nf] = (f32x4){0.f, 0.f, 0.f, 0.f};

    const bf16x8 zero8 = {};
    const ushort* fgb = fg + (size_t)b * HW * 64;

    #pragma unroll 1
    for (int t = 0; t < 9; ++t) {
        const int dy = t / 3 - 1, dx = t % 3 - 1;
        const int yy = R + dy;
        if ((unsigned)yy >= (unsigned)HH) continue;

        const int xA = CA + dx, xB = CB2 + dx;
        const bool va = (unsigned)xA < (unsigned)WW;
        const bool vb = (unsigned)xB < (unsigned)WW;
        const int xAc = min(max(xA, 0), WW - 1);
        const int xBc = min(max(xB, 0), WW - 1);

        const ushort* rowb = fgb + (size_t)yy * WW * 64;
        const ushort* pA = rowb + (size_t)xAc * 64 + lg * 8;
        const ushort* pB = rowb + (size_t)xBc * 64 + lg * 8;
        const ushort* wp = wpb + (size_t)((li * 9 + t) * 2) * (4 * 512) + lane * 8;

        #pragma unroll
        for (int cb = 0; cb < 2; ++cb) {
            bf16x8 B0 = *reinterpret_cast<const bf16x8*>(pA + cb * 32);
            bf16x8 B1 = *reinterpret_cast<const bf16x8*>(pB + cb * 32);
            B0 = va ? B0 : zero8;
            B1 = vb ? B1 : zero8;
            const ushort* wpc = wp + (size_t)cb * (4 * 512);
            #pragma unroll
            for (int mf = 0; mf < 4; ++mf) {
                const bf16x8 A = *reinterpret_cast<const bf16x8*>(wpc + mf * 512);
                acc[mf][0] = __builtin_amdgcn_mfma_f32_16x16x32_bf16(A, B0, acc[mf][0], 0, 0, 0);
                acc[mf][1] = __builtin_amdgcn_mfma_f32_16x16x32_bf16(A, B1, acc[mf][1], 0, 0, 0);
            }
        }
    }

    // Epilogue: co = mf*16 + lg*4 + rr, px c = c0 + nf*16 + l15; gelu + residual.
    #pragma unroll
    for (int nf = 0; nf < 2; ++nf) {
        const int c = c0 + nf * 16 + l15;
        const int C = dec96(c);
        const ushort* res = fgb + ((size_t)R * WW + C) * 64;
        #pragma unroll
        for (int mf = 0; mf < 4; ++mf) {
            const int co = mf * 16 + lg * 4;
            ushort r4[4];
            *reinterpret_cast<uint2*>(r4) = *reinterpret_cast<const uint2*>(res + co);
            #pragma unroll
            for (int rr = 0; rr < 4; ++rr) {
                const float v = geluf(acc[mf][nf][rr] + ddct_b[li * 64 + co + rr]) + bf2f(r4[rr]);
                ycomp[((((size_t)li * BB + b) * 64 + co + rr) * 96 + r) * 96 + c] = v;
            }
        }
    }
}

// Depthwise 3x3 stride 8 dil 2 pad 2 -> 32x32 (DCT->IDCT identity skipped).
__global__ __launch_bounds__(256) void dctc_kernel(
    const float* __restrict__ ycomp, const float* __restrict__ dctc_w,
    const float* __restrict__ dctc_b, float* __restrict__ s_all)
{
    const int idx = blockIdx.x * 256 + threadIdx.x;
    if (idx >= 7 * BB * 64 * 32 * 32) return;
    const int ow = idx & 31;
    const int oh = (idx >> 5) & 31;
    const int c  = (idx >> 10) & 63;
    const int b  = (idx >> 16) & (BB - 1);
    const int li = idx >> 17;

    const float* yc = ycomp + (((size_t)li * BB + b) * 64 + c) * (96 * 96);
    const float* w  = dctc_w + (li * 64 + c) * 9;
    float acc = dctc_b[li * 64 + c];
    #pragma unroll
    for (int ky = 0; ky < 3; ++ky) {
        const int cr = 3 * oh + ky - 1;
        if (cr < 0) continue;
        #pragma unroll
        for (int kx = 0; kx < 3; ++kx) {
            const int cc = 3 * ow + kx - 1;
            if (cc < 0) continue;
            acc = fmaf(yc[cr * 96 + cc], w[ky * 3 + kx], acc);
        }
    }
    s_all[idx] = acc;
}

// Gate + bilinear upsample + multiply, writing gated in NHWC bf16.
__global__ __launch_bounds__(256) void gated_nhwc_kernel(
    const float* __restrict__ relu1, const float* __restrict__ dw3_w,
    const float* __restrict__ dw3_b, const float* __restrict__ s_all,
    ushort* __restrict__ gt)
{
    __shared__ float sm[32][32];   // [k][px]
    const int pix0 = blockIdx.x * 32;
    const int b  = pix0 >> 16;
    const int y  = (pix0 >> 8) & 255;
    const int x0 = pix0 & 255;

    {
        const int spx = threadIdx.x & 31;
        const int k0  = threadIdx.x >> 5;
        const float* rbase = relu1 + (size_t)b * 32 * HW + (size_t)y * WW + x0 + spx;
        #pragma unroll
        for (int i = 0; i < 4; ++i)
            sm[k0 + 8 * i][spx] = rbase[(size_t)(k0 + 8 * i) * HW];
    }
    __syncthreads();

    const int ch0 = threadIdx.x * 2;
    const int branch = ch0 >> 6;
    const int c0 = ch0 & 63;
    const int lmap[8] = {0, 1, 2, 3, 4, 3, 5, 6};
    const int li = lmap[branch];

    const float bb0 = dw3_b[ch0], bb1 = dw3_b[ch0 + 1];

    float acc0[32], acc1[32];
    #pragma unroll
    for (int px = 0; px < 32; ++px) { acc0[px] = bb0; acc1[px] = bb1; }

    const float* wp0 = dw3_w + ch0 * 32;
    #pragma unroll
    for (int k = 0; k < 32; ++k) {
        const float w0k = wp0[k];
        const float w1k = wp0[32 + k];
        const float4* row = reinterpret_cast<const float4*>(&sm[k][0]);
        #pragma unroll
        for (int q = 0; q < 8; ++q) {
            const float4 r4 = row[q];
            acc0[q*4+0] = fmaf(r4.x, w0k, acc0[q*4+0]);
            acc0[q*4+1] = fmaf(r4.y, w0k, acc0[q*4+1]);
            acc0[q*4+2] = fmaf(r4.z, w0k, acc0[q*4+2]);
            acc0[q*4+3] = fmaf(r4.w, w0k, acc0[q*4+3]);
            acc1[q*4+0] = fmaf(r4.x, w1k, acc1[q*4+0]);
            acc1[q*4+1] = fmaf(r4.y, w1k, acc1[q*4+1]);
            acc1[q*4+2] = fmaf(r4.z, w1k, acc1[q*4+2]);
            acc1[q*4+3] = fmaf(r4.w, w1k, acc1[q*4+3]);
        }
    }

    const float* sp0 = s_all + (((size_t)li * BB + b) * 64 + c0) * 1024;
    const float* sp1 = sp0 + 1024;

    const float sy = (y + 0.5f) * 0.125f - 0.5f;
    const float fy0f = floorf(sy);
    const float fy = sy - fy0f;
    int y0 = (int)fy0f;
    const int y1 = min(y0 + 1, 31);
    y0 = max(y0, 0);

    float n0[6], n1[6];
    const int xb = (x0 >> 3) - 1;
    #pragma unroll
    for (int jj = 0; jj < 6; ++jj) {
        const int xn = min(max(xb + jj, 0), 31);
        const float a00 = sp0[y0 * 32 + xn], a01 = sp0[y1 * 32 + xn];
        const float a10 = sp1[y0 * 32 + xn], a11 = sp1[y1 * 32 + xn];
        n0[jj] = a00 + fy * (a01 - a00);
        n1[jj] = a10 + fy * (a11 - a10);
    }

    ushort* gbase = gt + (size_t)pix0 * 512 + ch0;
    #pragma unroll
    for (int px = 0; px < 32; ++px) {
        const int   j  = (px + 4) >> 3;
        const float fx = (float)((px + 4) & 7) * 0.125f + 0.0625f;
        const float va = n0[j] + fx * (n0[j + 1] - n0[j]);
        const float vb = n1[j] + fx * (n1[j + 1] - n1[j]);
        const float g0 = 1.0f / (1.0f + exp2f(-1.4426950408889634f * acc0[px]));
        const float g1 = 1.0f / (1.0f + exp2f(-1.4426950408889634f * acc1[px]));
        const uint pack = (uint)f2bf(va * g0) | ((uint)f2bf(vb * g1) << 16);
        *reinterpret_cast<uint*>(gbase + (size_t)px * 512) = pack;
    }
}

// Prepack ar_w into MFMA A-fragment order (bf16).
__global__ __launch_bounds__(256) void prepack_w_kernel(
    const float* __restrict__ ar_w, ushort* __restrict__ wpack)
{
    const int idx = blockIdx.x * 256 + threadIdx.x;   // 9*16*5*64 = 46080
    if (idx >= 9 * 16 * 5 * 64) return;
    const int lane = idx & 63;
    int rest = idx >> 6;
    const int mf = rest % 5; rest /= 5;
    const int cb = rest & 15;
    const int t  = rest >> 4;
    const int co  = mf * 16 + (lane & 15);
    const int ci0 = cb * 32 + (lane >> 4) * 8;
    ushort* dst = wpack + (size_t)idx * 8;
    #pragma unroll
    for (int j = 0; j < 8; ++j) {
        const float w = (co < 72) ? ar_w[((size_t)co * 512 + ci0 + j) * 9 + t] : 0.0f;
        dst[j] = f2bf(w);
    }
}

// Final conv 512->72 as implicit GEMM on MFMA (NHWC bf16 input).
__global__ __launch_bounds__(256) void conv_ar_mfma_kernel(
    const ushort* __restrict__ gt, const ushort* __restrict__ wpack,
    const float* __restrict__ ar_b, float* __restrict__ out)
{
    const int lane = threadIdx.x & 63;
    const int wave = threadIdx.x >> 6;
    const int l15  = lane & 15;
    const int lg   = lane >> 4;

    const int bid  = blockIdx.x;          // 1024 = b(2) * y(256) * xt(2)
    const int b    = bid >> 9;
    const int rest = bid & 511;
    const int y    = rest >> 1;
    const int x0   = (rest & 1) * 128 + wave * 32;

    f32x4 acc[5][2];
    #pragma unroll
    for (int mf = 0; mf < 5; ++mf)
        #pragma unroll
        for (int nf = 0; nf < 2; ++nf)
            acc[mf][nf] = (f32x4){0.f, 0.f, 0.f, 0.f};

    const bf16x8 zero8 = {};

    #pragma unroll 1
    for (int t = 0; t < 9; ++t) {
        const int dy = t / 3 - 1, dx = t % 3 - 1;
        const int yy = y + dy;
        if ((unsigned)yy >= (unsigned)HH) continue;

        const int xA = x0 + l15 + dx;
        const int xB = xA + 16;
        const bool va = (unsigned)xA < (unsigned)WW;
        const bool vb = (unsigned)xB < (unsigned)WW;
        const int xAc = min(max(xA, 0), WW - 1);
        const int xBc = min(xB, WW - 1);

        const ushort* rowbase = gt + ((size_t)(b * HH + yy) * WW) * 512;
        const ushort* pA = rowbase + (size_t)xAc * 512 + lg * 8;
        const ushort* pB = rowbase + (size_t)xBc * 512 + lg * 8;
        const ushort* wp = wpack + (size_t)t * (16 * 5 * 512) + lane * 8;

        #pragma unroll 2
        for (int cb = 0; cb < 16; ++cb) {
            bf16x8 B0 = *reinterpret_cast<const bf16x8*>(pA + cb * 32);
            bf16x8 B1 = *reinterpret_cast<const bf16x8*>(pB + cb * 32);
            B0 = va ? B0 : zero8;
            B1 = vb ? B1 : zero8;
            const ushort* wpc = wp + (size_t)cb * (5 * 512);
            #pragma unroll
            for (int mf = 0; mf < 5; ++mf) {
                const bf16x8 A = *reinterpret_cast<const bf16x8*>(wpc + mf * 512);
                acc[mf][0] = __builtin_amdgcn_mfma_f32_16x16x32_bf16(A, B0, acc[mf][0], 0, 0, 0);
                acc[mf][1] = __builtin_amdgcn_mfma_f32_16x16x32_bf16(A, B1, acc[mf][1], 0, 0, 0);
            }
        }
    }

    #pragma unroll
    for (int mf = 0; mf < 5; ++mf) {
        const int co = mf * 16 + lg * 4;
        if (co >= 72) continue;
        #pragma unroll
        for (int nf = 0; nf < 2; ++nf) {
            const int x = x0 + nf * 16 + l15;
            float* op = out + (((size_t)(b * 72 + co) * HH + y) * WW) + x;
            #pragma unroll
            for (int r = 0; r < 4; ++r)
                op[(size_t)r * HW] = acc[mf][nf][r] + ar_b[co + r];
        }
    }
}

extern "C" void kernel_launch(void* const* d_in, const int* in_sizes, int n_in,
                              void* d_out, int out_size, void* d_ws, size_t ws_size,
                              hipStream_t stream) {
    const float* x      = (const float*)d_in[0];
    const float* conv_w = (const float*)d_in[1];
    const float* conv_b = (const float*)d_in[2];
    const float* ddct_w = (const float*)d_in[3];
    const float* ddct_b = (const float*)d_in[4];
    const float* dctc_w = (const float*)d_in[5];
    const float* dctc_b = (const float*)d_in[6];
    const float* dw1_w  = (const float*)d_in[7];
    const float* dw1_b  = (const float*)d_in[8];
    const float* dw3_w  = (const float*)d_in[9];
    const float* dw3_b  = (const float*)d_in[10];
    const float* ar_w   = (const float*)d_in[11];
    const float* ar_b   = (const float*)d_in[12];
    float* out = (float*)d_out;

    float* ws = (float*)d_ws;
    // Layout (float slots). fg + ycomp are dead before gated_t is written
    // (gated_t spans [0 .. 33,554,432) and aliases them).
    ushort* gated_t = (ushort*)ws;
    ushort* fg    = (ushort*)ws;                 // 8,388,608 us = [0 .. 4,194,304) f
    float* ycomp  = ws + 4194304;                // 8,257,536 f -> ends 12,451,840
    float* s_all  = ws + 33554432;               // 917,504 f
    float* relu1  = ws + 34471936;               // 4,194,304 f
    ushort* wpack = (ushort*)(ws + 38666240);    // 368,640 us = 184,320 f -> ends 38,850,560
    ushort* wpb   = (ushort*)(ws + 38850560);    // 258,048 us = 129,024 f -> ends 38,979,584

    const dim3 blk(32, 8);

    // 0) weight prepacks
    prepack_w_kernel<<<dim3(180), dim3(256), 0, stream>>>(ar_w, wpack);
    prepack_wb_kernel<<<dim3(126), dim3(256), 0, stream>>>(ddct_w, wpb);

    // 1) feat (NHWC bf16) = gelu(conv3x3(x))    72 -> 64
    conv1_nhwc_kernel<<<dim3(8, 32, BB * 8), blk, 0, stream>>>(x, conv_w, conv_b, fg);

    // 2) branch convs (7 layers) as MFMA implicit GEMM on compact grid
    branch_mfma_kernel<<<dim3(7 * BB * 72), dim3(256), 0, stream>>>(
        fg, wpb, ddct_b, ycomp);

    // 3) depthwise stride-8 convs
    dctc_kernel<<<dim3((7 * BB * 64 * 32 * 32) / 256), dim3(256), 0, stream>>>(
        ycomp, dctc_w, dctc_b, s_all);

    // 4) relu1 = relu(conv3x3(x))               72 -> 32
    conv3x3_kernel<72, 8, 2, float>
        <<<dim3(8, 32, BB * 4), blk, 0, stream>>>(x, dw1_w, dw1_b, relu1, 4);

    // 5) gated (NHWC bf16) = upsample(s) * sigmoid(1x1conv(relu1))
    gated_nhwc_kernel<<<dim3(BB * HW / 32), dim3(256), 0, stream>>>(
        relu1, dw3_w, dw3_b, s_all, gated_t);

    // 6) out = conv3x3(gated, ar_w)             512 -> 72, MFMA implicit GEMM
    conv_ar_mfma_kernel<<<dim3(BB * HH * 2), dim3(256), 0, stream>>>(
        gated_t, wpack, ar_b, out);
}

// Round 9
// 490.523 us; speedup vs baseline: 9.6434x; 1.5493x over previous
//
#include <hip/hip_runtime.h>
#include <hip/hip_bf16.h>

#define BB 2
#define HH 256
#define WW 256
#define HW (HH*WW)

typedef __attribute__((ext_vector_type(8))) short bf16x8;
typedef __attribute__((ext_vector_type(4))) float f32x4;

__device__ __forceinline__ float geluf(float x) {
    return 0.5f * x * (1.0f + erff(x * 0.7071067811865475f));
}

__device__ __forceinline__ ushort f2bf(float f) {
    __hip_bfloat16 h = __float2bfloat16(f);
    return *reinterpret_cast<ushort*>(&h);
}
__device__ __forceinline__ float bf2f(ushort u) {
    uint v = ((uint)u) << 16;
    return *reinterpret_cast<float*>(&v);
}

// compact index [0,96) -> actual coordinate (rows/cols = 0,2,6 mod 8)
__device__ __forceinline__ int dec96(int i) {
    int q = i / 3, r = i - q * 3;
    return q * 8 + (r == 0 ? 0 : (r == 1 ? 2 : 6));
}

// x (NCHW fp32, 72ch) -> xt (NHWC bf16, 96ch zero-padded). Coalesced reads
// per channel; 96B contiguous write per thread.
__global__ __launch_bounds__(256) void xpose_kernel(
    const float* __restrict__ x, ushort* __restrict__ xt)
{
    const int pix = blockIdx.x * 256 + threadIdx.x;   // [0, BB*HW)
    const int b   = pix >> 16;
    const int rem = pix & 65535;

    uint w[48];
    const float* xb = x + (size_t)b * 72 * HW + rem;
    #pragma unroll
    for (int i = 0; i < 36; ++i) {
        const ushort lo = f2bf(xb[(size_t)(2 * i)     * HW]);
        const ushort hi = f2bf(xb[(size_t)(2 * i + 1) * HW]);
        w[i] = (uint)lo | ((uint)hi << 16);
    }
    #pragma unroll
    for (int i = 36; i < 48; ++i) w[i] = 0;

    uint* dst = reinterpret_cast<uint*>(xt + (size_t)pix * 96);
    #pragma unroll
    for (int k = 0; k < 12; ++k) {
        uint4 u = { w[4*k], w[4*k+1], w[4*k+2], w[4*k+3] };
        *reinterpret_cast<uint4*>(dst + 4 * k) = u;
    }
}

// Prepack fused conv1(64co)+dw1(32co) weights into MFMA A-frag order:
// wpc1[((t*3+cb)*6+mf)*512 + lane*8 + j]; co=mf*16+(lane&15), ci=cb*32+(lane>>4)*8+j
__global__ __launch_bounds__(256) void prepack_w1_kernel(
    const float* __restrict__ conv_w, const float* __restrict__ dw1_w,
    ushort* __restrict__ wpc1)
{
    const int idx = blockIdx.x * 256 + threadIdx.x;   // 9*3*6*64 = 10368
    if (idx >= 9 * 3 * 6 * 64) return;
    const int lane = idx & 63;
    int rest = idx >> 6;
    const int mf = rest % 6; rest /= 6;
    const int cb = rest % 3;
    const int t  = rest / 3;
    const int co  = mf * 16 + (lane & 15);
    const int ci0 = cb * 32 + (lane >> 4) * 8;
    ushort* dst = wpc1 + (size_t)idx * 8;
    #pragma unroll
    for (int j = 0; j < 8; ++j) {
        const int ci = ci0 + j;
        float w = 0.0f;
        if (ci < 72)
            w = (co < 64) ? conv_w[((size_t)co * 72 + ci) * 9 + t]
                          : dw1_w[((size_t)(co - 64) * 72 + ci) * 9 + t];
        dst[j] = f2bf(w);
    }
}

// Fused conv1+dw1 as MFMA implicit GEMM (M=96, K=9*96) over xt.
// mf 0..3 -> fg (NHWC bf16, gelu); mf 4..5 -> relu1 (NCHW fp32, relu).
__global__ __launch_bounds__(256) void conv1dw1_mfma_kernel(
    const ushort* __restrict__ xt, const ushort* __restrict__ wpc1,
    const float* __restrict__ conv_b, const float* __restrict__ dw1_b,
    ushort* __restrict__ fg, float* __restrict__ relu1)
{
    const int lane = threadIdx.x & 63;
    const int wave = threadIdx.x >> 6;
    const int l15  = lane & 15;
    const int lg   = lane >> 4;

    const int bid  = blockIdx.x;          // 1024 = b(2) * y(256) * half(2)
    const int b    = bid >> 9;
    const int rest = bid & 511;
    const int y    = rest >> 1;
    const int x0   = (rest & 1) * 128 + wave * 32;

    f32x4 acc[6][2];
    #pragma unroll
    for (int mf = 0; mf < 6; ++mf)
        #pragma unroll
        for (int nf = 0; nf < 2; ++nf)
            acc[mf][nf] = (f32x4){0.f, 0.f, 0.f, 0.f};

    const bf16x8 zero8 = {};

    #pragma unroll 1
    for (int t = 0; t < 9; ++t) {
        const int dy = t / 3 - 1, dx = t % 3 - 1;
        const int yy = y + dy;
        if ((unsigned)yy >= (unsigned)HH) continue;

        const int xA = x0 + l15 + dx;
        const int xB = xA + 16;
        const bool va = (unsigned)xA < (unsigned)WW;
        const bool vb = (unsigned)xB < (unsigned)WW;
        const int xAc = min(max(xA, 0), WW - 1);
        const int xBc = min(xB, WW - 1);

        const ushort* rowbase = xt + ((size_t)(b * HH + yy) * WW) * 96;
        const ushort* pA = rowbase + (size_t)xAc * 96 + lg * 8;
        const ushort* pB = rowbase + (size_t)xBc * 96 + lg * 8;
        const ushort* wp = wpc1 + (size_t)(t * 3) * (6 * 512) + lane * 8;

        #pragma unroll
        for (int cb = 0; cb < 3; ++cb) {
            bf16x8 B0 = *reinterpret_cast<const bf16x8*>(pA + cb * 32);
            bf16x8 B1 = *reinterpret_cast<const bf16x8*>(pB + cb * 32);
            B0 = va ? B0 : zero8;
            B1 = vb ? B1 : zero8;
            const ushort* wpc = wp + (size_t)cb * (6 * 512);
            #pragma unroll
            for (int mf = 0; mf < 6; ++mf) {
                const bf16x8 A = *reinterpret_cast<const bf16x8*>(wpc + mf * 512);
                acc[mf][0] = __builtin_amdgcn_mfma_f32_16x16x32_bf16(A, B0, acc[mf][0], 0, 0, 0);
                acc[mf][1] = __builtin_amdgcn_mfma_f32_16x16x32_bf16(A, B1, acc[mf][1], 0, 0, 0);
            }
        }
    }

    // fg epilogue: co = mf*16+lg*4+r, px = x0+nf*16+l15, gelu -> bf16 NHWC
    #pragma unroll
    for (int nf = 0; nf < 2; ++nf) {
        const int xx = x0 + nf * 16 + l15;
        ushort* fgp = fg + ((size_t)(b * HH + y) * WW + xx) * 64;
        #pragma unroll
        for (int mf = 0; mf < 4; ++mf) {
            const int co = mf * 16 + lg * 4;
            ushort pk[4];
            #pragma unroll
            for (int r = 0; r < 4; ++r)
                pk[r] = f2bf(geluf(acc[mf][nf][r] + conv_b[co + r]));
            *reinterpret_cast<uint2*>(fgp + co) = *reinterpret_cast<uint2*>(pk);
        }
    }
    // relu1 epilogue: NCHW fp32
    #pragma unroll
    for (int mf = 4; mf < 6; ++mf) {
        const int co = (mf - 4) * 16 + lg * 4;
        #pragma unroll
        for (int nf = 0; nf < 2; ++nf) {
            const int xx = x0 + nf * 16 + l15;
            float* op = relu1 + ((size_t)(b * 32 + co) * HH + y) * WW + xx;
            #pragma unroll
            for (int r = 0; r < 4; ++r)
                op[(size_t)r * HW] = fmaxf(acc[mf][nf][r] + dw1_b[co + r], 0.0f);
        }
    }
}

// Prepack ddct weights (7 layers) into MFMA A-fragment order.
__global__ __launch_bounds__(256) void prepack_wb_kernel(
    const float* __restrict__ ddct_w, ushort* __restrict__ wpb)
{
    const int idx = blockIdx.x * 256 + threadIdx.x;   // 7*9*2*4*64 = 32256
    if (idx >= 7 * 9 * 2 * 4 * 64) return;
    const int lane = idx & 63;
    int rest = idx >> 6;
    const int mf = rest & 3; rest >>= 2;
    const int cb = rest & 1; rest >>= 1;
    const int t  = rest % 9;
    const int li = rest / 9;
    const int co  = mf * 16 + (lane & 15);
    const int ci0 = cb * 32 + (lane >> 4) * 8;
    ushort* dst = wpb + (size_t)idx * 8;
    #pragma unroll
    for (int j = 0; j < 8; ++j)
        dst[j] = f2bf(ddct_w[(((size_t)li * 64 + co) * 64 + ci0 + j) * 9 + t]);
}

// All 7 branch convs (64->64, 3x3, pad 1) on the compact 96x96 grid as MFMA
// implicit GEMM over NHWC bf16 feat. Epilogue fuses gelu + residual.
__global__ __launch_bounds__(256) void branch_mfma_kernel(
    const ushort* __restrict__ fg, const ushort* __restrict__ wpb,
    const float* __restrict__ ddct_b, float* __restrict__ ycomp)
{
    const int lane = threadIdx.x & 63;
    const int wave = threadIdx.x >> 6;
    const int l15  = lane & 15;
    const int lg   = lane >> 4;

    int bid = blockIdx.x;              // (li*BB+b)*72 + t72
    const int t72 = bid % 72; bid /= 72;
    const int b  = bid & 1;
    const int li = bid >> 1;
    const int widx = t72 * 4 + wave;
    const int r  = widx / 3;
    const int c0 = (widx - r * 3) * 32;
    const int R  = dec96(r);

    const int cA = c0 + l15, cB = cA + 16;
    const int CA = dec96(cA), CB2 = dec96(cB);

    f32x4 acc[4][2];
    #pragma unroll
    for (int mf = 0; mf < 4; ++mf)
        #pragma unroll
        for (int nf = 0; nf < 2; ++nf)
            acc[mf][nf] = (f32x4){0.f, 0.f, 0.f, 0.f};

    const bf16x8 zero8 = {};
    const ushort* fgb = fg + (size_t)b * HW * 64;

    #pragma unroll 1
    for (int t = 0; t < 9; ++t) {
        const int dy = t / 3 - 1, dx = t % 3 - 1;
        const int yy = R + dy;
        if ((unsigned)yy >= (unsigned)HH) continue;

        const int xA = CA + dx, xB = CB2 + dx;
        const bool va = (unsigned)xA < (unsigned)WW;
        const bool vb = (unsigned)xB < (unsigned)WW;
        const int xAc = min(max(xA, 0), WW - 1);
        const int xBc = min(max(xB, 0), WW - 1);

        const ushort* rowb = fgb + (size_t)yy * WW * 64;
        const ushort* pA = rowb + (size_t)xAc * 64 + lg * 8;
        const ushort* pB = rowb + (size_t)xBc * 64 + lg * 8;
        const ushort* wp = wpb + (size_t)((li * 9 + t) * 2) * (4 * 512) + lane * 8;

        #pragma unroll
        for (int cb = 0; cb < 2; ++cb) {
            bf16x8 B0 = *reinterpret_cast<const bf16x8*>(pA + cb * 32);
            bf16x8 B1 = *reinterpret_cast<const bf16x8*>(pB + cb * 32);
            B0 = va ? B0 : zero8;
            B1 = vb ? B1 : zero8;
            const ushort* wpc = wp + (size_t)cb * (4 * 512);
            #pragma unroll
            for (int mf = 0; mf < 4; ++mf) {
                const bf16x8 A = *reinterpret_cast<const bf16x8*>(wpc + mf * 512);
                acc[mf][0] = __builtin_amdgcn_mfma_f32_16x16x32_bf16(A, B0, acc[mf][0], 0, 0, 0);
                acc[mf][1] = __builtin_amdgcn_mfma_f32_16x16x32_bf16(A, B1, acc[mf][1], 0, 0, 0);
            }
        }
    }

    #pragma unroll
    for (int nf = 0; nf < 2; ++nf) {
        const int c = c0 + nf * 16 + l15;
        const int C = dec96(c);
        const ushort* res = fgb + ((size_t)R * WW + C) * 64;
        #pragma unroll
        for (int mf = 0; mf < 4; ++mf) {
            const int co = mf * 16 + lg * 4;
            ushort r4[4];
            *reinterpret_cast<uint2*>(r4) = *reinterpret_cast<const uint2*>(res + co);
            #pragma unroll
            for (int rr = 0; rr < 4; ++rr) {
                const float v = geluf(acc[mf][nf][rr] + ddct_b[li * 64 + co + rr]) + bf2f(r4[rr]);
                ycomp[((((size_t)li * BB + b) * 64 + co + rr) * 96 + r) * 96 + c] = v;
            }
        }
    }
}

// Depthwise 3x3 stride 8 dil 2 pad 2 -> 32x32 (DCT->IDCT identity skipped).
__global__ __launch_bounds__(256) void dctc_kernel(
    const float* __restrict__ ycomp, const float* __restrict__ dctc_w,
    const float* __restrict__ dctc_b, float* __restrict__ s_all)
{
    const int idx = blockIdx.x * 256 + threadIdx.x;
    if (idx >= 7 * BB * 64 * 32 * 32) return;
    const int ow = idx & 31;
    const int oh = (idx >> 5) & 31;
    const int c  = (idx >> 10) & 63;
    const int b  = (idx >> 16) & (BB - 1);
    const int li = idx >> 17;

    const float* yc = ycomp + (((size_t)li * BB + b) * 64 + c) * (96 * 96);
    const float* w  = dctc_w + (li * 64 + c) * 9;
    float acc = dctc_b[li * 64 + c];
    #pragma unroll
    for (int ky = 0; ky < 3; ++ky) {
        const int cr = 3 * oh + ky - 1;
        if (cr < 0) continue;
        #pragma unroll
        for (int kx = 0; kx < 3; ++kx) {
            const int cc = 3 * ow + kx - 1;
            if (cc < 0) continue;
            acc = fmaf(yc[cr * 96 + cc], w[ky * 3 + kx], acc);
        }
    }
    s_all[idx] = acc;
}

// Gate + bilinear upsample + multiply, writing gated in NHWC bf16.
__global__ __launch_bounds__(256) void gated_nhwc_kernel(
    const float* __restrict__ relu1, const float* __restrict__ dw3_w,
    const float* __restrict__ dw3_b, const float* __restrict__ s_all,
    ushort* __restrict__ gt)
{
    __shared__ float sm[32][32];   // [k][px]
    const int pix0 = blockIdx.x * 32;
    const int b  = pix0 >> 16;
    const int y  = (pix0 >> 8) & 255;
    const int x0 = pix0 & 255;

    {
        const int spx = threadIdx.x & 31;
        const int k0  = threadIdx.x >> 5;
        const float* rbase = relu1 + (size_t)b * 32 * HW + (size_t)y * WW + x0 + spx;
        #pragma unroll
        for (int i = 0; i < 4; ++i)
            sm[k0 + 8 * i][spx] = rbase[(size_t)(k0 + 8 * i) * HW];
    }
    __syncthreads();

    const int ch0 = threadIdx.x * 2;
    const int branch = ch0 >> 6;
    const int c0 = ch0 & 63;
    const int lmap[8] = {0, 1, 2, 3, 4, 3, 5, 6};
    const int li = lmap[branch];

    const float bb0 = dw3_b[ch0], bb1 = dw3_b[ch0 + 1];

    float acc0[32], acc1[32];
    #pragma unroll
    for (int px = 0; px < 32; ++px) { acc0[px] = bb0; acc1[px] = bb1; }

    const float* wp0 = dw3_w + ch0 * 32;
    #pragma unroll
    for (int k = 0; k < 32; ++k) {
        const float w0k = wp0[k];
        const float w1k = wp0[32 + k];
        const float4* row = reinterpret_cast<const float4*>(&sm[k][0]);
        #pragma unroll
        for (int q = 0; q < 8; ++q) {
            const float4 r4 = row[q];
            acc0[q*4+0] = fmaf(r4.x, w0k, acc0[q*4+0]);
            acc0[q*4+1] = fmaf(r4.y, w0k, acc0[q*4+1]);
            acc0[q*4+2] = fmaf(r4.z, w0k, acc0[q*4+2]);
            acc0[q*4+3] = fmaf(r4.w, w0k, acc0[q*4+3]);
            acc1[q*4+0] = fmaf(r4.x, w1k, acc1[q*4+0]);
            acc1[q*4+1] = fmaf(r4.y, w1k, acc1[q*4+1]);
            acc1[q*4+2] = fmaf(r4.z, w1k, acc1[q*4+2]);
            acc1[q*4+3] = fmaf(r4.w, w1k, acc1[q*4+3]);
        }
    }

    const float* sp0 = s_all + (((size_t)li * BB + b) * 64 + c0) * 1024;
    const float* sp1 = sp0 + 1024;

    const float sy = (y + 0.5f) * 0.125f - 0.5f;
    const float fy0f = floorf(sy);
    const float fy = sy - fy0f;
    int y0 = (int)fy0f;
    const int y1 = min(y0 + 1, 31);
    y0 = max(y0, 0);

    float n0[6], n1[6];
    const int xb = (x0 >> 3) - 1;
    #pragma unroll
    for (int jj = 0; jj < 6; ++jj) {
        const int xn = min(max(xb + jj, 0), 31);
        const float a00 = sp0[y0 * 32 + xn], a01 = sp0[y1 * 32 + xn];
        const float a10 = sp1[y0 * 32 + xn], a11 = sp1[y1 * 32 + xn];
        n0[jj] = a00 + fy * (a01 - a00);
        n1[jj] = a10 + fy * (a11 - a10);
    }

    ushort* gbase = gt + (size_t)pix0 * 512 + ch0;
    #pragma unroll
    for (int px = 0; px < 32; ++px) {
        const int   j  = (px + 4) >> 3;
        const float fx = (float)((px + 4) & 7) * 0.125f + 0.0625f;
        const float va = n0[j] + fx * (n0[j + 1] - n0[j]);
        const float vb = n1[j] + fx * (n1[j + 1] - n1[j]);
        const float g0 = 1.0f / (1.0f + exp2f(-1.4426950408889634f * acc0[px]));
        const float g1 = 1.0f / (1.0f + exp2f(-1.4426950408889634f * acc1[px]));
        const uint pack = (uint)f2bf(va * g0) | ((uint)f2bf(vb * g1) << 16);
        *reinterpret_cast<uint*>(gbase + (size_t)px * 512) = pack;
    }
}

// Prepack ar_w into MFMA A-fragment order (bf16).
__global__ __launch_bounds__(256) void prepack_w_kernel(
    const float* __restrict__ ar_w, ushort* __restrict__ wpack)
{
    const int idx = blockIdx.x * 256 + threadIdx.x;   // 9*16*5*64 = 46080
    if (idx >= 9 * 16 * 5 * 64) return;
    const int lane = idx & 63;
    int rest = idx >> 6;
    const int mf = rest % 5; rest /= 5;
    const int cb = rest & 15;
    const int t  = rest >> 4;
    const int co  = mf * 16 + (lane & 15);
    const int ci0 = cb * 32 + (lane >> 4) * 8;
    ushort* dst = wpack + (size_t)idx * 8;
    #pragma unroll
    for (int j = 0; j < 8; ++j) {
        const float w = (co < 72) ? ar_w[((size_t)co * 512 + ci0 + j) * 9 + t] : 0.0f;
        dst[j] = f2bf(w);
    }
}

// Final conv 512->72 as implicit GEMM on MFMA (NHWC bf16 input).
__global__ __launch_bounds__(256) void conv_ar_mfma_kernel(
    const ushort* __restrict__ gt, const ushort* __restrict__ wpack,
    const float* __restrict__ ar_b, float* __restrict__ out)
{
    const int lane = threadIdx.x & 63;
    const int wave = threadIdx.x >> 6;
    const int l15  = lane & 15;
    const int lg   = lane >> 4;

    const int bid  = blockIdx.x;          // 1024 = b(2) * y(256) * xt(2)
    const int b    = bid >> 9;
    const int rest = bid & 511;
    const int y    = rest >> 1;
    const int x0   = (rest & 1) * 128 + wave * 32;

    f32x4 acc[5][2];
    #pragma unroll
    for (int mf = 0; mf < 5; ++mf)
        #pragma unroll
        for (int nf = 0; nf < 2; ++nf)
            acc[mf][nf] = (f32x4){0.f, 0.f, 0.f, 0.f};

    const bf16x8 zero8 = {};

    #pragma unroll 1
    for (int t = 0; t < 9; ++t) {
        const int dy = t / 3 - 1, dx = t % 3 - 1;
        const int yy = y + dy;
        if ((unsigned)yy >= (unsigned)HH) continue;

        const int xA = x0 + l15 + dx;
        const int xB = xA + 16;
        const bool va = (unsigned)xA < (unsigned)WW;
        const bool vb = (unsigned)xB < (unsigned)WW;
        const int xAc = min(max(xA, 0), WW - 1);
        const int xBc = min(xB, WW - 1);

        const ushort* rowbase = gt + ((size_t)(b * HH + yy) * WW) * 512;
        const ushort* pA = rowbase + (size_t)xAc * 512 + lg * 8;
        const ushort* pB = rowbase + (size_t)xBc * 512 + lg * 8;
        const ushort* wp = wpack + (size_t)t * (16 * 5 * 512) + lane * 8;

        #pragma unroll 2
        for (int cb = 0; cb < 16; ++cb) {
            bf16x8 B0 = *reinterpret_cast<const bf16x8*>(pA + cb * 32);
            bf16x8 B1 = *reinterpret_cast<const bf16x8*>(pB + cb * 32);
            B0 = va ? B0 : zero8;
            B1 = vb ? B1 : zero8;
            const ushort* wpc = wp + (size_t)cb * (5 * 512);
            #pragma unroll
            for (int mf = 0; mf < 5; ++mf) {
                const bf16x8 A = *reinterpret_cast<const bf16x8*>(wpc + mf * 512);
                acc[mf][0] = __builtin_amdgcn_mfma_f32_16x16x32_bf16(A, B0, acc[mf][0], 0, 0, 0);
                acc[mf][1] = __builtin_amdgcn_mfma_f32_16x16x32_bf16(A, B1, acc[mf][1], 0, 0, 0);
            }
        }
    }

    #pragma unroll
    for (int mf = 0; mf < 5; ++mf) {
        const int co = mf * 16 + lg * 4;
        if (co >= 72) continue;
        #pragma unroll
        for (int nf = 0; nf < 2; ++nf) {
            const int x = x0 + nf * 16 + l15;
            float* op = out + (((size_t)(b * 72 + co) * HH + y) * WW) + x;
            #pragma unroll
            for (int r = 0; r < 4; ++r)
                op[(size_t)r * HW] = acc[mf][nf][r] + ar_b[co + r];
        }
    }
}

extern "C" void kernel_launch(void* const* d_in, const int* in_sizes, int n_in,
                              void* d_out, int out_size, void* d_ws, size_t ws_size,
                              hipStream_t stream) {
    const float* x      = (const float*)d_in[0];
    const float* conv_w = (const float*)d_in[1];
    const float* conv_b = (const float*)d_in[2];
    const float* ddct_w = (const float*)d_in[3];
    const float* ddct_b = (const float*)d_in[4];
    const float* dctc_w = (const float*)d_in[5];
    const float* dctc_b = (const float*)d_in[6];
    const float* dw1_w  = (const float*)d_in[7];
    const float* dw1_b  = (const float*)d_in[8];
    const float* dw3_w  = (const float*)d_in[9];
    const float* dw3_b  = (const float*)d_in[10];
    const float* ar_w   = (const float*)d_in[11];
    const float* ar_b   = (const float*)d_in[12];
    float* out = (float*)d_out;

    float* ws = (float*)d_ws;
    // Layout (float slots). fg + ycomp are dead before gated_t is written.
    ushort* gated_t = (ushort*)ws;               // 67,108,864 us = [0 .. 33,554,432) f
    ushort* fg    = (ushort*)ws;                 // 8,388,608 us = [0 .. 4,194,304) f
    float* ycomp  = ws + 4194304;                // -> ends 12,451,840
    float* s_all  = ws + 33554432;               // 917,504 f
    float* relu1  = ws + 34471936;               // 4,194,304 f
    ushort* wpack = (ushort*)(ws + 38666240);    // 368,640 us -> ends 38,850,560 f
    ushort* wpb   = (ushort*)(ws + 38850560);    // 258,048 us -> ends 38,979,584 f
    ushort* wpc1  = (ushort*)(ws + 38979584);    // 82,944 us  -> ends 39,021,056 f
    ushort* xt    = (ushort*)(ws + 39021056);    // 12,582,912 us -> ends 45,312,512 f

    // 0) weight prepacks + x transpose
    prepack_w_kernel<<<dim3(180), dim3(256), 0, stream>>>(ar_w, wpack);
    prepack_wb_kernel<<<dim3(126), dim3(256), 0, stream>>>(ddct_w, wpb);
    prepack_w1_kernel<<<dim3(41), dim3(256), 0, stream>>>(conv_w, dw1_w, wpc1);
    xpose_kernel<<<dim3(BB * HW / 256), dim3(256), 0, stream>>>(x, xt);

    // 1) fused conv1 (fg NHWC bf16, gelu) + dw1 (relu1 NCHW fp32, relu)
    conv1dw1_mfma_kernel<<<dim3(BB * HH * 2), dim3(256), 0, stream>>>(
        xt, wpc1, conv_b, dw1_b, fg, relu1);

    // 2) branch convs (7 layers) as MFMA implicit GEMM on compact grid
    branch_mfma_kernel<<<dim3(7 * BB * 72), dim3(256), 0, stream>>>(
        fg, wpb, ddct_b, ycomp);

    // 3) depthwise stride-8 convs
    dctc_kernel<<<dim3((7 * BB * 64 * 32 * 32) / 256), dim3(256), 0, stream>>>(
        ycomp, dctc_w, dctc_b, s_all);

    // 4) gated (NHWC bf16) = upsample(s) * sigmoid(1x1conv(relu1))
    gated_nhwc_kernel<<<dim3(BB * HW / 32), dim3(256), 0, stream>>>(
        relu1, dw3_w, dw3_b, s_all, gated_t);

    // 5) out = conv3x3(gated, ar_w)  512 -> 72, MFMA implicit GEMM
    conv_ar_mfma_kernel<<<dim3(BB * HH * 2), dim3(256), 0, stream>>>(
        gated_t, wpack, ar_b, out);
}

// Round 11
// 480.167 us; speedup vs baseline: 9.8514x; 1.0216x over previous
//
#include <hip/hip_runtime.h>
#include <hip/hip_bf16.h>

#define BB 2
#define HH 256
#define WW 256
#define HW (HH*WW)

typedef __attribute__((ext_vector_type(8))) short bf16x8;
typedef __attribute__((ext_vector_type(4))) float f32x4;

__device__ __forceinline__ float geluf(float x) {
    return 0.5f * x * (1.0f + erff(x * 0.7071067811865475f));
}

__device__ __forceinline__ ushort f2bf(float f) {
    __hip_bfloat16 h = __float2bfloat16(f);
    return *reinterpret_cast<ushort*>(&h);
}
__device__ __forceinline__ float bf2f(ushort u) {
    uint v = ((uint)u) << 16;
    return *reinterpret_cast<float*>(&v);
}

// compact index [0,96) -> actual coordinate (rows/cols = 0,2,6 mod 8)
__device__ __forceinline__ int dec96(int i) {
    int q = i / 3, r = i - q * 3;
    return q * 8 + (r == 0 ? 0 : (r == 1 ? 2 : 6));
}

// x (NCHW fp32, 72ch) -> xt (NHWC bf16, 96ch zero-padded).
__global__ __launch_bounds__(256) void xpose_kernel(
    const float* __restrict__ x, ushort* __restrict__ xt)
{
    const int pix = blockIdx.x * 256 + threadIdx.x;   // [0, BB*HW)
    const int b   = pix >> 16;
    const int rem = pix & 65535;

    uint w[48];
    const float* xb = x + (size_t)b * 72 * HW + rem;
    #pragma unroll
    for (int i = 0; i < 36; ++i) {
        const ushort lo = f2bf(xb[(size_t)(2 * i)     * HW]);
        const ushort hi = f2bf(xb[(size_t)(2 * i + 1) * HW]);
        w[i] = (uint)lo | ((uint)hi << 16);
    }
    #pragma unroll
    for (int i = 36; i < 48; ++i) w[i] = 0;

    uint* dst = reinterpret_cast<uint*>(xt + (size_t)pix * 96);
    #pragma unroll
    for (int k = 0; k < 12; ++k) {
        uint4 u = { w[4*k], w[4*k+1], w[4*k+2], w[4*k+3] };
        *reinterpret_cast<uint4*>(dst + 4 * k) = u;
    }
}

// Prepack fused conv1(64co)+dw1(32co) weights into MFMA A-frag order.
__global__ __launch_bounds__(256) void prepack_w1_kernel(
    const float* __restrict__ conv_w, const float* __restrict__ dw1_w,
    ushort* __restrict__ wpc1)
{
    const int idx = blockIdx.x * 256 + threadIdx.x;   // 9*3*6*64 = 10368
    if (idx >= 9 * 3 * 6 * 64) return;
    const int lane = idx & 63;
    int rest = idx >> 6;
    const int mf = rest % 6; rest /= 6;
    const int cb = rest % 3;
    const int t  = rest / 3;
    const int co  = mf * 16 + (lane & 15);
    const int ci0 = cb * 32 + (lane >> 4) * 8;
    ushort* dst = wpc1 + (size_t)idx * 8;
    #pragma unroll
    for (int j = 0; j < 8; ++j) {
        const int ci = ci0 + j;
        float w = 0.0f;
        if (ci < 72)
            w = (co < 64) ? conv_w[((size_t)co * 72 + ci) * 9 + t]
                          : dw1_w[((size_t)(co - 64) * 72 + ci) * 9 + t];
        dst[j] = f2bf(w);
    }
}

// Fused conv1+dw1 as MFMA implicit GEMM (M=96, K=9*96) over xt.
__global__ __launch_bounds__(256) void conv1dw1_mfma_kernel(
    const ushort* __restrict__ xt, const ushort* __restrict__ wpc1,
    const float* __restrict__ conv_b, const float* __restrict__ dw1_b,
    ushort* __restrict__ fg, float* __restrict__ relu1)
{
    const int lane = threadIdx.x & 63;
    const int wave = threadIdx.x >> 6;
    const int l15  = lane & 15;
    const int lg   = lane >> 4;

    const int bid  = blockIdx.x;          // 1024 = b(2) * y(256) * half(2)
    const int b    = bid >> 9;
    const int rest = bid & 511;
    const int y    = rest >> 1;
    const int x0   = (rest & 1) * 128 + wave * 32;

    f32x4 acc[6][2];
    #pragma unroll
    for (int mf = 0; mf < 6; ++mf)
        #pragma unroll
        for (int nf = 0; nf < 2; ++nf)
            acc[mf][nf] = (f32x4){0.f, 0.f, 0.f, 0.f};

    const bf16x8 zero8 = {};

    #pragma unroll 1
    for (int t = 0; t < 9; ++t) {
        const int dy = t / 3 - 1, dx = t % 3 - 1;
        const int yy = y + dy;
        if ((unsigned)yy >= (unsigned)HH) continue;

        const int xA = x0 + l15 + dx;
        const int xB = xA + 16;
        const bool va = (unsigned)xA < (unsigned)WW;
        const bool vb = (unsigned)xB < (unsigned)WW;
        const int xAc = min(max(xA, 0), WW - 1);
        const int xBc = min(xB, WW - 1);

        const ushort* rowbase = xt + ((size_t)(b * HH + yy) * WW) * 96;
        const ushort* pA = rowbase + (size_t)xAc * 96 + lg * 8;
        const ushort* pB = rowbase + (size_t)xBc * 96 + lg * 8;
        const ushort* wp = wpc1 + (size_t)(t * 3) * (6 * 512) + lane * 8;

        #pragma unroll
        for (int cb = 0; cb < 3; ++cb) {
            bf16x8 B0 = *reinterpret_cast<const bf16x8*>(pA + cb * 32);
            bf16x8 B1 = *reinterpret_cast<const bf16x8*>(pB + cb * 32);
            B0 = va ? B0 : zero8;
            B1 = vb ? B1 : zero8;
            const ushort* wpc = wp + (size_t)cb * (6 * 512);
            #pragma unroll
            for (int mf = 0; mf < 6; ++mf) {
                const bf16x8 A = *reinterpret_cast<const bf16x8*>(wpc + mf * 512);
                acc[mf][0] = __builtin_amdgcn_mfma_f32_16x16x32_bf16(A, B0, acc[mf][0], 0, 0, 0);
                acc[mf][1] = __builtin_amdgcn_mfma_f32_16x16x32_bf16(A, B1, acc[mf][1], 0, 0, 0);
            }
        }
    }

    #pragma unroll
    for (int nf = 0; nf < 2; ++nf) {
        const int xx = x0 + nf * 16 + l15;
        ushort* fgp = fg + ((size_t)(b * HH + y) * WW + xx) * 64;
        #pragma unroll
        for (int mf = 0; mf < 4; ++mf) {
            const int co = mf * 16 + lg * 4;
            ushort pk[4];
            #pragma unroll
            for (int r = 0; r < 4; ++r)
                pk[r] = f2bf(geluf(acc[mf][nf][r] + conv_b[co + r]));
            *reinterpret_cast<uint2*>(fgp + co) = *reinterpret_cast<uint2*>(pk);
        }
    }
    #pragma unroll
    for (int mf = 4; mf < 6; ++mf) {
        const int co = (mf - 4) * 16 + lg * 4;
        #pragma unroll
        for (int nf = 0; nf < 2; ++nf) {
            const int xx = x0 + nf * 16 + l15;
            float* op = relu1 + ((size_t)(b * 32 + co) * HH + y) * WW + xx;
            #pragma unroll
            for (int r = 0; r < 4; ++r)
                op[(size_t)r * HW] = fmaxf(acc[mf][nf][r] + dw1_b[co + r], 0.0f);
        }
    }
}

// Prepack ddct weights (7 layers) into MFMA A-fragment order.
__global__ __launch_bounds__(256) void prepack_wb_kernel(
    const float* __restrict__ ddct_w, ushort* __restrict__ wpb)
{
    const int idx = blockIdx.x * 256 + threadIdx.x;   // 7*9*2*4*64 = 32256
    if (idx >= 7 * 9 * 2 * 4 * 64) return;
    const int lane = idx & 63;
    int rest = idx >> 6;
    const int mf = rest & 3; rest >>= 2;
    const int cb = rest & 1; rest >>= 1;
    const int t  = rest % 9;
    const int li = rest / 9;
    const int co  = mf * 16 + (lane & 15);
    const int ci0 = cb * 32 + (lane >> 4) * 8;
    ushort* dst = wpb + (size_t)idx * 8;
    #pragma unroll
    for (int j = 0; j < 8; ++j)
        dst[j] = f2bf(ddct_w[(((size_t)li * 64 + co) * 64 + ci0 + j) * 9 + t]);
}

// All 7 branch convs on the compact 96x96 grid as MFMA implicit GEMM.
__global__ __launch_bounds__(256) void branch_mfma_kernel(
    const ushort* __restrict__ fg, const ushort* __restrict__ wpb,
    const float* __restrict__ ddct_b, float* __restrict__ ycomp)
{
    const int lane = threadIdx.x & 63;
    const int wave = threadIdx.x >> 6;
    const int l15  = lane & 15;
    const int lg   = lane >> 4;

    int bid = blockIdx.x;              // (li*BB+b)*72 + t72
    const int t72 = bid % 72; bid /= 72;
    const int b  = bid & 1;
    const int li = bid >> 1;
    const int widx = t72 * 4 + wave;
    const int r  = widx / 3;
    const int c0 = (widx - r * 3) * 32;
    const int R  = dec96(r);

    const int cA = c0 + l15, cB = cA + 16;
    const int CA = dec96(cA), CB2 = dec96(cB);

    f32x4 acc[4][2];
    #pragma unroll
    for (int mf = 0; mf < 4; ++mf)
        #pragma unroll
        for (int nf = 0; nf < 2; ++nf)
            acc[mf][nf] = (f32x4){0.f, 0.f, 0.f, 0.f};

    const bf16x8 zero8 = {};
    const ushort* fgb = fg + (size_t)b * HW * 64;

    #pragma unroll 1
    for (int t = 0; t < 9; ++t) {
        const int dy = t / 3 - 1, dx = t % 3 - 1;
        const int yy = R + dy;
        if ((unsigned)yy >= (unsigned)HH) continue;

        const int xA = CA + dx, xB = CB2 + dx;
        const bool va = (unsigned)xA < (unsigned)WW;
        const bool vb = (unsigned)xB < (unsigned)WW;
        const int xAc = min(max(xA, 0), WW - 1);
        const int xBc = min(max(xB, 0), WW - 1);

        const ushort* rowb = fgb + (size_t)yy * WW * 64;
        const ushort* pA = rowb + (size_t)xAc * 64 + lg * 8;
        const ushort* pB = rowb + (size_t)xBc * 64 + lg * 8;
        const ushort* wp = wpb + (size_t)((li * 9 + t) * 2) * (4 * 512) + lane * 8;

        #pragma unroll
        for (int cb = 0; cb < 2; ++cb) {
            bf16x8 B0 = *reinterpret_cast<const bf16x8*>(pA + cb * 32);
            bf16x8 B1 = *reinterpret_cast<const bf16x8*>(pB + cb * 32);
            B0 = va ? B0 : zero8;
            B1 = vb ? B1 : zero8;
            const ushort* wpc = wp + (size_t)cb * (4 * 512);
            #pragma unroll
            for (int mf = 0; mf < 4; ++mf) {
                const bf16x8 A = *reinterpret_cast<const bf16x8*>(wpc + mf * 512);
                acc[mf][0] = __builtin_amdgcn_mfma_f32_16x16x32_bf16(A, B0, acc[mf][0], 0, 0, 0);
                acc[mf][1] = __builtin_amdgcn_mfma_f32_16x16x32_bf16(A, B1, acc[mf][1], 0, 0, 0);
            }
        }
    }

    #pragma unroll
    for (int nf = 0; nf < 2; ++nf) {
        const int c = c0 + nf * 16 + l15;
        const int C = dec96(c);
        const ushort* res = fgb + ((size_t)R * WW + C) * 64;
        #pragma unroll
        for (int mf = 0; mf < 4; ++mf) {
            const int co = mf * 16 + lg * 4;
            ushort r4[4];
            *reinterpret_cast<uint2*>(r4) = *reinterpret_cast<const uint2*>(res + co);
            #pragma unroll
            for (int rr = 0; rr < 4; ++rr) {
                const float v = geluf(acc[mf][nf][rr] + ddct_b[li * 64 + co + rr]) + bf2f(r4[rr]);
                ycomp[((((size_t)li * BB + b) * 64 + co + rr) * 96 + r) * 96 + c] = v;
            }
        }
    }
}

// Depthwise 3x3 stride 8 dil 2 pad 2 -> 32x32 (DCT->IDCT identity skipped).
__global__ __launch_bounds__(256) void dctc_kernel(
    const float* __restrict__ ycomp, const float* __restrict__ dctc_w,
    const float* __restrict__ dctc_b, float* __restrict__ s_all)
{
    const int idx = blockIdx.x * 256 + threadIdx.x;
    if (idx >= 7 * BB * 64 * 32 * 32) return;
    const int ow = idx & 31;
    const int oh = (idx >> 5) & 31;
    const int c  = (idx >> 10) & 63;
    const int b  = (idx >> 16) & (BB - 1);
    const int li = idx >> 17;

    const float* yc = ycomp + (((size_t)li * BB + b) * 64 + c) * (96 * 96);
    const float* w  = dctc_w + (li * 64 + c) * 9;
    float acc = dctc_b[li * 64 + c];
    #pragma unroll
    for (int ky = 0; ky < 3; ++ky) {
        const int cr = 3 * oh + ky - 1;
        if (cr < 0) continue;
        #pragma unroll
        for (int kx = 0; kx < 3; ++kx) {
            const int cc = 3 * ow + kx - 1;
            if (cc < 0) continue;
            acc = fmaf(yc[cr * 96 + cc], w[ky * 3 + kx], acc);
        }
    }
    s_all[idx] = acc;
}

// Gate + bilinear upsample + multiply, writing gated in NHWC bf16.
__global__ __launch_bounds__(256) void gated_nhwc_kernel(
    const float* __restrict__ relu1, const float* __restrict__ dw3_w,
    const float* __restrict__ dw3_b, const float* __restrict__ s_all,
    ushort* __restrict__ gt)
{
    __shared__ float sm[32][32];   // [k][px]
    const int pix0 = blockIdx.x * 32;
    const int b  = pix0 >> 16;
    const int y  = (pix0 >> 8) & 255;
    const int x0 = pix0 & 255;

    {
        const int spx = threadIdx.x & 31;
        const int k0  = threadIdx.x >> 5;
        const float* rbase = relu1 + (size_t)b * 32 * HW + (size_t)y * WW + x0 + spx;
        #pragma unroll
        for (int i = 0; i < 4; ++i)
            sm[k0 + 8 * i][spx] = rbase[(size_t)(k0 + 8 * i) * HW];
    }
    __syncthreads();

    const int ch0 = threadIdx.x * 2;
    const int branch = ch0 >> 6;
    const int c0 = ch0 & 63;
    const int lmap[8] = {0, 1, 2, 3, 4, 3, 5, 6};
    const int li = lmap[branch];

    const float bb0 = dw3_b[ch0], bb1 = dw3_b[ch0 + 1];

    float acc0[32], acc1[32];
    #pragma unroll
    for (int px = 0; px < 32; ++px) { acc0[px] = bb0; acc1[px] = bb1; }

    const float* wp0 = dw3_w + ch0 * 32;
    #pragma unroll
    for (int k = 0; k < 32; ++k) {
        const float w0k = wp0[k];
        const float w1k = wp0[32 + k];
        const float4* row = reinterpret_cast<const float4*>(&sm[k][0]);
        #pragma unroll
        for (int q = 0; q < 8; ++q) {
            const float4 r4 = row[q];
            acc0[q*4+0] = fmaf(r4.x, w0k, acc0[q*4+0]);
            acc0[q*4+1] = fmaf(r4.y, w0k, acc0[q*4+1]);
            acc0[q*4+2] = fmaf(r4.z, w0k, acc0[q*4+2]);
            acc0[q*4+3] = fmaf(r4.w, w0k, acc0[q*4+3]);
            acc1[q*4+0] = fmaf(r4.x, w1k, acc1[q*4+0]);
            acc1[q*4+1] = fmaf(r4.y, w1k, acc1[q*4+1]);
            acc1[q*4+2] = fmaf(r4.z, w1k, acc1[q*4+2]);
            acc1[q*4+3] = fmaf(r4.w, w1k, acc1[q*4+3]);
        }
    }

    const float* sp0 = s_all + (((size_t)li * BB + b) * 64 + c0) * 1024;
    const float* sp1 = sp0 + 1024;

    const float sy = (y + 0.5f) * 0.125f - 0.5f;
    const float fy0f = floorf(sy);
    const float fy = sy - fy0f;
    int y0 = (int)fy0f;
    const int y1 = min(y0 + 1, 31);
    y0 = max(y0, 0);

    float n0[6], n1[6];
    const int xb = (x0 >> 3) - 1;
    #pragma unroll
    for (int jj = 0; jj < 6; ++jj) {
        const int xn = min(max(xb + jj, 0), 31);
        const float a00 = sp0[y0 * 32 + xn], a01 = sp0[y1 * 32 + xn];
        const float a10 = sp1[y0 * 32 + xn], a11 = sp1[y1 * 32 + xn];
        n0[jj] = a00 + fy * (a01 - a00);
        n1[jj] = a10 + fy * (a11 - a10);
    }

    ushort* gbase = gt + (size_t)pix0 * 512 + ch0;
    #pragma unroll
    for (int px = 0; px < 32; ++px) {
        const int   j  = (px + 4) >> 3;
        const float fx = (float)((px + 4) & 7) * 0.125f + 0.0625f;
        const float va = n0[j] + fx * (n0[j + 1] - n0[j]);
        const float vb = n1[j] + fx * (n1[j + 1] - n1[j]);
        const float g0 = 1.0f / (1.0f + exp2f(-1.4426950408889634f * acc0[px]));
        const float g1 = 1.0f / (1.0f + exp2f(-1.4426950408889634f * acc1[px]));
        const uint pack = (uint)f2bf(va * g0) | ((uint)f2bf(vb * g1) << 16);
        *reinterpret_cast<uint*>(gbase + (size_t)px * 512) = pack;
    }
}

// Prepack ar_w into MFMA A-fragment order (bf16).
__global__ __launch_bounds__(256) void prepack_w_kernel(
    const float* __restrict__ ar_w, ushort* __restrict__ wpack)
{
    const int idx = blockIdx.x * 256 + threadIdx.x;   // 9*16*5*64 = 46080
    if (idx >= 9 * 16 * 5 * 64) return;
    const int lane = idx & 63;
    int rest = idx >> 6;
    const int mf = rest % 5; rest /= 5;
    const int cb = rest & 15;
    const int t  = rest >> 4;
    const int co  = mf * 16 + (lane & 15);
    const int ci0 = cb * 32 + (lane >> 4) * 8;
    ushort* dst = wpack + (size_t)idx * 8;
    #pragma unroll
    for (int j = 0; j < 8; ++j) {
        const float w = (co < 72) ? ar_w[((size_t)co * 512 + ci0 + j) * 9 + t] : 0.0f;
        dst[j] = f2bf(w);
    }
}

// Final conv 512->72 as implicit GEMM on MFMA (NHWC bf16 input).
// v2: XCD-aware bijective swizzle (each XCD owns 64 consecutive y rows) +
// cb-outer/tap-inner K loop (per-phase row working set 64B/px -> ~1MB/XCD,
// fits L2). Targets the 4.4x HBM over-fetch seen in round 9.
__global__ __launch_bounds__(256) void conv_ar_mfma_kernel(
    const ushort* __restrict__ gt, const ushort* __restrict__ wpack,
    const float* __restrict__ ar_b, float* __restrict__ out)
{
    const int lane = threadIdx.x & 63;
    const int wave = threadIdx.x >> 6;
    const int l15  = lane & 15;
    const int lg   = lane >> 4;

    // bijective XCD swizzle: nwg=1024, 8 XCDs, 128 logical blocks per XCD
    const int lb = (blockIdx.x & 7) * 128 + (blockIdx.x >> 3);
    const int b  = lb >> 9;
    const int y  = (lb >> 1) & 255;
    const int x0 = (lb & 1) * 128 + wave * 32;

    f32x4 acc[5][2];
    #pragma unroll
    for (int mf = 0; mf < 5; ++mf)
        #pragma unroll
        for (int nf = 0; nf < 2; ++nf)
            acc[mf][nf] = (f32x4){0.f, 0.f, 0.f, 0.f};

    // hoisted row pointers / x offsets (uniform over K loop)
    const ushort* rowp[3];
    bool rowok[3];
    #pragma unroll
    for (int dy = 0; dy < 3; ++dy) {
        const int yy = y + dy - 1;
        rowok[dy] = (unsigned)yy < (unsigned)HH;
        rowp[dy]  = gt + ((size_t)(b * HH + (rowok[dy] ? yy : 0)) * WW) * 512;
    }
    int offA[3], offB[3];
    bool vA[3], vB[3];
    #pragma unroll
    for (int dx = 0; dx < 3; ++dx) {
        const int xA = x0 + l15 + dx - 1;
        const int xB = xA + 16;
        vA[dx] = (unsigned)xA < (unsigned)WW;
        vB[dx] = (unsigned)xB < (unsigned)WW;
        offA[dx] = min(max(xA, 0), WW - 1) * 512 + lg * 8;
        offB[dx] = min(xB, WW - 1) * 512 + lg * 8;
    }

    const bf16x8 zero8 = {};

    #pragma unroll 1
    for (int cb = 0; cb < 16; ++cb) {
        const int cbo = cb * 32;
        #pragma unroll
        for (int t = 0; t < 9; ++t) {
            const int dy = t / 3, dx = t % 3;
            if (!rowok[dy]) continue;   // wave-uniform
            bf16x8 B0 = *reinterpret_cast<const bf16x8*>(rowp[dy] + offA[dx] + cbo);
            bf16x8 B1 = *reinterpret_cast<const bf16x8*>(rowp[dy] + offB[dx] + cbo);
            B0 = vA[dx] ? B0 : zero8;
            B1 = vB[dx] ? B1 : zero8;
            const ushort* wpc = wpack + (size_t)(t * 16 + cb) * (5 * 512) + lane * 8;
            #pragma unroll
            for (int mf = 0; mf < 5; ++mf) {
                const bf16x8 A = *reinterpret_cast<const bf16x8*>(wpc + mf * 512);
                acc[mf][0] = __builtin_amdgcn_mfma_f32_16x16x32_bf16(A, B0, acc[mf][0], 0, 0, 0);
                acc[mf][1] = __builtin_amdgcn_mfma_f32_16x16x32_bf16(A, B1, acc[mf][1], 0, 0, 0);
            }
        }
    }

    #pragma unroll
    for (int mf = 0; mf < 5; ++mf) {
        const int co = mf * 16 + lg * 4;
        if (co >= 72) continue;
        #pragma unroll
        for (int nf = 0; nf < 2; ++nf) {
            const int x = x0 + nf * 16 + l15;
            float* op = out + (((size_t)(b * 72 + co) * HH + y) * WW) + x;
            #pragma unroll
            for (int r = 0; r < 4; ++r)
                op[(size_t)r * HW] = acc[mf][nf][r] + ar_b[co + r];
        }
    }
}

extern "C" void kernel_launch(void* const* d_in, const int* in_sizes, int n_in,
                              void* d_out, int out_size, void* d_ws, size_t ws_size,
                              hipStream_t stream) {
    const float* x      = (const float*)d_in[0];
    const float* conv_w = (const float*)d_in[1];
    const float* conv_b = (const float*)d_in[2];
    const float* ddct_w = (const float*)d_in[3];
    const float* ddct_b = (const float*)d_in[4];
    const float* dctc_w = (const float*)d_in[5];
    const float* dctc_b = (const float*)d_in[6];
    const float* dw1_w  = (const float*)d_in[7];
    const float* dw1_b  = (const float*)d_in[8];
    const float* dw3_w  = (const float*)d_in[9];
    const float* dw3_b  = (const float*)d_in[10];
    const float* ar_w   = (const float*)d_in[11];
    const float* ar_b   = (const float*)d_in[12];
    float* out = (float*)d_out;

    float* ws = (float*)d_ws;
    // Layout (float slots). fg + ycomp are dead before gated_t is written.
    ushort* gated_t = (ushort*)ws;               // [0 .. 33,554,432) f
    ushort* fg    = (ushort*)ws;                 // [0 .. 4,194,304) f
    float* ycomp  = ws + 4194304;                // -> ends 12,451,840
    float* s_all  = ws + 33554432;               // 917,504 f
    float* relu1  = ws + 34471936;               // 4,194,304 f
    ushort* wpack = (ushort*)(ws + 38666240);    // -> ends 38,850,560 f
    ushort* wpb   = (ushort*)(ws + 38850560);    // -> ends 38,979,584 f
    ushort* wpc1  = (ushort*)(ws + 38979584);    // -> ends 39,021,056 f
    ushort* xt    = (ushort*)(ws + 39021056);    // -> ends 45,312,512 f

    // 0) weight prepacks + x transpose
    prepack_w_kernel<<<dim3(180), dim3(256), 0, stream>>>(ar_w, wpack);
    prepack_wb_kernel<<<dim3(126), dim3(256), 0, stream>>>(ddct_w, wpb);
    prepack_w1_kernel<<<dim3(41), dim3(256), 0, stream>>>(conv_w, dw1_w, wpc1);
    xpose_kernel<<<dim3(BB * HW / 256), dim3(256), 0, stream>>>(x, xt);

    // 1) fused conv1 (fg NHWC bf16, gelu) + dw1 (relu1 NCHW fp32, relu)
    conv1dw1_mfma_kernel<<<dim3(BB * HH * 2), dim3(256), 0, stream>>>(
        xt, wpc1, conv_b, dw1_b, fg, relu1);

    // 2) branch convs (7 layers) as MFMA implicit GEMM on compact grid
    branch_mfma_kernel<<<dim3(7 * BB * 72), dim3(256), 0, stream>>>(
        fg, wpb, ddct_b, ycomp);

    // 3) depthwise stride-8 convs
    dctc_kernel<<<dim3((7 * BB * 64 * 32 * 32) / 256), dim3(256), 0, stream>>>(
        ycomp, dctc_w, dctc_b, s_all);

    // 4) gated (NHWC bf16) = upsample(s) * sigmoid(1x1conv(relu1))
    gated_nhwc_kernel<<<dim3(BB * HW / 32), dim3(256), 0, stream>>>(
        relu1, dw3_w, dw3_b, s_all, gated_t);

    // 5) out = conv3x3(gated, ar_w)  512 -> 72, MFMA implicit GEMM
    conv_ar_mfma_kernel<<<dim3(BB * HH * 2), dim3(256), 0, stream>>>(
        gated_t, wpack, ar_b, out);
}

// Round 13
// 456.215 us; speedup vs baseline: 10.3686x; 1.0525x over previous
//
#include <hip/hip_runtime.h>
#include <hip/hip_bf16.h>

#define BB 2
#define HH 256
#define WW 256
#define HW (HH*WW)

typedef __attribute__((ext_vector_type(8))) short bf16x8;
typedef __attribute__((ext_vector_type(4))) float f32x4;

__device__ __forceinline__ float geluf(float x) {
    return 0.5f * x * (1.0f + erff(x * 0.7071067811865475f));
}

__device__ __forceinline__ ushort f2bf(float f) {
    __hip_bfloat16 h = __float2bfloat16(f);
    return *reinterpret_cast<ushort*>(&h);
}
__device__ __forceinline__ float bf2f(ushort u) {
    uint v = ((uint)u) << 16;
    return *reinterpret_cast<float*>(&v);
}

// compact index [0,96) -> actual coordinate (rows/cols = 0,2,6 mod 8)
__device__ __forceinline__ int dec96(int i) {
    int q = i / 3, r = i - q * 3;
    return q * 8 + (r == 0 ? 0 : (r == 1 ? 2 : 6));
}

// x (NCHW fp32, 72ch) -> xt (NHWC bf16, 96ch zero-padded).
__global__ __launch_bounds__(256) void xpose_kernel(
    const float* __restrict__ x, ushort* __restrict__ xt)
{
    const int pix = blockIdx.x * 256 + threadIdx.x;   // [0, BB*HW)
    const int b   = pix >> 16;
    const int rem = pix & 65535;

    uint w[48];
    const float* xb = x + (size_t)b * 72 * HW + rem;
    #pragma unroll
    for (int i = 0; i < 36; ++i) {
        const ushort lo = f2bf(xb[(size_t)(2 * i)     * HW]);
        const ushort hi = f2bf(xb[(size_t)(2 * i + 1) * HW]);
        w[i] = (uint)lo | ((uint)hi << 16);
    }
    #pragma unroll
    for (int i = 36; i < 48; ++i) w[i] = 0;

    uint* dst = reinterpret_cast<uint*>(xt + (size_t)pix * 96);
    #pragma unroll
    for (int k = 0; k < 12; ++k) {
        uint4 u = { w[4*k], w[4*k+1], w[4*k+2], w[4*k+3] };
        *reinterpret_cast<uint4*>(dst + 4 * k) = u;
    }
}

// Prepack fused conv1(64co)+dw1(32co) weights into MFMA A-frag order.
__global__ __launch_bounds__(256) void prepack_w1_kernel(
    const float* __restrict__ conv_w, const float* __restrict__ dw1_w,
    ushort* __restrict__ wpc1)
{
    const int idx = blockIdx.x * 256 + threadIdx.x;   // 9*3*6*64 = 10368
    if (idx >= 9 * 3 * 6 * 64) return;
    const int lane = idx & 63;
    int rest = idx >> 6;
    const int mf = rest % 6; rest /= 6;
    const int cb = rest % 3;
    const int t  = rest / 3;
    const int co  = mf * 16 + (lane & 15);
    const int ci0 = cb * 32 + (lane >> 4) * 8;
    ushort* dst = wpc1 + (size_t)idx * 8;
    #pragma unroll
    for (int j = 0; j < 8; ++j) {
        const int ci = ci0 + j;
        float w = 0.0f;
        if (ci < 72)
            w = (co < 64) ? conv_w[((size_t)co * 72 + ci) * 9 + t]
                          : dw1_w[((size_t)(co - 64) * 72 + ci) * 9 + t];
        dst[j] = f2bf(w);
    }
}

// Fused conv1+dw1 as MFMA implicit GEMM (M=96, K=9*96) over xt.
__global__ __launch_bounds__(256) void conv1dw1_mfma_kernel(
    const ushort* __restrict__ xt, const ushort* __restrict__ wpc1,
    const float* __restrict__ conv_b, const float* __restrict__ dw1_b,
    ushort* __restrict__ fg, float* __restrict__ relu1)
{
    const int lane = threadIdx.x & 63;
    const int wave = threadIdx.x >> 6;
    const int l15  = lane & 15;
    const int lg   = lane >> 4;

    const int bid  = blockIdx.x;          // 1024 = b(2) * y(256) * half(2)
    const int b    = bid >> 9;
    const int rest = bid & 511;
    const int y    = rest >> 1;
    const int x0   = (rest & 1) * 128 + wave * 32;

    f32x4 acc[6][2];
    #pragma unroll
    for (int mf = 0; mf < 6; ++mf)
        #pragma unroll
        for (int nf = 0; nf < 2; ++nf)
            acc[mf][nf] = (f32x4){0.f, 0.f, 0.f, 0.f};

    const bf16x8 zero8 = {};

    #pragma unroll 1
    for (int t = 0; t < 9; ++t) {
        const int dy = t / 3 - 1, dx = t % 3 - 1;
        const int yy = y + dy;
        if ((unsigned)yy >= (unsigned)HH) continue;

        const int xA = x0 + l15 + dx;
        const int xB = xA + 16;
        const bool va = (unsigned)xA < (unsigned)WW;
        const bool vb = (unsigned)xB < (unsigned)WW;
        const int xAc = min(max(xA, 0), WW - 1);
        const int xBc = min(xB, WW - 1);

        const ushort* rowbase = xt + ((size_t)(b * HH + yy) * WW) * 96;
        const ushort* pA = rowbase + (size_t)xAc * 96 + lg * 8;
        const ushort* pB = rowbase + (size_t)xBc * 96 + lg * 8;
        const ushort* wp = wpc1 + (size_t)(t * 3) * (6 * 512) + lane * 8;

        #pragma unroll
        for (int cb = 0; cb < 3; ++cb) {
            bf16x8 B0 = *reinterpret_cast<const bf16x8*>(pA + cb * 32);
            bf16x8 B1 = *reinterpret_cast<const bf16x8*>(pB + cb * 32);
            B0 = va ? B0 : zero8;
            B1 = vb ? B1 : zero8;
            const ushort* wpc = wp + (size_t)cb * (6 * 512);
            #pragma unroll
            for (int mf = 0; mf < 6; ++mf) {
                const bf16x8 A = *reinterpret_cast<const bf16x8*>(wpc + mf * 512);
                acc[mf][0] = __builtin_amdgcn_mfma_f32_16x16x32_bf16(A, B0, acc[mf][0], 0, 0, 0);
                acc[mf][1] = __builtin_amdgcn_mfma_f32_16x16x32_bf16(A, B1, acc[mf][1], 0, 0, 0);
            }
        }
    }

    #pragma unroll
    for (int nf = 0; nf < 2; ++nf) {
        const int xx = x0 + nf * 16 + l15;
        ushort* fgp = fg + ((size_t)(b * HH + y) * WW + xx) * 64;
        #pragma unroll
        for (int mf = 0; mf < 4; ++mf) {
            const int co = mf * 16 + lg * 4;
            ushort pk[4];
            #pragma unroll
            for (int r = 0; r < 4; ++r)
                pk[r] = f2bf(geluf(acc[mf][nf][r] + conv_b[co + r]));
            *reinterpret_cast<uint2*>(fgp + co) = *reinterpret_cast<uint2*>(pk);
        }
    }
    #pragma unroll
    for (int mf = 4; mf < 6; ++mf) {
        const int co = (mf - 4) * 16 + lg * 4;
        #pragma unroll
        for (int nf = 0; nf < 2; ++nf) {
            const int xx = x0 + nf * 16 + l15;
            float* op = relu1 + ((size_t)(b * 32 + co) * HH + y) * WW + xx;
            #pragma unroll
            for (int r = 0; r < 4; ++r)
                op[(size_t)r * HW] = fmaxf(acc[mf][nf][r] + dw1_b[co + r], 0.0f);
        }
    }
}

// Prepack ddct weights (7 layers) into MFMA A-fragment order.
__global__ __launch_bounds__(256) void prepack_wb_kernel(
    const float* __restrict__ ddct_w, ushort* __restrict__ wpb)
{
    const int idx = blockIdx.x * 256 + threadIdx.x;   // 7*9*2*4*64 = 32256
    if (idx >= 7 * 9 * 2 * 4 * 64) return;
    const int lane = idx & 63;
    int rest = idx >> 6;
    const int mf = rest & 3; rest >>= 2;
    const int cb = rest & 1; rest >>= 1;
    const int t  = rest % 9;
    const int li = rest / 9;
    const int co  = mf * 16 + (lane & 15);
    const int ci0 = cb * 32 + (lane >> 4) * 8;
    ushort* dst = wpb + (size_t)idx * 8;
    #pragma unroll
    for (int j = 0; j < 8; ++j)
        dst[j] = f2bf(ddct_w[(((size_t)li * 64 + co) * 64 + ci0 + j) * 9 + t]);
}

// All 7 branch convs on the compact 96x96 grid as MFMA implicit GEMM.
__global__ __launch_bounds__(256) void branch_mfma_kernel(
    const ushort* __restrict__ fg, const ushort* __restrict__ wpb,
    const float* __restrict__ ddct_b, float* __restrict__ ycomp)
{
    const int lane = threadIdx.x & 63;
    const int wave = threadIdx.x >> 6;
    const int l15  = lane & 15;
    const int lg   = lane >> 4;

    int bid = blockIdx.x;              // (li*BB+b)*72 + t72
    const int t72 = bid % 72; bid /= 72;
    const int b  = bid & 1;
    const int li = bid >> 1;
    const int widx = t72 * 4 + wave;
    const int r  = widx / 3;
    const int c0 = (widx - r * 3) * 32;
    const int R  = dec96(r);

    const int cA = c0 + l15, cB = cA + 16;
    const int CA = dec96(cA), CB2 = dec96(cB);

    f32x4 acc[4][2];
    #pragma unroll
    for (int mf = 0; mf < 4; ++mf)
        #pragma unroll
        for (int nf = 0; nf < 2; ++nf)
            acc[mf][nf] = (f32x4){0.f, 0.f, 0.f, 0.f};

    const bf16x8 zero8 = {};
    const ushort* fgb = fg + (size_t)b * HW * 64;

    #pragma unroll 1
    for (int t = 0; t < 9; ++t) {
        const int dy = t / 3 - 1, dx = t % 3 - 1;
        const int yy = R + dy;
        if ((unsigned)yy >= (unsigned)HH) continue;

        const int xA = CA + dx, xB = CB2 + dx;
        const bool va = (unsigned)xA < (unsigned)WW;
        const bool vb = (unsigned)xB < (unsigned)WW;
        const int xAc = min(max(xA, 0), WW - 1);
        const int xBc = min(max(xB, 0), WW - 1);

        const ushort* rowb = fgb + (size_t)yy * WW * 64;
        const ushort* pA = rowb + (size_t)xAc * 64 + lg * 8;
        const ushort* pB = rowb + (size_t)xBc * 64 + lg * 8;
        const ushort* wp = wpb + (size_t)((li * 9 + t) * 2) * (4 * 512) + lane * 8;

        #pragma unroll
        for (int cb = 0; cb < 2; ++cb) {
            bf16x8 B0 = *reinterpret_cast<const bf16x8*>(pA + cb * 32);
            bf16x8 B1 = *reinterpret_cast<const bf16x8*>(pB + cb * 32);
            B0 = va ? B0 : zero8;
            B1 = vb ? B1 : zero8;
            const ushort* wpc = wp + (size_t)cb * (4 * 512);
            #pragma unroll
            for (int mf = 0; mf < 4; ++mf) {
                const bf16x8 A = *reinterpret_cast<const bf16x8*>(wpc + mf * 512);
                acc[mf][0] = __builtin_amdgcn_mfma_f32_16x16x32_bf16(A, B0, acc[mf][0], 0, 0, 0);
                acc[mf][1] = __builtin_amdgcn_mfma_f32_16x16x32_bf16(A, B1, acc[mf][1], 0, 0, 0);
            }
        }
    }

    #pragma unroll
    for (int nf = 0; nf < 2; ++nf) {
        const int c = c0 + nf * 16 + l15;
        const int C = dec96(c);
        const ushort* res = fgb + ((size_t)R * WW + C) * 64;
        #pragma unroll
        for (int mf = 0; mf < 4; ++mf) {
            const int co = mf * 16 + lg * 4;
            ushort r4[4];
            *reinterpret_cast<uint2*>(r4) = *reinterpret_cast<const uint2*>(res + co);
            #pragma unroll
            for (int rr = 0; rr < 4; ++rr) {
                const float v = geluf(acc[mf][nf][rr] + ddct_b[li * 64 + co + rr]) + bf2f(r4[rr]);
                ycomp[((((size_t)li * BB + b) * 64 + co + rr) * 96 + r) * 96 + c] = v;
            }
        }
    }
}

// Depthwise 3x3 stride 8 dil 2 pad 2 -> 32x32 (DCT->IDCT identity skipped).
__global__ __launch_bounds__(256) void dctc_kernel(
    const float* __restrict__ ycomp, const float* __restrict__ dctc_w,
    const float* __restrict__ dctc_b, float* __restrict__ s_all)
{
    const int idx = blockIdx.x * 256 + threadIdx.x;
    if (idx >= 7 * BB * 64 * 32 * 32) return;
    const int ow = idx & 31;
    const int oh = (idx >> 5) & 31;
    const int c  = (idx >> 10) & 63;
    const int b  = (idx >> 16) & (BB - 1);
    const int li = idx >> 17;

    const float* yc = ycomp + (((size_t)li * BB + b) * 64 + c) * (96 * 96);
    const float* w  = dctc_w + (li * 64 + c) * 9;
    float acc = dctc_b[li * 64 + c];
    #pragma unroll
    for (int ky = 0; ky < 3; ++ky) {
        const int cr = 3 * oh + ky - 1;
        if (cr < 0) continue;
        #pragma unroll
        for (int kx = 0; kx < 3; ++kx) {
            const int cc = 3 * ow + kx - 1;
            if (cc < 0) continue;
            acc = fmaf(yc[cr * 96 + cc], w[ky * 3 + kx], acc);
        }
    }
    s_all[idx] = acc;
}

// Gate + bilinear upsample + multiply, writing gated in NHWC bf16.
__global__ __launch_bounds__(256) void gated_nhwc_kernel(
    const float* __restrict__ relu1, const float* __restrict__ dw3_w,
    const float* __restrict__ dw3_b, const float* __restrict__ s_all,
    ushort* __restrict__ gt)
{
    __shared__ float sm[32][32];   // [k][px]
    const int pix0 = blockIdx.x * 32;
    const int b  = pix0 >> 16;
    const int y  = (pix0 >> 8) & 255;
    const int x0 = pix0 & 255;

    {
        const int spx = threadIdx.x & 31;
        const int k0  = threadIdx.x >> 5;
        const float* rbase = relu1 + (size_t)b * 32 * HW + (size_t)y * WW + x0 + spx;
        #pragma unroll
        for (int i = 0; i < 4; ++i)
            sm[k0 + 8 * i][spx] = rbase[(size_t)(k0 + 8 * i) * HW];
    }
    __syncthreads();

    const int ch0 = threadIdx.x * 2;
    const int branch = ch0 >> 6;
    const int c0 = ch0 & 63;
    const int lmap[8] = {0, 1, 2, 3, 4, 3, 5, 6};
    const int li = lmap[branch];

    const float bb0 = dw3_b[ch0], bb1 = dw3_b[ch0 + 1];

    float acc0[32], acc1[32];
    #pragma unroll
    for (int px = 0; px < 32; ++px) { acc0[px] = bb0; acc1[px] = bb1; }

    const float* wp0 = dw3_w + ch0 * 32;
    #pragma unroll
    for (int k = 0; k < 32; ++k) {
        const float w0k = wp0[k];
        const float w1k = wp0[32 + k];
        const float4* row = reinterpret_cast<const float4*>(&sm[k][0]);
        #pragma unroll
        for (int q = 0; q < 8; ++q) {
            const float4 r4 = row[q];
            acc0[q*4+0] = fmaf(r4.x, w0k, acc0[q*4+0]);
            acc0[q*4+1] = fmaf(r4.y, w0k, acc0[q*4+1]);
            acc0[q*4+2] = fmaf(r4.z, w0k, acc0[q*4+2]);
            acc0[q*4+3] = fmaf(r4.w, w0k, acc0[q*4+3]);
            acc1[q*4+0] = fmaf(r4.x, w1k, acc1[q*4+0]);
            acc1[q*4+1] = fmaf(r4.y, w1k, acc1[q*4+1]);
            acc1[q*4+2] = fmaf(r4.z, w1k, acc1[q*4+2]);
            acc1[q*4+3] = fmaf(r4.w, w1k, acc1[q*4+3]);
        }
    }

    const float* sp0 = s_all + (((size_t)li * BB + b) * 64 + c0) * 1024;
    const float* sp1 = sp0 + 1024;

    const float sy = (y + 0.5f) * 0.125f - 0.5f;
    const float fy0f = floorf(sy);
    const float fy = sy - fy0f;
    int y0 = (int)fy0f;
    const int y1 = min(y0 + 1, 31);
    y0 = max(y0, 0);

    float n0[6], n1[6];
    const int xb = (x0 >> 3) - 1;
    #pragma unroll
    for (int jj = 0; jj < 6; ++jj) {
        const int xn = min(max(xb + jj, 0), 31);
        const float a00 = sp0[y0 * 32 + xn], a01 = sp0[y1 * 32 + xn];
        const float a10 = sp1[y0 * 32 + xn], a11 = sp1[y1 * 32 + xn];
        n0[jj] = a00 + fy * (a01 - a00);
        n1[jj] = a10 + fy * (a11 - a10);
    }

    ushort* gbase = gt + (size_t)pix0 * 512 + ch0;
    #pragma unroll
    for (int px = 0; px < 32; ++px) {
        const int   j  = (px + 4) >> 3;
        const float fx = (float)((px + 4) & 7) * 0.125f + 0.0625f;
        const float va = n0[j] + fx * (n0[j + 1] - n0[j]);
        const float vb = n1[j] + fx * (n1[j + 1] - n1[j]);
        const float g0 = 1.0f / (1.0f + exp2f(-1.4426950408889634f * acc0[px]));
        const float g1 = 1.0f / (1.0f + exp2f(-1.4426950408889634f * acc1[px]));
        const uint pack = (uint)f2bf(va * g0) | ((uint)f2bf(vb * g1) << 16);
        *reinterpret_cast<uint*>(gbase + (size_t)px * 512) = pack;
    }
}

// Prepack ar_w into MFMA A-fragment order (bf16).
__global__ __launch_bounds__(256) void prepack_w_kernel(
    const float* __restrict__ ar_w, ushort* __restrict__ wpack)
{
    const int idx = blockIdx.x * 256 + threadIdx.x;   // 9*16*5*64 = 46080
    if (idx >= 9 * 16 * 5 * 64) return;
    const int lane = idx & 63;
    int rest = idx >> 6;
    const int mf = rest % 5; rest /= 5;
    const int cb = rest & 15;
    const int t  = rest >> 4;
    const int co  = mf * 16 + (lane & 15);
    const int ci0 = cb * 32 + (lane >> 4) * 8;
    ushort* dst = wpack + (size_t)idx * 8;
    #pragma unroll
    for (int j = 0; j < 8; ++j) {
        const float w = (co < 72) ? ar_w[((size_t)co * 512 + ci0 + j) * 9 + t] : 0.0f;
        dst[j] = f2bf(w);
    }
}

// Final conv 512->72 as implicit GEMM on MFMA (NHWC bf16 input).
// v3: 64 px per wave (acc[5][4]) — doubles MFMA cover per load window,
// halves per-wave A-fragment L2 streaming (round-11: latency-bound at
// VGPR=60, MfmaUtil 17%). Block = 4 waves = full 256-px row. Keeps
// bijective XCD swizzle + cb-outer/tap-inner K loop from v2.
__global__ __launch_bounds__(256) void conv_ar_mfma_kernel(
    const ushort* __restrict__ gt, const ushort* __restrict__ wpack,
    const float* __restrict__ ar_b, float* __restrict__ out)
{
    const int lane = threadIdx.x & 63;
    const int wave = threadIdx.x >> 6;
    const int l15  = lane & 15;
    const int lg   = lane >> 4;

    // bijective XCD swizzle: nwg=512, 8 XCDs, 64 logical blocks per XCD
    const int lb = (blockIdx.x & 7) * 64 + (blockIdx.x >> 3);
    const int b  = lb >> 8;
    const int y  = lb & 255;
    const int x0 = wave * 64;

    f32x4 acc[5][4];
    #pragma unroll
    for (int mf = 0; mf < 5; ++mf)
        #pragma unroll
        for (int nf = 0; nf < 4; ++nf)
            acc[mf][nf] = (f32x4){0.f, 0.f, 0.f, 0.f};

    // hoisted row pointers / x offsets (uniform over K loop)
    const ushort* rowp[3];
    bool rowok[3];
    #pragma unroll
    for (int dy = 0; dy < 3; ++dy) {
        const int yy = y + dy - 1;
        rowok[dy] = (unsigned)yy < (unsigned)HH;
        rowp[dy]  = gt + ((size_t)(b * HH + (rowok[dy] ? yy : 0)) * WW) * 512;
    }
    int  offx[3][4];
    bool vx[3][4];
    #pragma unroll
    for (int dx = 0; dx < 3; ++dx) {
        #pragma unroll
        for (int nf = 0; nf < 4; ++nf) {
            const int xx = x0 + nf * 16 + l15 + dx - 1;
            vx[dx][nf]   = (unsigned)xx < (unsigned)WW;
            offx[dx][nf] = min(max(xx, 0), WW - 1) * 512 + lg * 8;
        }
    }

    const bf16x8 zero8 = {};

    #pragma unroll 1
    for (int cb = 0; cb < 16; ++cb) {
        const int cbo = cb * 32;
        #pragma unroll
        for (int t = 0; t < 9; ++t) {
            const int dy = t / 3, dx = t % 3;
            if (!rowok[dy]) continue;   // wave-uniform
            bf16x8 Bv[4];
            #pragma unroll
            for (int nf = 0; nf < 4; ++nf) {
                bf16x8 v = *reinterpret_cast<const bf16x8*>(rowp[dy] + offx[dx][nf] + cbo);
                Bv[nf] = vx[dx][nf] ? v : zero8;
            }
            const ushort* wpc = wpack + (size_t)(t * 16 + cb) * (5 * 512) + lane * 8;
            #pragma unroll
            for (int mf = 0; mf < 5; ++mf) {
                const bf16x8 A = *reinterpret_cast<const bf16x8*>(wpc + mf * 512);
                #pragma unroll
                for (int nf = 0; nf < 4; ++nf)
                    acc[mf][nf] = __builtin_amdgcn_mfma_f32_16x16x32_bf16(A, Bv[nf], acc[mf][nf], 0, 0, 0);
            }
        }
    }

    #pragma unroll
    for (int mf = 0; mf < 5; ++mf) {
        const int co = mf * 16 + lg * 4;
        if (co >= 72) continue;
        #pragma unroll
        for (int nf = 0; nf < 4; ++nf) {
            const int x = x0 + nf * 16 + l15;
            float* op = out + (((size_t)(b * 72 + co) * HH + y) * WW) + x;
            #pragma unroll
            for (int r = 0; r < 4; ++r)
                op[(size_t)r * HW] = acc[mf][nf][r] + ar_b[co + r];
        }
    }
}

extern "C" void kernel_launch(void* const* d_in, const int* in_sizes, int n_in,
                              void* d_out, int out_size, void* d_ws, size_t ws_size,
                              hipStream_t stream) {
    const float* x      = (const float*)d_in[0];
    const float* conv_w = (const float*)d_in[1];
    const float* conv_b = (const float*)d_in[2];
    const float* ddct_w = (const float*)d_in[3];
    const float* ddct_b = (const float*)d_in[4];
    const float* dctc_w = (const float*)d_in[5];
    const float* dctc_b = (const float*)d_in[6];
    const float* dw1_w  = (const float*)d_in[7];
    const float* dw1_b  = (const float*)d_in[8];
    const float* dw3_w  = (const float*)d_in[9];
    const float* dw3_b  = (const float*)d_in[10];
    const float* ar_w   = (const float*)d_in[11];
    const float* ar_b   = (const float*)d_in[12];
    float* out = (float*)d_out;

    float* ws = (float*)d_ws;
    // Layout (float slots). fg + ycomp are dead before gated_t is written.
    ushort* gated_t = (ushort*)ws;               // [0 .. 33,554,432) f
    ushort* fg    = (ushort*)ws;                 // [0 .. 4,194,304) f
    float* ycomp  = ws + 4194304;                // -> ends 12,451,840
    float* s_all  = ws + 33554432;               // 917,504 f
    float* relu1  = ws + 34471936;               // 4,194,304 f
    ushort* wpack = (ushort*)(ws + 38666240);    // -> ends 38,850,560 f
    ushort* wpb   = (ushort*)(ws + 38850560);    // -> ends 38,979,584 f
    ushort* wpc1  = (ushort*)(ws + 38979584);    // -> ends 39,021,056 f
    ushort* xt    = (ushort*)(ws + 39021056);    // -> ends 45,312,512 f

    // 0) weight prepacks + x transpose
    prepack_w_kernel<<<dim3(180), dim3(256), 0, stream>>>(ar_w, wpack);
    prepack_wb_kernel<<<dim3(126), dim3(256), 0, stream>>>(ddct_w, wpb);
    prepack_w1_kernel<<<dim3(41), dim3(256), 0, stream>>>(conv_w, dw1_w, wpc1);
    xpose_kernel<<<dim3(BB * HW / 256), dim3(256), 0, stream>>>(x, xt);

    // 1) fused conv1 (fg NHWC bf16, gelu) + dw1 (relu1 NCHW fp32, relu)
    conv1dw1_mfma_kernel<<<dim3(BB * HH * 2), dim3(256), 0, stream>>>(
        xt, wpc1, conv_b, dw1_b, fg, relu1);

    // 2) branch convs (7 layers) as MFMA implicit GEMM on compact grid
    branch_mfma_kernel<<<dim3(7 * BB * 72), dim3(256), 0, stream>>>(
        fg, wpb, ddct_b, ycomp);

    // 3) depthwise stride-8 convs
    dctc_kernel<<<dim3((7 * BB * 64 * 32 * 32) / 256), dim3(256), 0, stream>>>(
        ycomp, dctc_w, dctc_b, s_all);

    // 4) gated (NHWC bf16) = upsample(s) * sigmoid(1x1conv(relu1))
    gated_nhwc_kernel<<<dim3(BB * HW / 32), dim3(256), 0, stream>>>(
        relu1, dw3_w, dw3_b, s_all, gated_t);

    // 5) out = conv3x3(gated, ar_w)  512 -> 72, MFMA implicit GEMM (64px/wave)
    conv_ar_mfma_kernel<<<dim3(BB * HH), dim3(256), 0, stream>>>(
        gated_t, wpack, ar_b, out);
}

// Round 14
// 430.768 us; speedup vs baseline: 10.9811x; 1.0591x over previous
//
#include <hip/hip_runtime.h>
#include <hip/hip_bf16.h>

#define BB 2
#define HH 256
#define WW 256
#define HW (HH*WW)

typedef __attribute__((ext_vector_type(8))) short bf16x8;
typedef __attribute__((ext_vector_type(4))) float f32x4;

__device__ __forceinline__ float geluf(float x) {
    return 0.5f * x * (1.0f + erff(x * 0.7071067811865475f));
}

__device__ __forceinline__ ushort f2bf(float f) {
    __hip_bfloat16 h = __float2bfloat16(f);
    return *reinterpret_cast<ushort*>(&h);
}
__device__ __forceinline__ float bf2f(ushort u) {
    uint v = ((uint)u) << 16;
    return *reinterpret_cast<float*>(&v);
}

// compact index [0,96) -> actual coordinate (rows/cols = 0,2,6 mod 8)
__device__ __forceinline__ int dec96(int i) {
    int q = i / 3, r = i - q * 3;
    return q * 8 + (r == 0 ? 0 : (r == 1 ? 2 : 6));
}

// x (NCHW fp32, 72ch) -> xt (NHWC bf16, 96ch zero-padded).
__global__ __launch_bounds__(256) void xpose_kernel(
    const float* __restrict__ x, ushort* __restrict__ xt)
{
    const int pix = blockIdx.x * 256 + threadIdx.x;   // [0, BB*HW)
    const int b   = pix >> 16;
    const int rem = pix & 65535;

    uint w[48];
    const float* xb = x + (size_t)b * 72 * HW + rem;
    #pragma unroll
    for (int i = 0; i < 36; ++i) {
        const ushort lo = f2bf(xb[(size_t)(2 * i)     * HW]);
        const ushort hi = f2bf(xb[(size_t)(2 * i + 1) * HW]);
        w[i] = (uint)lo | ((uint)hi << 16);
    }
    #pragma unroll
    for (int i = 36; i < 48; ++i) w[i] = 0;

    uint* dst = reinterpret_cast<uint*>(xt + (size_t)pix * 96);
    #pragma unroll
    for (int k = 0; k < 12; ++k) {
        uint4 u = { w[4*k], w[4*k+1], w[4*k+2], w[4*k+3] };
        *reinterpret_cast<uint4*>(dst + 4 * k) = u;
    }
}

// Prepack fused conv1(64co)+dw1(32co) weights into MFMA A-frag order.
__global__ __launch_bounds__(256) void prepack_w1_kernel(
    const float* __restrict__ conv_w, const float* __restrict__ dw1_w,
    ushort* __restrict__ wpc1)
{
    const int idx = blockIdx.x * 256 + threadIdx.x;   // 9*3*6*64 = 10368
    if (idx >= 9 * 3 * 6 * 64) return;
    const int lane = idx & 63;
    int rest = idx >> 6;
    const int mf = rest % 6; rest /= 6;
    const int cb = rest % 3;
    const int t  = rest / 3;
    const int co  = mf * 16 + (lane & 15);
    const int ci0 = cb * 32 + (lane >> 4) * 8;
    ushort* dst = wpc1 + (size_t)idx * 8;
    #pragma unroll
    for (int j = 0; j < 8; ++j) {
        const int ci = ci0 + j;
        float w = 0.0f;
        if (ci < 72)
            w = (co < 64) ? conv_w[((size_t)co * 72 + ci) * 9 + t]
                          : dw1_w[((size_t)(co - 64) * 72 + ci) * 9 + t];
        dst[j] = f2bf(w);
    }
}

// Fused conv1+dw1 as MFMA implicit GEMM (M=96, K=9*96) over xt.
__global__ __launch_bounds__(256) void conv1dw1_mfma_kernel(
    const ushort* __restrict__ xt, const ushort* __restrict__ wpc1,
    const float* __restrict__ conv_b, const float* __restrict__ dw1_b,
    ushort* __restrict__ fg, float* __restrict__ relu1)
{
    const int lane = threadIdx.x & 63;
    const int wave = threadIdx.x >> 6;
    const int l15  = lane & 15;
    const int lg   = lane >> 4;

    const int bid  = blockIdx.x;          // 1024 = b(2) * y(256) * half(2)
    const int b    = bid >> 9;
    const int rest = bid & 511;
    const int y    = rest >> 1;
    const int x0   = (rest & 1) * 128 + wave * 32;

    f32x4 acc[6][2];
    #pragma unroll
    for (int mf = 0; mf < 6; ++mf)
        #pragma unroll
        for (int nf = 0; nf < 2; ++nf)
            acc[mf][nf] = (f32x4){0.f, 0.f, 0.f, 0.f};

    const bf16x8 zero8 = {};

    #pragma unroll 1
    for (int t = 0; t < 9; ++t) {
        const int dy = t / 3 - 1, dx = t % 3 - 1;
        const int yy = y + dy;
        if ((unsigned)yy >= (unsigned)HH) continue;

        const int xA = x0 + l15 + dx;
        const int xB = xA + 16;
        const bool va = (unsigned)xA < (unsigned)WW;
        const bool vb = (unsigned)xB < (unsigned)WW;
        const int xAc = min(max(xA, 0), WW - 1);
        const int xBc = min(xB, WW - 1);

        const ushort* rowbase = xt + ((size_t)(b * HH + yy) * WW) * 96;
        const ushort* pA = rowbase + (size_t)xAc * 96 + lg * 8;
        const ushort* pB = rowbase + (size_t)xBc * 96 + lg * 8;
        const ushort* wp = wpc1 + (size_t)(t * 3) * (6 * 512) + lane * 8;

        #pragma unroll
        for (int cb = 0; cb < 3; ++cb) {
            bf16x8 B0 = *reinterpret_cast<const bf16x8*>(pA + cb * 32);
            bf16x8 B1 = *reinterpret_cast<const bf16x8*>(pB + cb * 32);
            B0 = va ? B0 : zero8;
            B1 = vb ? B1 : zero8;
            const ushort* wpc = wp + (size_t)cb * (6 * 512);
            #pragma unroll
            for (int mf = 0; mf < 6; ++mf) {
                const bf16x8 A = *reinterpret_cast<const bf16x8*>(wpc + mf * 512);
                acc[mf][0] = __builtin_amdgcn_mfma_f32_16x16x32_bf16(A, B0, acc[mf][0], 0, 0, 0);
                acc[mf][1] = __builtin_amdgcn_mfma_f32_16x16x32_bf16(A, B1, acc[mf][1], 0, 0, 0);
            }
        }
    }

    #pragma unroll
    for (int nf = 0; nf < 2; ++nf) {
        const int xx = x0 + nf * 16 + l15;
        ushort* fgp = fg + ((size_t)(b * HH + y) * WW + xx) * 64;
        #pragma unroll
        for (int mf = 0; mf < 4; ++mf) {
            const int co = mf * 16 + lg * 4;
            ushort pk[4];
            #pragma unroll
            for (int r = 0; r < 4; ++r)
                pk[r] = f2bf(geluf(acc[mf][nf][r] + conv_b[co + r]));
            *reinterpret_cast<uint2*>(fgp + co) = *reinterpret_cast<uint2*>(pk);
        }
    }
    #pragma unroll
    for (int mf = 4; mf < 6; ++mf) {
        const int co = (mf - 4) * 16 + lg * 4;
        #pragma unroll
        for (int nf = 0; nf < 2; ++nf) {
            const int xx = x0 + nf * 16 + l15;
            float* op = relu1 + ((size_t)(b * 32 + co) * HH + y) * WW + xx;
            #pragma unroll
            for (int r = 0; r < 4; ++r)
                op[(size_t)r * HW] = fmaxf(acc[mf][nf][r] + dw1_b[co + r], 0.0f);
        }
    }
}

// Prepack ddct weights (7 layers) into MFMA A-fragment order.
__global__ __launch_bounds__(256) void prepack_wb_kernel(
    const float* __restrict__ ddct_w, ushort* __restrict__ wpb)
{
    const int idx = blockIdx.x * 256 + threadIdx.x;   // 7*9*2*4*64 = 32256
    if (idx >= 7 * 9 * 2 * 4 * 64) return;
    const int lane = idx & 63;
    int rest = idx >> 6;
    const int mf = rest & 3; rest >>= 2;
    const int cb = rest & 1; rest >>= 1;
    const int t  = rest % 9;
    const int li = rest / 9;
    const int co  = mf * 16 + (lane & 15);
    const int ci0 = cb * 32 + (lane >> 4) * 8;
    ushort* dst = wpb + (size_t)idx * 8;
    #pragma unroll
    for (int j = 0; j < 8; ++j)
        dst[j] = f2bf(ddct_w[(((size_t)li * 64 + co) * 64 + ci0 + j) * 9 + t]);
}

// All 7 branch convs on the compact 96x96 grid as MFMA implicit GEMM.
__global__ __launch_bounds__(256) void branch_mfma_kernel(
    const ushort* __restrict__ fg, const ushort* __restrict__ wpb,
    const float* __restrict__ ddct_b, float* __restrict__ ycomp)
{
    const int lane = threadIdx.x & 63;
    const int wave = threadIdx.x >> 6;
    const int l15  = lane & 15;
    const int lg   = lane >> 4;

    int bid = blockIdx.x;              // (li*BB+b)*72 + t72
    const int t72 = bid % 72; bid /= 72;
    const int b  = bid & 1;
    const int li = bid >> 1;
    const int widx = t72 * 4 + wave;
    const int r  = widx / 3;
    const int c0 = (widx - r * 3) * 32;
    const int R  = dec96(r);

    const int cA = c0 + l15, cB = cA + 16;
    const int CA = dec96(cA), CB2 = dec96(cB);

    f32x4 acc[4][2];
    #pragma unroll
    for (int mf = 0; mf < 4; ++mf)
        #pragma unroll
        for (int nf = 0; nf < 2; ++nf)
            acc[mf][nf] = (f32x4){0.f, 0.f, 0.f, 0.f};

    const bf16x8 zero8 = {};
    const ushort* fgb = fg + (size_t)b * HW * 64;

    #pragma unroll 1
    for (int t = 0; t < 9; ++t) {
        const int dy = t / 3 - 1, dx = t % 3 - 1;
        const int yy = R + dy;
        if ((unsigned)yy >= (unsigned)HH) continue;

        const int xA = CA + dx, xB = CB2 + dx;
        const bool va = (unsigned)xA < (unsigned)WW;
        const bool vb = (unsigned)xB < (unsigned)WW;
        const int xAc = min(max(xA, 0), WW - 1);
        const int xBc = min(max(xB, 0), WW - 1);

        const ushort* rowb = fgb + (size_t)yy * WW * 64;
        const ushort* pA = rowb + (size_t)xAc * 64 + lg * 8;
        const ushort* pB = rowb + (size_t)xBc * 64 + lg * 8;
        const ushort* wp = wpb + (size_t)((li * 9 + t) * 2) * (4 * 512) + lane * 8;

        #pragma unroll
        for (int cb = 0; cb < 2; ++cb) {
            bf16x8 B0 = *reinterpret_cast<const bf16x8*>(pA + cb * 32);
            bf16x8 B1 = *reinterpret_cast<const bf16x8*>(pB + cb * 32);
            B0 = va ? B0 : zero8;
            B1 = vb ? B1 : zero8;
            const ushort* wpc = wp + (size_t)cb * (4 * 512);
            #pragma unroll
            for (int mf = 0; mf < 4; ++mf) {
                const bf16x8 A = *reinterpret_cast<const bf16x8*>(wpc + mf * 512);
                acc[mf][0] = __builtin_amdgcn_mfma_f32_16x16x32_bf16(A, B0, acc[mf][0], 0, 0, 0);
                acc[mf][1] = __builtin_amdgcn_mfma_f32_16x16x32_bf16(A, B1, acc[mf][1], 0, 0, 0);
            }
        }
    }

    #pragma unroll
    for (int nf = 0; nf < 2; ++nf) {
        const int c = c0 + nf * 16 + l15;
        const int C = dec96(c);
        const ushort* res = fgb + ((size_t)R * WW + C) * 64;
        #pragma unroll
        for (int mf = 0; mf < 4; ++mf) {
            const int co = mf * 16 + lg * 4;
            ushort r4[4];
            *reinterpret_cast<uint2*>(r4) = *reinterpret_cast<const uint2*>(res + co);
            #pragma unroll
            for (int rr = 0; rr < 4; ++rr) {
                const float v = geluf(acc[mf][nf][rr] + ddct_b[li * 64 + co + rr]) + bf2f(r4[rr]);
                ycomp[((((size_t)li * BB + b) * 64 + co + rr) * 96 + r) * 96 + c] = v;
            }
        }
    }
}

// Depthwise 3x3 stride 8 dil 2 pad 2 -> 32x32 (DCT->IDCT identity skipped).
__global__ __launch_bounds__(256) void dctc_kernel(
    const float* __restrict__ ycomp, const float* __restrict__ dctc_w,
    const float* __restrict__ dctc_b, float* __restrict__ s_all)
{
    const int idx = blockIdx.x * 256 + threadIdx.x;
    if (idx >= 7 * BB * 64 * 32 * 32) return;
    const int ow = idx & 31;
    const int oh = (idx >> 5) & 31;
    const int c  = (idx >> 10) & 63;
    const int b  = (idx >> 16) & (BB - 1);
    const int li = idx >> 17;

    const float* yc = ycomp + (((size_t)li * BB + b) * 64 + c) * (96 * 96);
    const float* w  = dctc_w + (li * 64 + c) * 9;
    float acc = dctc_b[li * 64 + c];
    #pragma unroll
    for (int ky = 0; ky < 3; ++ky) {
        const int cr = 3 * oh + ky - 1;
        if (cr < 0) continue;
        #pragma unroll
        for (int kx = 0; kx < 3; ++kx) {
            const int cc = 3 * ow + kx - 1;
            if (cc < 0) continue;
            acc = fmaf(yc[cr * 96 + cc], w[ky * 3 + kx], acc);
        }
    }
    s_all[idx] = acc;
}

// Gate + bilinear upsample + multiply, writing gated in NHWC bf16.
__global__ __launch_bounds__(256) void gated_nhwc_kernel(
    const float* __restrict__ relu1, const float* __restrict__ dw3_w,
    const float* __restrict__ dw3_b, const float* __restrict__ s_all,
    ushort* __restrict__ gt)
{
    __shared__ float sm[32][32];   // [k][px]
    const int pix0 = blockIdx.x * 32;
    const int b  = pix0 >> 16;
    const int y  = (pix0 >> 8) & 255;
    const int x0 = pix0 & 255;

    {
        const int spx = threadIdx.x & 31;
        const int k0  = threadIdx.x >> 5;
        const float* rbase = relu1 + (size_t)b * 32 * HW + (size_t)y * WW + x0 + spx;
        #pragma unroll
        for (int i = 0; i < 4; ++i)
            sm[k0 + 8 * i][spx] = rbase[(size_t)(k0 + 8 * i) * HW];
    }
    __syncthreads();

    const int ch0 = threadIdx.x * 2;
    const int branch = ch0 >> 6;
    const int c0 = ch0 & 63;
    const int lmap[8] = {0, 1, 2, 3, 4, 3, 5, 6};
    const int li = lmap[branch];

    const float bb0 = dw3_b[ch0], bb1 = dw3_b[ch0 + 1];

    float acc0[32], acc1[32];
    #pragma unroll
    for (int px = 0; px < 32; ++px) { acc0[px] = bb0; acc1[px] = bb1; }

    const float* wp0 = dw3_w + ch0 * 32;
    #pragma unroll
    for (int k = 0; k < 32; ++k) {
        const float w0k = wp0[k];
        const float w1k = wp0[32 + k];
        const float4* row = reinterpret_cast<const float4*>(&sm[k][0]);
        #pragma unroll
        for (int q = 0; q < 8; ++q) {
            const float4 r4 = row[q];
            acc0[q*4+0] = fmaf(r4.x, w0k, acc0[q*4+0]);
            acc0[q*4+1] = fmaf(r4.y, w0k, acc0[q*4+1]);
            acc0[q*4+2] = fmaf(r4.z, w0k, acc0[q*4+2]);
            acc0[q*4+3] = fmaf(r4.w, w0k, acc0[q*4+3]);
            acc1[q*4+0] = fmaf(r4.x, w1k, acc1[q*4+0]);
            acc1[q*4+1] = fmaf(r4.y, w1k, acc1[q*4+1]);
            acc1[q*4+2] = fmaf(r4.z, w1k, acc1[q*4+2]);
            acc1[q*4+3] = fmaf(r4.w, w1k, acc1[q*4+3]);
        }
    }

    const float* sp0 = s_all + (((size_t)li * BB + b) * 64 + c0) * 1024;
    const float* sp1 = sp0 + 1024;

    const float sy = (y + 0.5f) * 0.125f - 0.5f;
    const float fy0f = floorf(sy);
    const float fy = sy - fy0f;
    int y0 = (int)fy0f;
    const int y1 = min(y0 + 1, 31);
    y0 = max(y0, 0);

    float n0[6], n1[6];
    const int xb = (x0 >> 3) - 1;
    #pragma unroll
    for (int jj = 0; jj < 6; ++jj) {
        const int xn = min(max(xb + jj, 0), 31);
        const float a00 = sp0[y0 * 32 + xn], a01 = sp0[y1 * 32 + xn];
        const float a10 = sp1[y0 * 32 + xn], a11 = sp1[y1 * 32 + xn];
        n0[jj] = a00 + fy * (a01 - a00);
        n1[jj] = a10 + fy * (a11 - a10);
    }

    ushort* gbase = gt + (size_t)pix0 * 512 + ch0;
    #pragma unroll
    for (int px = 0; px < 32; ++px) {
        const int   j  = (px + 4) >> 3;
        const float fx = (float)((px + 4) & 7) * 0.125f + 0.0625f;
        const float va = n0[j] + fx * (n0[j + 1] - n0[j]);
        const float vb = n1[j] + fx * (n1[j + 1] - n1[j]);
        const float g0 = 1.0f / (1.0f + exp2f(-1.4426950408889634f * acc0[px]));
        const float g1 = 1.0f / (1.0f + exp2f(-1.4426950408889634f * acc1[px]));
        const uint pack = (uint)f2bf(va * g0) | ((uint)f2bf(vb * g1) << 16);
        *reinterpret_cast<uint*>(gbase + (size_t)px * 512) = pack;
    }
}

// Prepack ar_w into MFMA A-fragment order (bf16), CB-MAJOR for LDS staging:
// wpack[(((cb*9 + t)*5 + mf)*64 + lane)*8 + j]
__global__ __launch_bounds__(256) void prepack_w_kernel(
    const float* __restrict__ ar_w, ushort* __restrict__ wpack)
{
    const int idx = blockIdx.x * 256 + threadIdx.x;   // 16*9*5*64 = 46080
    if (idx >= 16 * 9 * 5 * 64) return;
    const int lane = idx & 63;
    int rest = idx >> 6;
    const int mf = rest % 5; rest /= 5;
    const int t  = rest % 9;
    const int cb = rest / 9;
    const int co  = mf * 16 + (lane & 15);
    const int ci0 = cb * 32 + (lane >> 4) * 8;
    ushort* dst = wpack + (size_t)idx * 8;
    #pragma unroll
    for (int j = 0; j < 8; ++j) {
        const float w = (co < 72) ? ar_w[((size_t)co * 512 + ci0 + j) * 9 + t] : 0.0f;
        dst[j] = f2bf(w);
    }
}

#define WPK_CHUNK (9 * 5 * 512)   // ushorts per cb chunk = 23040 (46080 B)

// Final conv 512->72 as implicit GEMM on MFMA (NHWC bf16 input).
// v4: per-cb LDS-staged weights (46 KB, shared by all 4 waves; A-reads become
// conflict-free ds_read_b128) + __launch_bounds__(256,2) so the allocator can
// keep many B-loads in flight (round-13: VGPR=104 left ~3 loads in flight ->
// latency-bound at MfmaUtil 19%). Keeps 64px/wave, bijective XCD swizzle,
// cb-outer/tap-inner K loop.
__global__ __launch_bounds__(256, 2) void conv_ar_mfma_kernel(
    const ushort* __restrict__ gt, const ushort* __restrict__ wpack,
    const float* __restrict__ ar_b, float* __restrict__ out)
{
    __shared__ ushort smw[WPK_CHUNK];
    const int tid  = threadIdx.x;
    const int lane = tid & 63;
    const int wave = tid >> 6;
    const int l15  = lane & 15;
    const int lg   = lane >> 4;

    // bijective XCD swizzle: nwg=512, 8 XCDs, 64 logical blocks per XCD
    const int lb = (blockIdx.x & 7) * 64 + (blockIdx.x >> 3);
    const int b  = lb >> 8;
    const int y  = lb & 255;
    const int x0 = wave * 64;

    f32x4 acc[5][4];
    #pragma unroll
    for (int mf = 0; mf < 5; ++mf)
        #pragma unroll
        for (int nf = 0; nf < 4; ++nf)
            acc[mf][nf] = (f32x4){0.f, 0.f, 0.f, 0.f};

    // hoisted row pointers / x offsets (uniform over K loop)
    const ushort* rowp[3];
    bool rowok[3];
    #pragma unroll
    for (int dy = 0; dy < 3; ++dy) {
        const int yy = y + dy - 1;
        rowok[dy] = (unsigned)yy < (unsigned)HH;
        rowp[dy]  = gt + ((size_t)(b * HH + (rowok[dy] ? yy : 0)) * WW) * 512;
    }
    int  offx[3][4];
    bool vx[3][4];
    #pragma unroll
    for (int dx = 0; dx < 3; ++dx) {
        #pragma unroll
        for (int nf = 0; nf < 4; ++nf) {
            const int xx = x0 + nf * 16 + l15 + dx - 1;
            vx[dx][nf]   = (unsigned)xx < (unsigned)WW;
            offx[dx][nf] = min(max(xx, 0), WW - 1) * 512 + lg * 8;
        }
    }

    const bf16x8 zero8 = {};

    #pragma unroll 1
    for (int cb = 0; cb < 16; ++cb) {
        // stage this cb's weight chunk (46080 B = 2880 uint4) into LDS
        __syncthreads();
        {
            const uint4* src = reinterpret_cast<const uint4*>(wpack + (size_t)cb * WPK_CHUNK);
            uint4* dst = reinterpret_cast<uint4*>(smw);
            #pragma unroll
            for (int i = 0; i < 12; ++i) {
                const int e = i * 256 + tid;
                if (e < 2880) dst[e] = src[e];
            }
        }
        __syncthreads();

        const int cbo = cb * 32;
        #pragma unroll
        for (int t = 0; t < 9; ++t) {
            const int dy = t / 3, dx = t % 3;
            if (!rowok[dy]) continue;   // block-uniform (depends only on y)
            bf16x8 Bv[4];
            #pragma unroll
            for (int nf = 0; nf < 4; ++nf) {
                bf16x8 v = *reinterpret_cast<const bf16x8*>(rowp[dy] + offx[dx][nf] + cbo);
                Bv[nf] = vx[dx][nf] ? v : zero8;
            }
            const ushort* wl = smw + (t * 5) * 512 + lane * 8;
            #pragma unroll
            for (int mf = 0; mf < 5; ++mf) {
                const bf16x8 A = *reinterpret_cast<const bf16x8*>(wl + mf * 512);
                #pragma unroll
                for (int nf = 0; nf < 4; ++nf)
                    acc[mf][nf] = __builtin_amdgcn_mfma_f32_16x16x32_bf16(A, Bv[nf], acc[mf][nf], 0, 0, 0);
            }
        }
    }

    #pragma unroll
    for (int mf = 0; mf < 5; ++mf) {
        const int co = mf * 16 + lg * 4;
        if (co >= 72) continue;
        #pragma unroll
        for (int nf = 0; nf < 4; ++nf) {
            const int x = x0 + nf * 16 + l15;
            float* op = out + (((size_t)(b * 72 + co) * HH + y) * WW) + x;
            #pragma unroll
            for (int r = 0; r < 4; ++r)
                op[(size_t)r * HW] = acc[mf][nf][r] + ar_b[co + r];
        }
    }
}

extern "C" void kernel_launch(void* const* d_in, const int* in_sizes, int n_in,
                              void* d_out, int out_size, void* d_ws, size_t ws_size,
                              hipStream_t stream) {
    const float* x      = (const float*)d_in[0];
    const float* conv_w = (const float*)d_in[1];
    const float* conv_b = (const float*)d_in[2];
    const float* ddct_w = (const float*)d_in[3];
    const float* ddct_b = (const float*)d_in[4];
    const float* dctc_w = (const float*)d_in[5];
    const float* dctc_b = (const float*)d_in[6];
    const float* dw1_w  = (const float*)d_in[7];
    const float* dw1_b  = (const float*)d_in[8];
    const float* dw3_w  = (const float*)d_in[9];
    const float* dw3_b  = (const float*)d_in[10];
    const float* ar_w   = (const float*)d_in[11];
    const float* ar_b   = (const float*)d_in[12];
    float* out = (float*)d_out;

    float* ws = (float*)d_ws;
    // Layout (float slots). fg + ycomp are dead before gated_t is written.
    ushort* gated_t = (ushort*)ws;               // [0 .. 33,554,432) f
    ushort* fg    = (ushort*)ws;                 // [0 .. 4,194,304) f
    float* ycomp  = ws + 4194304;                // -> ends 12,451,840
    float* s_all  = ws + 33554432;               // 917,504 f
    float* relu1  = ws + 34471936;               // 4,194,304 f
    ushort* wpack = (ushort*)(ws + 38666240);    // -> ends 38,850,560 f
    ushort* wpb   = (ushort*)(ws + 38850560);    // -> ends 38,979,584 f
    ushort* wpc1  = (ushort*)(ws + 38979584);    // -> ends 39,021,056 f
    ushort* xt    = (ushort*)(ws + 39021056);    // -> ends 45,312,512 f

    // 0) weight prepacks + x transpose
    prepack_w_kernel<<<dim3(180), dim3(256), 0, stream>>>(ar_w, wpack);
    prepack_wb_kernel<<<dim3(126), dim3(256), 0, stream>>>(ddct_w, wpb);
    prepack_w1_kernel<<<dim3(41), dim3(256), 0, stream>>>(conv_w, dw1_w, wpc1);
    xpose_kernel<<<dim3(BB * HW / 256), dim3(256), 0, stream>>>(x, xt);

    // 1) fused conv1 (fg NHWC bf16, gelu) + dw1 (relu1 NCHW fp32, relu)
    conv1dw1_mfma_kernel<<<dim3(BB * HH * 2), dim3(256), 0, stream>>>(
        xt, wpc1, conv_b, dw1_b, fg, relu1);

    // 2) branch convs (7 layers) as MFMA implicit GEMM on compact grid
    branch_mfma_kernel<<<dim3(7 * BB * 72), dim3(256), 0, stream>>>(
        fg, wpb, ddct_b, ycomp);

    // 3) depthwise stride-8 convs
    dctc_kernel<<<dim3((7 * BB * 64 * 32 * 32) / 256), dim3(256), 0, stream>>>(
        ycomp, dctc_w, dctc_b, s_all);

    // 4) gated (NHWC bf16) = upsample(s) * sigmoid(1x1conv(relu1))
    gated_nhwc_kernel<<<dim3(BB * HW / 32), dim3(256), 0, stream>>>(
        relu1, dw3_w, dw3_b, s_all, gated_t);

    // 5) out = conv3x3(gated, ar_w)  512 -> 72, MFMA implicit GEMM (64px/wave,
    //    LDS-staged weights)
    conv_ar_mfma_kernel<<<dim3(BB * HH), dim3(256), 0, stream>>>(
        gated_t, wpack, ar_b, out);
}

// Round 15
// 402.635 us; speedup vs baseline: 11.7484x; 1.0699x over previous
//
#include <hip/hip_runtime.h>
#include <hip/hip_bf16.h>

#define BB 2
#define HH 256
#define WW 256
#define HW (HH*WW)

typedef __attribute__((ext_vector_type(8))) short bf16x8;
typedef __attribute__((ext_vector_type(4))) float f32x4;

__device__ __forceinline__ float geluf(float x) {
    return 0.5f * x * (1.0f + erff(x * 0.7071067811865475f));
}

__device__ __forceinline__ ushort f2bf(float f) {
    __hip_bfloat16 h = __float2bfloat16(f);
    return *reinterpret_cast<ushort*>(&h);
}
__device__ __forceinline__ float bf2f(ushort u) {
    uint v = ((uint)u) << 16;
    return *reinterpret_cast<float*>(&v);
}

// compact index [0,96) -> actual coordinate (rows/cols = 0,2,6 mod 8)
__device__ __forceinline__ int dec96(int i) {
    int q = i / 3, r = i - q * 3;
    return q * 8 + (r == 0 ? 0 : (r == 1 ? 2 : 6));
}

// x (NCHW fp32, 72ch) -> xt (NHWC bf16, 96ch zero-padded).
__global__ __launch_bounds__(256) void xpose_kernel(
    const float* __restrict__ x, ushort* __restrict__ xt)
{
    const int pix = blockIdx.x * 256 + threadIdx.x;   // [0, BB*HW)
    const int b   = pix >> 16;
    const int rem = pix & 65535;

    uint w[48];
    const float* xb = x + (size_t)b * 72 * HW + rem;
    #pragma unroll
    for (int i = 0; i < 36; ++i) {
        const ushort lo = f2bf(xb[(size_t)(2 * i)     * HW]);
        const ushort hi = f2bf(xb[(size_t)(2 * i + 1) * HW]);
        w[i] = (uint)lo | ((uint)hi << 16);
    }
    #pragma unroll
    for (int i = 36; i < 48; ++i) w[i] = 0;

    uint* dst = reinterpret_cast<uint*>(xt + (size_t)pix * 96);
    #pragma unroll
    for (int k = 0; k < 12; ++k) {
        uint4 u = { w[4*k], w[4*k+1], w[4*k+2], w[4*k+3] };
        *reinterpret_cast<uint4*>(dst + 4 * k) = u;
    }
}

// Prepack fused conv1(64co)+dw1(32co) weights into MFMA A-frag order.
__global__ __launch_bounds__(256) void prepack_w1_kernel(
    const float* __restrict__ conv_w, const float* __restrict__ dw1_w,
    ushort* __restrict__ wpc1)
{
    const int idx = blockIdx.x * 256 + threadIdx.x;   // 9*3*6*64 = 10368
    if (idx >= 9 * 3 * 6 * 64) return;
    const int lane = idx & 63;
    int rest = idx >> 6;
    const int mf = rest % 6; rest /= 6;
    const int cb = rest % 3;
    const int t  = rest / 3;
    const int co  = mf * 16 + (lane & 15);
    const int ci0 = cb * 32 + (lane >> 4) * 8;
    ushort* dst = wpc1 + (size_t)idx * 8;
    #pragma unroll
    for (int j = 0; j < 8; ++j) {
        const int ci = ci0 + j;
        float w = 0.0f;
        if (ci < 72)
            w = (co < 64) ? conv_w[((size_t)co * 72 + ci) * 9 + t]
                          : dw1_w[((size_t)(co - 64) * 72 + ci) * 9 + t];
        dst[j] = f2bf(w);
    }
}

// Fused conv1+dw1 as MFMA implicit GEMM (M=96, K=9*96) over xt.
__global__ __launch_bounds__(256) void conv1dw1_mfma_kernel(
    const ushort* __restrict__ xt, const ushort* __restrict__ wpc1,
    const float* __restrict__ conv_b, const float* __restrict__ dw1_b,
    ushort* __restrict__ fg, float* __restrict__ relu1)
{
    const int lane = threadIdx.x & 63;
    const int wave = threadIdx.x >> 6;
    const int l15  = lane & 15;
    const int lg   = lane >> 4;

    const int bid  = blockIdx.x;          // 1024 = b(2) * y(256) * half(2)
    const int b    = bid >> 9;
    const int rest = bid & 511;
    const int y    = rest >> 1;
    const int x0   = (rest & 1) * 128 + wave * 32;

    f32x4 acc[6][2];
    #pragma unroll
    for (int mf = 0; mf < 6; ++mf)
        #pragma unroll
        for (int nf = 0; nf < 2; ++nf)
            acc[mf][nf] = (f32x4){0.f, 0.f, 0.f, 0.f};

    const bf16x8 zero8 = {};

    #pragma unroll 1
    for (int t = 0; t < 9; ++t) {
        const int dy = t / 3 - 1, dx = t % 3 - 1;
        const int yy = y + dy;
        if ((unsigned)yy >= (unsigned)HH) continue;

        const int xA = x0 + l15 + dx;
        const int xB = xA + 16;
        const bool va = (unsigned)xA < (unsigned)WW;
        const bool vb = (unsigned)xB < (unsigned)WW;
        const int xAc = min(max(xA, 0), WW - 1);
        const int xBc = min(xB, WW - 1);

        const ushort* rowbase = xt + ((size_t)(b * HH + yy) * WW) * 96;
        const ushort* pA = rowbase + (size_t)xAc * 96 + lg * 8;
        const ushort* pB = rowbase + (size_t)xBc * 96 + lg * 8;
        const ushort* wp = wpc1 + (size_t)(t * 3) * (6 * 512) + lane * 8;

        #pragma unroll
        for (int cb = 0; cb < 3; ++cb) {
            bf16x8 B0 = *reinterpret_cast<const bf16x8*>(pA + cb * 32);
            bf16x8 B1 = *reinterpret_cast<const bf16x8*>(pB + cb * 32);
            B0 = va ? B0 : zero8;
            B1 = vb ? B1 : zero8;
            const ushort* wpc = wp + (size_t)cb * (6 * 512);
            #pragma unroll
            for (int mf = 0; mf < 6; ++mf) {
                const bf16x8 A = *reinterpret_cast<const bf16x8*>(wpc + mf * 512);
                acc[mf][0] = __builtin_amdgcn_mfma_f32_16x16x32_bf16(A, B0, acc[mf][0], 0, 0, 0);
                acc[mf][1] = __builtin_amdgcn_mfma_f32_16x16x32_bf16(A, B1, acc[mf][1], 0, 0, 0);
            }
        }
    }

    #pragma unroll
    for (int nf = 0; nf < 2; ++nf) {
        const int xx = x0 + nf * 16 + l15;
        ushort* fgp = fg + ((size_t)(b * HH + y) * WW + xx) * 64;
        #pragma unroll
        for (int mf = 0; mf < 4; ++mf) {
            const int co = mf * 16 + lg * 4;
            ushort pk[4];
            #pragma unroll
            for (int r = 0; r < 4; ++r)
                pk[r] = f2bf(geluf(acc[mf][nf][r] + conv_b[co + r]));
            *reinterpret_cast<uint2*>(fgp + co) = *reinterpret_cast<uint2*>(pk);
        }
    }
    #pragma unroll
    for (int mf = 4; mf < 6; ++mf) {
        const int co = (mf - 4) * 16 + lg * 4;
        #pragma unroll
        for (int nf = 0; nf < 2; ++nf) {
            const int xx = x0 + nf * 16 + l15;
            float* op = relu1 + ((size_t)(b * 32 + co) * HH + y) * WW + xx;
            #pragma unroll
            for (int r = 0; r < 4; ++r)
                op[(size_t)r * HW] = fmaxf(acc[mf][nf][r] + dw1_b[co + r], 0.0f);
        }
    }
}

// Prepack ddct weights (7 layers) into MFMA A-fragment order.
__global__ __launch_bounds__(256) void prepack_wb_kernel(
    const float* __restrict__ ddct_w, ushort* __restrict__ wpb)
{
    const int idx = blockIdx.x * 256 + threadIdx.x;   // 7*9*2*4*64 = 32256
    if (idx >= 7 * 9 * 2 * 4 * 64) return;
    const int lane = idx & 63;
    int rest = idx >> 6;
    const int mf = rest & 3; rest >>= 2;
    const int cb = rest & 1; rest >>= 1;
    const int t  = rest % 9;
    const int li = rest / 9;
    const int co  = mf * 16 + (lane & 15);
    const int ci0 = cb * 32 + (lane >> 4) * 8;
    ushort* dst = wpb + (size_t)idx * 8;
    #pragma unroll
    for (int j = 0; j < 8; ++j)
        dst[j] = f2bf(ddct_w[(((size_t)li * 64 + co) * 64 + ci0 + j) * 9 + t]);
}

// All 7 branch convs on the compact 96x96 grid as MFMA implicit GEMM.
__global__ __launch_bounds__(256) void branch_mfma_kernel(
    const ushort* __restrict__ fg, const ushort* __restrict__ wpb,
    const float* __restrict__ ddct_b, float* __restrict__ ycomp)
{
    const int lane = threadIdx.x & 63;
    const int wave = threadIdx.x >> 6;
    const int l15  = lane & 15;
    const int lg   = lane >> 4;

    int bid = blockIdx.x;              // (li*BB+b)*72 + t72
    const int t72 = bid % 72; bid /= 72;
    const int b  = bid & 1;
    const int li = bid >> 1;
    const int widx = t72 * 4 + wave;
    const int r  = widx / 3;
    const int c0 = (widx - r * 3) * 32;
    const int R  = dec96(r);

    const int cA = c0 + l15, cB = cA + 16;
    const int CA = dec96(cA), CB2 = dec96(cB);

    f32x4 acc[4][2];
    #pragma unroll
    for (int mf = 0; mf < 4; ++mf)
        #pragma unroll
        for (int nf = 0; nf < 2; ++nf)
            acc[mf][nf] = (f32x4){0.f, 0.f, 0.f, 0.f};

    const bf16x8 zero8 = {};
    const ushort* fgb = fg + (size_t)b * HW * 64;

    #pragma unroll 1
    for (int t = 0; t < 9; ++t) {
        const int dy = t / 3 - 1, dx = t % 3 - 1;
        const int yy = R + dy;
        if ((unsigned)yy >= (unsigned)HH) continue;

        const int xA = CA + dx, xB = CB2 + dx;
        const bool va = (unsigned)xA < (unsigned)WW;
        const bool vb = (unsigned)xB < (unsigned)WW;
        const int xAc = min(max(xA, 0), WW - 1);
        const int xBc = min(max(xB, 0), WW - 1);

        const ushort* rowb = fgb + (size_t)yy * WW * 64;
        const ushort* pA = rowb + (size_t)xAc * 64 + lg * 8;
        const ushort* pB = rowb + (size_t)xBc * 64 + lg * 8;
        const ushort* wp = wpb + (size_t)((li * 9 + t) * 2) * (4 * 512) + lane * 8;

        #pragma unroll
        for (int cb = 0; cb < 2; ++cb) {
            bf16x8 B0 = *reinterpret_cast<const bf16x8*>(pA + cb * 32);
            bf16x8 B1 = *reinterpret_cast<const bf16x8*>(pB + cb * 32);
            B0 = va ? B0 : zero8;
            B1 = vb ? B1 : zero8;
            const ushort* wpc = wp + (size_t)cb * (4 * 512);
            #pragma unroll
            for (int mf = 0; mf < 4; ++mf) {
                const bf16x8 A = *reinterpret_cast<const bf16x8*>(wpc + mf * 512);
                acc[mf][0] = __builtin_amdgcn_mfma_f32_16x16x32_bf16(A, B0, acc[mf][0], 0, 0, 0);
                acc[mf][1] = __builtin_amdgcn_mfma_f32_16x16x32_bf16(A, B1, acc[mf][1], 0, 0, 0);
            }
        }
    }

    #pragma unroll
    for (int nf = 0; nf < 2; ++nf) {
        const int c = c0 + nf * 16 + l15;
        const int C = dec96(c);
        const ushort* res = fgb + ((size_t)R * WW + C) * 64;
        #pragma unroll
        for (int mf = 0; mf < 4; ++mf) {
            const int co = mf * 16 + lg * 4;
            ushort r4[4];
            *reinterpret_cast<uint2*>(r4) = *reinterpret_cast<const uint2*>(res + co);
            #pragma unroll
            for (int rr = 0; rr < 4; ++rr) {
                const float v = geluf(acc[mf][nf][rr] + ddct_b[li * 64 + co + rr]) + bf2f(r4[rr]);
                ycomp[((((size_t)li * BB + b) * 64 + co + rr) * 96 + r) * 96 + c] = v;
            }
        }
    }
}

// Depthwise 3x3 stride 8 dil 2 pad 2 -> 32x32 (DCT->IDCT identity skipped).
__global__ __launch_bounds__(256) void dctc_kernel(
    const float* __restrict__ ycomp, const float* __restrict__ dctc_w,
    const float* __restrict__ dctc_b, float* __restrict__ s_all)
{
    const int idx = blockIdx.x * 256 + threadIdx.x;
    if (idx >= 7 * BB * 64 * 32 * 32) return;
    const int ow = idx & 31;
    const int oh = (idx >> 5) & 31;
    const int c  = (idx >> 10) & 63;
    const int b  = (idx >> 16) & (BB - 1);
    const int li = idx >> 17;

    const float* yc = ycomp + (((size_t)li * BB + b) * 64 + c) * (96 * 96);
    const float* w  = dctc_w + (li * 64 + c) * 9;
    float acc = dctc_b[li * 64 + c];
    #pragma unroll
    for (int ky = 0; ky < 3; ++ky) {
        const int cr = 3 * oh + ky - 1;
        if (cr < 0) continue;
        #pragma unroll
        for (int kx = 0; kx < 3; ++kx) {
            const int cc = 3 * ow + kx - 1;
            if (cc < 0) continue;
            acc = fmaf(yc[cr * 96 + cc], w[ky * 3 + kx], acc);
        }
    }
    s_all[idx] = acc;
}

// Transpose gate weights: dw3t[k][512] = dw3_w[ch][k] (fp32).
__global__ __launch_bounds__(256) void prepack_w3_kernel(
    const float* __restrict__ dw3_w, float* __restrict__ dw3t)
{
    const int idx = blockIdx.x * 256 + threadIdx.x;   // 32*512 = 16384
    if (idx >= 32 * 512) return;
    const int ch = idx & 511;
    const int k  = idx >> 9;
    dw3t[k * 512 + ch] = dw3_w[ch * 32 + k];
}

// Gate + bilinear upsample + multiply, writing gated in NHWC bf16.
// v3 (round-14 post-mortem): weight access was lane-scattered (stride-256B ->
// 64 cache lines PER LOAD INST, 64 loads/thread). Now reads transposed
// dw3t[k][512] (wave-contiguous float2) and hoists all 32 k-weights into
// registers before the conv loop. launch_bounds(256,3) for VGPR headroom.
__global__ __launch_bounds__(256, 3) void gated_nhwc_kernel(
    const float* __restrict__ relu1, const float* __restrict__ dw3t,
    const float* __restrict__ dw3_b, const float* __restrict__ s_all,
    ushort* __restrict__ gt)
{
    __shared__ float sm[32][32];   // [k][px]
    const int pix0 = blockIdx.x * 32;
    const int b  = pix0 >> 16;
    const int y  = (pix0 >> 8) & 255;
    const int x0 = pix0 & 255;

    {
        const int spx = threadIdx.x & 31;
        const int k0  = threadIdx.x >> 5;
        const float* rbase = relu1 + (size_t)b * 32 * HW + (size_t)y * WW + x0 + spx;
        #pragma unroll
        for (int i = 0; i < 4; ++i)
            sm[k0 + 8 * i][spx] = rbase[(size_t)(k0 + 8 * i) * HW];
    }
    __syncthreads();

    const int ch0 = threadIdx.x * 2;
    const int branch = ch0 >> 6;
    const int c0 = ch0 & 63;
    const int lmap[8] = {0, 1, 2, 3, 4, 3, 5, 6};
    const int li = lmap[branch];

    const float bb0 = dw3_b[ch0], bb1 = dw3_b[ch0 + 1];

    // hoisted, coalesced weights: lane reads float2 at dw3t[k][ch0]
    float2 wreg[32];
    #pragma unroll
    for (int k = 0; k < 32; ++k)
        wreg[k] = *reinterpret_cast<const float2*>(dw3t + k * 512 + ch0);

    float acc0[32], acc1[32];
    #pragma unroll
    for (int px = 0; px < 32; ++px) { acc0[px] = bb0; acc1[px] = bb1; }

    #pragma unroll
    for (int k = 0; k < 32; ++k) {
        const float w0k = wreg[k].x;
        const float w1k = wreg[k].y;
        const float4* row = reinterpret_cast<const float4*>(&sm[k][0]);
        #pragma unroll
        for (int q = 0; q < 8; ++q) {
            const float4 r4 = row[q];
            acc0[q*4+0] = fmaf(r4.x, w0k, acc0[q*4+0]);
            acc0[q*4+1] = fmaf(r4.y, w0k, acc0[q*4+1]);
            acc0[q*4+2] = fmaf(r4.z, w0k, acc0[q*4+2]);
            acc0[q*4+3] = fmaf(r4.w, w0k, acc0[q*4+3]);
            acc1[q*4+0] = fmaf(r4.x, w1k, acc1[q*4+0]);
            acc1[q*4+1] = fmaf(r4.y, w1k, acc1[q*4+1]);
            acc1[q*4+2] = fmaf(r4.z, w1k, acc1[q*4+2]);
            acc1[q*4+3] = fmaf(r4.w, w1k, acc1[q*4+3]);
        }
    }

    const float* sp0 = s_all + (((size_t)li * BB + b) * 64 + c0) * 1024;
    const float* sp1 = sp0 + 1024;

    const float sy = (y + 0.5f) * 0.125f - 0.5f;
    const float fy0f = floorf(sy);
    const float fy = sy - fy0f;
    int y0 = (int)fy0f;
    const int y1 = min(y0 + 1, 31);
    y0 = max(y0, 0);

    float n0[6], n1[6];
    const int xb = (x0 >> 3) - 1;
    #pragma unroll
    for (int jj = 0; jj < 6; ++jj) {
        const int xn = min(max(xb + jj, 0), 31);
        const float a00 = sp0[y0 * 32 + xn], a01 = sp0[y1 * 32 + xn];
        const float a10 = sp1[y0 * 32 + xn], a11 = sp1[y1 * 32 + xn];
        n0[jj] = a00 + fy * (a01 - a00);
        n1[jj] = a10 + fy * (a11 - a10);
    }

    ushort* gbase = gt + (size_t)pix0 * 512 + ch0;
    #pragma unroll
    for (int px = 0; px < 32; ++px) {
        const int   j  = (px + 4) >> 3;
        const float fx = (float)((px + 4) & 7) * 0.125f + 0.0625f;
        const float va = n0[j] + fx * (n0[j + 1] - n0[j]);
        const float vb = n1[j] + fx * (n1[j + 1] - n1[j]);
        const float g0 = 1.0f / (1.0f + exp2f(-1.4426950408889634f * acc0[px]));
        const float g1 = 1.0f / (1.0f + exp2f(-1.4426950408889634f * acc1[px]));
        const uint pack = (uint)f2bf(va * g0) | ((uint)f2bf(vb * g1) << 16);
        *reinterpret_cast<uint*>(gbase + (size_t)px * 512) = pack;
    }
}

// Prepack ar_w into MFMA A-fragment order (bf16), CB-MAJOR for LDS staging:
// wpack[(((cb*9 + t)*5 + mf)*64 + lane)*8 + j]
__global__ __launch_bounds__(256) void prepack_w_kernel(
    const float* __restrict__ ar_w, ushort* __restrict__ wpack)
{
    const int idx = blockIdx.x * 256 + threadIdx.x;   // 16*9*5*64 = 46080
    if (idx >= 16 * 9 * 5 * 64) return;
    const int lane = idx & 63;
    int rest = idx >> 6;
    const int mf = rest % 5; rest /= 5;
    const int t  = rest % 9;
    const int cb = rest / 9;
    const int co  = mf * 16 + (lane & 15);
    const int ci0 = cb * 32 + (lane >> 4) * 8;
    ushort* dst = wpack + (size_t)idx * 8;
    #pragma unroll
    for (int j = 0; j < 8; ++j) {
        const float w = (co < 72) ? ar_w[((size_t)co * 512 + ci0 + j) * 9 + t] : 0.0f;
        dst[j] = f2bf(w);
    }
}

#define WPK_CHUNK (9 * 5 * 512)   // ushorts per cb chunk = 23040 (46080 B)

// Final conv 512->72 as implicit GEMM on MFMA (NHWC bf16 input).
// v4: per-cb LDS-staged weights + launch_bounds(256,2). 64px/wave,
// bijective XCD swizzle, cb-outer/tap-inner K loop.
__global__ __launch_bounds__(256, 2) void conv_ar_mfma_kernel(
    const ushort* __restrict__ gt, const ushort* __restrict__ wpack,
    const float* __restrict__ ar_b, float* __restrict__ out)
{
    __shared__ ushort smw[WPK_CHUNK];
    const int tid  = threadIdx.x;
    const int lane = tid & 63;
    const int wave = tid >> 6;
    const int l15  = lane & 15;
    const int lg   = lane >> 4;

    // bijective XCD swizzle: nwg=512, 8 XCDs, 64 logical blocks per XCD
    const int lb = (blockIdx.x & 7) * 64 + (blockIdx.x >> 3);
    const int b  = lb >> 8;
    const int y  = lb & 255;
    const int x0 = wave * 64;

    f32x4 acc[5][4];
    #pragma unroll
    for (int mf = 0; mf < 5; ++mf)
        #pragma unroll
        for (int nf = 0; nf < 4; ++nf)
            acc[mf][nf] = (f32x4){0.f, 0.f, 0.f, 0.f};

    const ushort* rowp[3];
    bool rowok[3];
    #pragma unroll
    for (int dy = 0; dy < 3; ++dy) {
        const int yy = y + dy - 1;
        rowok[dy] = (unsigned)yy < (unsigned)HH;
        rowp[dy]  = gt + ((size_t)(b * HH + (rowok[dy] ? yy : 0)) * WW) * 512;
    }
    int  offx[3][4];
    bool vx[3][4];
    #pragma unroll
    for (int dx = 0; dx < 3; ++dx) {
        #pragma unroll
        for (int nf = 0; nf < 4; ++nf) {
            const int xx = x0 + nf * 16 + l15 + dx - 1;
            vx[dx][nf]   = (unsigned)xx < (unsigned)WW;
            offx[dx][nf] = min(max(xx, 0), WW - 1) * 512 + lg * 8;
        }
    }

    const bf16x8 zero8 = {};

    #pragma unroll 1
    for (int cb = 0; cb < 16; ++cb) {
        __syncthreads();
        {
            const uint4* src = reinterpret_cast<const uint4*>(wpack + (size_t)cb * WPK_CHUNK);
            uint4* dst = reinterpret_cast<uint4*>(smw);
            #pragma unroll
            for (int i = 0; i < 12; ++i) {
                const int e = i * 256 + tid;
                if (e < 2880) dst[e] = src[e];
            }
        }
        __syncthreads();

        const int cbo = cb * 32;
        #pragma unroll
        for (int t = 0; t < 9; ++t) {
            const int dy = t / 3, dx = t % 3;
            if (!rowok[dy]) continue;   // block-uniform (depends only on y)
            bf16x8 Bv[4];
            #pragma unroll
            for (int nf = 0; nf < 4; ++nf) {
                bf16x8 v = *reinterpret_cast<const bf16x8*>(rowp[dy] + offx[dx][nf] + cbo);
                Bv[nf] = vx[dx][nf] ? v : zero8;
            }
            const ushort* wl = smw + (t * 5) * 512 + lane * 8;
            #pragma unroll
            for (int mf = 0; mf < 5; ++mf) {
                const bf16x8 A = *reinterpret_cast<const bf16x8*>(wl + mf * 512);
                #pragma unroll
                for (int nf = 0; nf < 4; ++nf)
                    acc[mf][nf] = __builtin_amdgcn_mfma_f32_16x16x32_bf16(A, Bv[nf], acc[mf][nf], 0, 0, 0);
            }
        }
    }

    #pragma unroll
    for (int mf = 0; mf < 5; ++mf) {
        const int co = mf * 16 + lg * 4;
        if (co >= 72) continue;
        #pragma unroll
        for (int nf = 0; nf < 4; ++nf) {
            const int x = x0 + nf * 16 + l15;
            float* op = out + (((size_t)(b * 72 + co) * HH + y) * WW) + x;
            #pragma unroll
            for (int r = 0; r < 4; ++r)
                op[(size_t)r * HW] = acc[mf][nf][r] + ar_b[co + r];
        }
    }
}

extern "C" void kernel_launch(void* const* d_in, const int* in_sizes, int n_in,
                              void* d_out, int out_size, void* d_ws, size_t ws_size,
                              hipStream_t stream) {
    const float* x      = (const float*)d_in[0];
    const float* conv_w = (const float*)d_in[1];
    const float* conv_b = (const float*)d_in[2];
    const float* ddct_w = (const float*)d_in[3];
    const float* ddct_b = (const float*)d_in[4];
    const float* dctc_w = (const float*)d_in[5];
    const float* dctc_b = (const float*)d_in[6];
    const float* dw1_w  = (const float*)d_in[7];
    const float* dw1_b  = (const float*)d_in[8];
    const float* dw3_w  = (const float*)d_in[9];
    const float* dw3_b  = (const float*)d_in[10];
    const float* ar_w   = (const float*)d_in[11];
    const float* ar_b   = (const float*)d_in[12];
    float* out = (float*)d_out;

    float* ws = (float*)d_ws;
    // Layout (float slots). fg + ycomp are dead before gated_t is written.
    ushort* gated_t = (ushort*)ws;               // [0 .. 33,554,432) f
    ushort* fg    = (ushort*)ws;                 // [0 .. 4,194,304) f
    float* ycomp  = ws + 4194304;                // -> ends 12,451,840
    float* s_all  = ws + 33554432;               // 917,504 f
    float* relu1  = ws + 34471936;               // 4,194,304 f
    ushort* wpack = (ushort*)(ws + 38666240);    // -> ends 38,850,560 f
    ushort* wpb   = (ushort*)(ws + 38850560);    // -> ends 38,979,584 f
    ushort* wpc1  = (ushort*)(ws + 38979584);    // -> ends 39,021,056 f
    ushort* xt    = (ushort*)(ws + 39021056);    // -> ends 45,312,512 f
    float* dw3t   = ws + 45312512;               // 16,384 f -> ends 45,328,896

    // 0) weight prepacks + x transpose
    prepack_w_kernel<<<dim3(180), dim3(256), 0, stream>>>(ar_w, wpack);
    prepack_wb_kernel<<<dim3(126), dim3(256), 0, stream>>>(ddct_w, wpb);
    prepack_w1_kernel<<<dim3(41), dim3(256), 0, stream>>>(conv_w, dw1_w, wpc1);
    prepack_w3_kernel<<<dim3(64), dim3(256), 0, stream>>>(dw3_w, dw3t);
    xpose_kernel<<<dim3(BB * HW / 256), dim3(256), 0, stream>>>(x, xt);

    // 1) fused conv1 (fg NHWC bf16, gelu) + dw1 (relu1 NCHW fp32, relu)
    conv1dw1_mfma_kernel<<<dim3(BB * HH * 2), dim3(256), 0, stream>>>(
        xt, wpc1, conv_b, dw1_b, fg, relu1);

    // 2) branch convs (7 layers) as MFMA implicit GEMM on compact grid
    branch_mfma_kernel<<<dim3(7 * BB * 72), dim3(256), 0, stream>>>(
        fg, wpb, ddct_b, ycomp);

    // 3) depthwise stride-8 convs
    dctc_kernel<<<dim3((7 * BB * 64 * 32 * 32) / 256), dim3(256), 0, stream>>>(
        ycomp, dctc_w, dctc_b, s_all);

    // 4) gated (NHWC bf16) = upsample(s) * sigmoid(1x1conv(relu1))
    gated_nhwc_kernel<<<dim3(BB * HW / 32), dim3(256), 0, stream>>>(
        relu1, dw3t, dw3_b, s_all, gated_t);

    // 5) out = conv3x3(gated, ar_w)  512 -> 72, MFMA implicit GEMM (64px/wave,
    //    LDS-staged weights)
    conv_ar_mfma_kernel<<<dim3(BB * HH), dim3(256), 0, stream>>>(
        gated_t, wpack, ar_b, out);
}